// Round 9
// baseline (453.055 us; speedup 1.0000x reference)
//
#include <hip/hip_runtime.h>

typedef unsigned short u16;
typedef unsigned int u32;
typedef __attribute__((ext_vector_type(4))) short bf16x4;
typedef __attribute__((ext_vector_type(8))) short bf16x8;
typedef __attribute__((ext_vector_type(4))) float f32x4;

#define SCALE 0.125f
#define BLENDF 0.4875f
#define NTOT 2202
#define NPAD 2304
#define L2E 1.44269504f

#define SBAR()  __builtin_amdgcn_s_barrier()
#define SCHED0() __builtin_amdgcn_sched_barrier(0)
#define VMWAIT(n) asm volatile("s_waitcnt vmcnt(" #n ")" ::: "memory")

__device__ __forceinline__ u16 f2bf(float x){
  union { float f; unsigned u; } v; v.f = x;
  unsigned r = v.u + 0x7fffu + ((v.u >> 16) & 1u);
  return (u16)(r >> 16);
}
__device__ __forceinline__ float bf2f(u16 b){
  union { unsigned u; float f; } v; v.u = (u32)b << 16; return v.f;
}

__device__ __forceinline__ float fexp2(float x){
#if __has_builtin(__builtin_amdgcn_exp2f)
  return __builtin_amdgcn_exp2f(x);
#else
  return __expf(x * 0.6931472f);
#endif
}

__device__ __forceinline__ f32x4 MFMA(bf16x8 a, bf16x8 b, f32x4 c){
  return __builtin_amdgcn_mfma_f32_16x16x32_bf16(a, b, c, 0, 0, 0);
}

// async global->LDS, 16B per lane; LDS dest is wave-uniform base (+lane*16 implicit)
__device__ __forceinline__ void gload16(const u16* g, u16* l){
  __builtin_amdgcn_global_load_lds(
    (const __attribute__((address_space(1))) u32*)g,
    (__attribute__((address_space(3))) u32*)l, 16, 0, 0);
}

__device__ __forceinline__ float red64_sum(float x){
  x += __shfl_xor(x, 1, 64);
  x += __shfl_xor(x, 2, 64);
  x += __shfl_xor(x, 4, 64);
  x += __shfl_xor(x, 8, 64);
  x += __shfl_xor(x, 16, 64);
  x += __shfl_xor(x, 32, 64);
  return x;
}
// reduce over the l4 axis (lanes sharing the same lane&15)
__device__ __forceinline__ float redl4_sum(float x){
  x += __shfl_xor(x, 16, 64);
  x += __shfl_xor(x, 32, 64);
  return x;
}
__device__ __forceinline__ float redl4_max(float x){
  x = fmaxf(x, __shfl_xor(x, 16, 64));
  x = fmaxf(x, __shfl_xor(x, 32, 64));
  return x;
}

// ---------------- utility kernels ----------------

__global__ void k_zeropad(u16* __restrict__ a, u16* __restrict__ b,
                          u16* __restrict__ c, long n8){
  long i = (long)blockIdx.x * blockDim.x + threadIdx.x;
  if (i < n8){
    const bf16x8 z = {0,0,0,0,0,0,0,0};
    *(bf16x8*)(a + i*8) = z;
    *(bf16x8*)(b + i*8) = z;
    *(bf16x8*)(c + i*8) = z;
  }
}

__global__ void k_cast(const float* __restrict__ in, u16* __restrict__ out, long n){
  long i = ((long)blockIdx.x * blockDim.x + threadIdx.x) * 4;
  long stride = (long)gridDim.x * blockDim.x * 4;
  for (; i < n; i += stride){
    float4 f = *(const float4*)(in + i);
    bf16x4 v = { (short)f2bf(f.x), (short)f2bf(f.y), (short)f2bf(f.z), (short)f2bf(f.w) };
    *(bf16x4*)(out + i) = v;
  }
}

// w_vec[d] = sum_k Wsl[k] * Kp[k][d]  (rank-1 gate precompute)
__global__ __launch_bounds__(256) void k_wvec(const u16* __restrict__ Kp,
                                              const float* __restrict__ Wsl,
                                              float* __restrict__ wvec){
  const int d = blockIdx.x * 256 + threadIdx.x;
  float acc = 0.f;
  for (int k = 0; k < 256; ++k)
    acc += Wsl[k] * bf2f(Kp[(size_t)k * 1536 + d]);
  wvec[d] = acc;
}

struct WT { const float* s; u16* d; int K; };
struct WT10 { WT w[10]; };

// in: [K][1536] fp32 -> out: [1536][K] bf16
__global__ __launch_bounds__(256) void k_transpose_w(WT10 ws){
  const WT t = ws.w[blockIdx.z];
  const int r0 = blockIdx.y * 32;
  if (r0 >= t.K) return;
  const int c0 = blockIdx.x * 32;
  __shared__ float tile[32][33];
  const int x = threadIdx.x, y = threadIdx.y;
  #pragma unroll
  for (int k = 0; k < 4; ++k)
    tile[y + 8*k][x] = t.s[(size_t)(r0 + y + 8*k) * 1536 + c0 + x];
  __syncthreads();
  #pragma unroll
  for (int k = 0; k < 4; ++k)
    t.d[(size_t)(c0 + y + 8*k) * t.K + r0 + x] = f2bf(tile[x][y + 8*k]);
}

// in: [R][C] bf16 -> out[C][R] bf16 with columns PERMUTED within each 32-block:
// out[d][32b + p] = in[32b + k(p)][d], k(p) = ((p>>2)&1)*16 + (p>>3)*4 + (p&3)
// == MFMA k-slot map pi(l4,j) at p = l4*8+j -> a 16B read at col l4*8 is the B-fragment.
__global__ __launch_bounds__(256) void k_transpose_vp(const u16* __restrict__ in,
                                                      u16* __restrict__ out, int R, int C){
  const int r0 = blockIdx.y * 32, c0 = blockIdx.x * 32;
  __shared__ u16 tile[32][34];
  const int x = threadIdx.x, y = threadIdx.y;
  #pragma unroll
  for (int k = 0; k < 4; ++k)
    tile[y + 8*k][x] = in[(size_t)(r0 + y + 8*k) * C + c0 + x];
  __syncthreads();
  const int kx = (((x >> 2) & 1) << 4) + ((x >> 3) << 2) + (x & 3);
  #pragma unroll
  for (int k = 0; k < 4; ++k)
    out[(size_t)(c0 + y + 8*k) * R + r0 + x] = tile[kx][y + 8*k];
}

// ---------------- GEMM: C = A[M][K] * BT[N][K]^T, fused N-segments ----------------
// Fragment-major LDS chunks (conflict-free), DOUBLE-buffered with COUNTED vmcnt:
// next-tile loads stay in flight across raw barriers (T4); drain only at the end.

struct GOuts { void* C[3]; const float* b[3]; };

template<int OUTF32>
__global__ __launch_bounds__(256, 2) void k_gemm(
  const u16* __restrict__ A, int lda,
  const u16* __restrict__ BT, int ldb,
  GOuts o, int ldc, int M, int N, int K,
  int gx, int nCx, int rBlk, int cBlk)
{
  __shared__ alignas(1024) u16 As[2][8192];
  __shared__ alignas(1024) u16 Bs[2][8192];
  const int tid = threadIdx.x, lane = tid & 63, w = tid >> 6;
  const int l15 = lane & 15, l4 = lane >> 4;

  int bx, by;
  if (gx){
    const int xcd = blockIdx.x & 7, slot = blockIdx.x >> 3;
    const int rx = xcd / nCx, cx = xcd - rx * nCx;
    by = rx * rBlk + slot / cBlk;
    bx = cx * cBlk + slot % cBlk;
  } else {
    bx = blockIdx.x; by = blockIdx.y;
  }
  const int m0 = by * 128, n0 = bx * 128;
  const int wm = (w >> 1) * 64, wn = (w & 1) * 64;

  f32x4 acc[4][4];
  #pragma unroll
  for (int i = 0; i < 4; ++i)
    #pragma unroll
    for (int j = 0; j < 4; ++j)
      acc[i][j] = (f32x4){0.f, 0.f, 0.f, 0.f};

  auto STAGE = [&](int b, int k0){
    #pragma unroll
    for (int c = 0; c < 2; ++c)
      #pragma unroll
      for (int kk = 0; kk < 2; ++kk){
        const int rb = w * 2 + c;
        const int gcol = k0 + kk*32 + l4*8;
        const int ar = min(m0 + rb*16 + l15, M - 1);
        gload16(A + (size_t)ar * lda + gcol, &As[b][(rb*2 + kk) * 512]);
        const int br = min(n0 + rb*16 + l15, N - 1);
        gload16(BT + (size_t)br * ldb + gcol, &Bs[b][(rb*2 + kk) * 512]);
      }
  };

  STAGE(0, 0);
  __syncthreads();                      // prologue drain (once)

  const int nk = K >> 6;
  int buf = 0;
  for (int t = 0; t < nk; ++t){
    if (t + 1 < nk){
      STAGE(buf ^ 1, (t + 1) * 64);    // issue next tile BEFORE waiting
      VMWAIT(8);                        // wait only for current tile; next stays in flight
    } else {
      VMWAIT(0);
    }
    SCHED0();
    SBAR();
    SCHED0();
    #pragma unroll
    for (int kk = 0; kk < 2; ++kk){
      bf16x8 a[4], b[4];
      #pragma unroll
      for (int m = 0; m < 4; ++m)
        a[m] = *(const bf16x8*)(As[buf] + ((((w>>1)*4 + m)*2 + kk) * 512) + lane*8);
      #pragma unroll
      for (int n = 0; n < 4; ++n)
        b[n] = *(const bf16x8*)(Bs[buf] + ((((w&1)*4 + n)*2 + kk) * 512) + lane*8);
      #pragma unroll
      for (int m = 0; m < 4; ++m)
        #pragma unroll
        for (int n = 0; n < 4; ++n)
          acc[m][n] = MFMA(a[m], b[n], acc[m][n]);
    }
    SCHED0();
    SBAR();                             // protect buf from next iteration's STAGE
    buf ^= 1;
  }

  #pragma unroll
  for (int n = 0; n < 4; ++n){
    const int colg = n0 + wn + n*16 + l15;
    const int sel = colg / 1536;
    const int col = colg - sel * 1536;
    const float* bp = o.b[sel];
    const float bi = bp ? bp[col] : 0.f;
    #pragma unroll
    for (int m = 0; m < 4; ++m){
      const int row0 = m0 + wm + m*16 + l4*4;
      #pragma unroll
      for (int r = 0; r < 4; ++r){
        const int row = row0 + r;
        if (row < M){
          float val = acc[m][n][r] + bi;
          if (OUTF32) ((float*)o.C[sel])[(size_t)row * ldc + col] = val;
          else        ((u16*)o.C[sel])[(size_t)row * ldc + col] = f2bf(val);
        }
      }
    }
  }
}

// ---------------- cross attention: flash-style, rank-1 gate, counted vmcnt ----------------

__global__ __launch_bounds__(256, 4) void k_cross_attn(
  const u16* __restrict__ Q,     // [*, 1536], rows 0..2047 used
  const u16* __restrict__ Kp,    // [256][1536]
  const u16* __restrict__ VpP,   // [1536][256], cols pi-permuted per 32-block
  const float* __restrict__ clip,
  const float* __restrict__ Wsl, // [512]
  const float* __restrict__ bslp,
  const float* __restrict__ wvec,// [1536]
  float* __restrict__ multi)     // [2048][1536]
{
  const int h = blockIdx.y;
  const int tid = threadIdx.x, lane = tid & 63, w = tid >> 6;
  const int l15 = lane & 15, l4 = lane >> 4;
  const int qrow = blockIdx.x * 64 + w * 16 + l15;

  __shared__ alignas(1024) u16 Ks[2][4096];
  __shared__ alignas(1024) u16 VTs[2][4096];
  __shared__ float clip_l[256];
  if (tid < 256) clip_l[tid] = clip[tid];

  float cd = 0.f;
  for (int p = lane; p < 256; p += 64) cd += clip[p] * Wsl[256 + p];
  cd = red64_sum(cd);
  const float gate_c = cd + bslp[0];

  bf16x8 qf[2];
  #pragma unroll
  for (int kk = 0; kk < 2; ++kk)
    qf[kk] = *(const bf16x8*)(Q + (size_t)qrow * 1536 + h*64 + kk*32 + l4*8);

  // gate = SCALE * (w_h . q_row) + gate_c   (per q = l15; sum over l4 axis)
  float gd = 0.f;
  #pragma unroll
  for (int kk = 0; kk < 2; ++kk){
    const float4 w0 = *(const float4*)(wvec + h*64 + kk*32 + l4*8);
    const float4 w1 = *(const float4*)(wvec + h*64 + kk*32 + l4*8 + 4);
    gd += w0.x * bf2f((u16)qf[kk][0]) + w0.y * bf2f((u16)qf[kk][1]);
    gd += w0.z * bf2f((u16)qf[kk][2]) + w0.w * bf2f((u16)qf[kk][3]);
    gd += w1.x * bf2f((u16)qf[kk][4]) + w1.y * bf2f((u16)qf[kk][5]);
    gd += w1.z * bf2f((u16)qf[kk][6]) + w1.w * bf2f((u16)qf[kk][7]);
  }
  const float gate = SCALE * redl4_sum(gd) + gate_c;

  f32x4 O[4];
  #pragma unroll
  for (int nb = 0; nb < 4; ++nb) O[nb] = (f32x4){0.f, 0.f, 0.f, 0.f};
  float m_ = -1e30f, l_ = 0.f;

  auto STAGE = [&](int buf, int kt0){
    #pragma unroll
    for (int c = 0; c < 2; ++c){
      gload16(Kp + (size_t)(kt0 + w*16 + l15) * 1536 + h*64 + c*32 + l4*8,
              &Ks[buf][(w*2 + c) * 512]);
      gload16(VpP + (size_t)(h*64 + w*16 + l15) * 256 + kt0 + c*32 + l4*8,
              &VTs[buf][(w*2 + c) * 512]);
    }
  };

  STAGE(0, 0);
  __syncthreads();                      // prologue drain + clip_l visibility

  int buf = 0;
  for (int nt = 0; nt < 4; ++nt){
    if (nt + 1 < 4){
      STAGE(buf ^ 1, (nt + 1) * 64);
      VMWAIT(4);
    } else {
      VMWAIT(0);
    }
    SCHED0();
    SBAR();
    SCHED0();
    const int kt0 = nt * 64;

    f32x4 s[4];
    __builtin_amdgcn_s_setprio(1);
    #pragma unroll
    for (int n4 = 0; n4 < 4; ++n4){
      f32x4 t = {0.f, 0.f, 0.f, 0.f};
      #pragma unroll
      for (int kk = 0; kk < 2; ++kk){
        bf16x8 kf = *(const bf16x8*)(&Ks[buf][(n4*2 + kk) * 512 + lane*8]);
        t = MFMA(kf, qf[kk], t);
      }
      s[n4] = t;
    }
    __builtin_amdgcn_s_setprio(0);

    // bias: s = S*SCALE + gate*clip[key], key = kt0 + n4*16 + l4*4 + r
    #pragma unroll
    for (int n4 = 0; n4 < 4; ++n4){
      const float4 cv = *(const float4*)&clip_l[kt0 + n4*16 + l4*4];
      s[n4][0] = fmaf(s[n4][0], SCALE, gate * cv.x);
      s[n4][1] = fmaf(s[n4][1], SCALE, gate * cv.y);
      s[n4][2] = fmaf(s[n4][2], SCALE, gate * cv.z);
      s[n4][3] = fmaf(s[n4][3], SCALE, gate * cv.w);
    }

    float mt = -1e30f;
    #pragma unroll
    for (int n4 = 0; n4 < 4; ++n4)
      mt = fmaxf(mt, fmaxf(fmaxf(s[n4][0], s[n4][1]), fmaxf(s[n4][2], s[n4][3])));
    mt = redl4_max(mt);

    const float mn = fmaxf(m_, mt);
    const float al = fexp2((m_ - mn) * L2E);
    m_ = mn;
    l_ *= al;
    float alo[4];
    #pragma unroll
    for (int r = 0; r < 4; ++r) alo[r] = __shfl(al, l4*4 + r, 16);
    #pragma unroll
    for (int nb = 0; nb < 4; ++nb)
      #pragma unroll
      for (int r = 0; r < 4; ++r) O[nb][r] *= alo[r];

    const float m2 = m_ * L2E;
    u16 pb[16];
    float ls = 0.f;
    #pragma unroll
    for (int n4 = 0; n4 < 4; ++n4)
      #pragma unroll
      for (int r = 0; r < 4; ++r){
        float pv = fexp2(fmaf(s[n4][r], L2E, -m2));
        ls += pv;
        pb[n4*4 + r] = f2bf(pv);
      }
    l_ += redl4_sum(ls);

    __builtin_amdgcn_s_setprio(1);
    #pragma unroll
    for (int kk = 0; kk < 2; ++kk){
      bf16x8 pa = { (short)pb[kk*8+0], (short)pb[kk*8+1], (short)pb[kk*8+2], (short)pb[kk*8+3],
                    (short)pb[kk*8+4], (short)pb[kk*8+5], (short)pb[kk*8+6], (short)pb[kk*8+7] };
      #pragma unroll
      for (int nb = 0; nb < 4; ++nb){
        bf16x8 vt = *(const bf16x8*)(&VTs[buf][(nb*2 + kk) * 512 + lane*8]);
        O[nb] = MFMA(pa, vt, O[nb]);
      }
    }
    __builtin_amdgcn_s_setprio(0);

    SCHED0();
    SBAR();
    buf ^= 1;
  }

  const float inv = 1.f / l_;
  float li[4];
  #pragma unroll
  for (int r = 0; r < 4; ++r) li[r] = __shfl(inv, l4*4 + r, 16);
  #pragma unroll
  for (int r = 0; r < 4; ++r){
    const int row = blockIdx.x * 64 + w * 16 + l4*4 + r;
    #pragma unroll
    for (int nb = 0; nb < 4; ++nb)
      multi[(size_t)row * 1536 + h*64 + nb*16 + l15] = O[nb][r] * li[r];
  }
}

// ---------------- self attention (flash, swapped QK^T, counted-vmcnt dbuf) ----------------

__global__ __launch_bounds__(256, 4) void k_self_attn(
  const u16* __restrict__ q2,   // [2304][1536]
  const u16* __restrict__ k2,   // [2304][1536]
  const u16* __restrict__ v2P,  // [1536][2304], cols pi-permuted per 32-block
  float* __restrict__ hsout)    // [2202][1536]
{
  const int p = blockIdx.x;
  const int h  = (p & 7) * 3 + (p >> 3) / 35;
  const int qb = (p >> 3) % 35;
  const int tid = threadIdx.x, lane = tid & 63, w = tid >> 6;
  const int l15 = lane & 15, l4 = lane >> 4;
  const int qrow = qb * 64 + w * 16 + l15;

  __shared__ alignas(1024) u16 Ks[2][4096];
  __shared__ alignas(1024) u16 VTs[2][4096];

  bf16x8 qf[2];
  #pragma unroll
  for (int kk = 0; kk < 2; ++kk)
    qf[kk] = *(const bf16x8*)(q2 + (size_t)qrow * 1536 + h*64 + kk*32 + l4*8);

  f32x4 O[4];
  #pragma unroll
  for (int nb = 0; nb < 4; ++nb) O[nb] = (f32x4){0.f, 0.f, 0.f, 0.f};
  float m_ = -1e30f, l_ = 0.f;
  const float C2 = SCALE * L2E;
  const float THR = 44.36f;             // 8 / C2

  const u16* kp  = k2 + h*64;
  const u16* vp0 = v2P + (size_t)(h*64) * NPAD;

  auto STAGE = [&](int buf, int kt0){
    #pragma unroll
    for (int c = 0; c < 2; ++c){
      gload16(kp + (size_t)(kt0 + w*16 + l15) * 1536 + c*32 + l4*8,
              &Ks[buf][(w*2 + c) * 512]);
      gload16(vp0 + (size_t)(w*16 + l15) * NPAD + kt0 + c*32 + l4*8,
              &VTs[buf][(w*2 + c) * 512]);
    }
  };

  STAGE(0, 0);
  __syncthreads();                      // prologue drain (once)

  int buf = 0;
  for (int nt = 0; nt < 35; ++nt){
    if (nt + 1 < 35){
      STAGE(buf ^ 1, (nt + 1) * 64);
      VMWAIT(4);
    } else {
      VMWAIT(0);
    }
    SCHED0();
    SBAR();
    SCHED0();
    const int kt0 = nt * 64;

    f32x4 s[4];
    __builtin_amdgcn_s_setprio(1);
    #pragma unroll
    for (int n4 = 0; n4 < 4; ++n4){
      f32x4 t = {0.f, 0.f, 0.f, 0.f};
      #pragma unroll
      for (int kk = 0; kk < 2; ++kk){
        bf16x8 kf = *(const bf16x8*)(&Ks[buf][(n4*2 + kk) * 512 + lane*8]);
        t = MFMA(kf, qf[kk], t);
      }
      s[n4] = t;
    }
    __builtin_amdgcn_s_setprio(0);

    if (kt0 + 64 > NTOT){                       // only the last tile
      #pragma unroll
      for (int n4 = 0; n4 < 4; ++n4){
        const int keyb = kt0 + n4*16 + l4*4;
        #pragma unroll
        for (int r = 0; r < 4; ++r)
          if (keyb + r >= NTOT) s[n4][r] = -1e30f;
      }
    }

    float mt = -1e30f;
    #pragma unroll
    for (int n4 = 0; n4 < 4; ++n4)
      mt = fmaxf(mt, fmaxf(fmaxf(s[n4][0], s[n4][1]), fmaxf(s[n4][2], s[n4][3])));
    mt = redl4_max(mt);

    if (__any(mt > m_ + THR)){                  // T13 defer-max
      const float mn = fmaxf(m_, mt);
      const float al = fexp2((m_ - mn) * C2);
      m_ = mn;
      l_ *= al;
      float alo[4];
      #pragma unroll
      for (int r = 0; r < 4; ++r) alo[r] = __shfl(al, l4*4 + r, 16);
      #pragma unroll
      for (int nb = 0; nb < 4; ++nb)
        #pragma unroll
        for (int r = 0; r < 4; ++r) O[nb][r] *= alo[r];
    }
    const float m2 = m_ * C2;

    u16 pb[16];
    float ls = 0.f;
    #pragma unroll
    for (int n4 = 0; n4 < 4; ++n4)
      #pragma unroll
      for (int r = 0; r < 4; ++r){
        float pv = fexp2(fmaf(s[n4][r], C2, -m2));
        ls += pv;
        pb[n4*4 + r] = f2bf(pv);
      }
    l_ += redl4_sum(ls);

    __builtin_amdgcn_s_setprio(1);
    #pragma unroll
    for (int kk = 0; kk < 2; ++kk){
      bf16x8 pa = { (short)pb[kk*8+0], (short)pb[kk*8+1], (short)pb[kk*8+2], (short)pb[kk*8+3],
                    (short)pb[kk*8+4], (short)pb[kk*8+5], (short)pb[kk*8+6], (short)pb[kk*8+7] };
      #pragma unroll
      for (int nb = 0; nb < 4; ++nb){
        bf16x8 vt = *(const bf16x8*)(&VTs[buf][(nb*2 + kk) * 512 + lane*8]);
        O[nb] = MFMA(pa, vt, O[nb]);
      }
    }
    __builtin_amdgcn_s_setprio(0);

    SCHED0();
    SBAR();
    buf ^= 1;
  }

  const float inv = 1.f / l_;
  float li[4];
  #pragma unroll
  for (int r = 0; r < 4; ++r) li[r] = __shfl(inv, l4*4 + r, 16);
  #pragma unroll
  for (int r = 0; r < 4; ++r){
    const int row = qb * 64 + w * 16 + l4*4 + r;
    if (row < NTOT){
      #pragma unroll
      for (int nb = 0; nb < 4; ++nb)
        hsout[(size_t)row * 1536 + h*64 + nb*16 + l15] = O[nb][r] * li[r];
    }
  }
}

// ---------------- adaptive gate + blend ----------------

__global__ __launch_bounds__(256) void k_adaptive(
  const float* __restrict__ multi, const float* __restrict__ hsbuf,
  const float* __restrict__ Wad, const float* __restrict__ badp,
  u16* __restrict__ blended)
{
  const int lane = threadIdx.x & 63, wid = threadIdx.x >> 6;
  const int q = blockIdx.x * 4 + wid;
  const float* mrow = multi + (size_t)q * 1536;
  const float* hrow = hsbuf + (size_t)q * 1536;
  float acc = 0.f;
  #pragma unroll
  for (int i = 0; i < 24; ++i){
    int d = lane + 64 * i;
    acc += mrow[d] * Wad[d] + hrow[d] * Wad[1536 + d];
  }
  acc = red64_sum(acc) + badp[0];
  const float sig = 1.f / (1.f + __expf(-acc));
  const float f = BLENDF * sig;
  u16* brow = blended + (size_t)q * 1536;
  #pragma unroll
  for (int i = 0; i < 24; ++i){
    int d = lane + 64 * i;
    brow[d] = f2bf(f * mrow[d] + hrow[d]);
  }
}

// ---------------- launch ----------------

extern "C" void kernel_launch(void* const* d_in, const int* in_sizes, int n_in,
                              void* d_out, int out_size, void* d_ws, size_t ws_size,
                              hipStream_t stream)
{
  (void)in_sizes; (void)n_in; (void)out_size; (void)ws_size;
  const float* hs   = (const float*)d_in[0];
  const float* enc  = (const float*)d_in[1];
  const float* pics = (const float*)d_in[2];
  const float* clip = (const float*)d_in[3];
  const float* Wq   = (const float*)d_in[4];  const float* bq   = (const float*)d_in[5];
  const float* Wk   = (const float*)d_in[6];  const float* bk   = (const float*)d_in[7];
  const float* Wv   = (const float*)d_in[8];  const float* bv   = (const float*)d_in[9];
  const float* Waq  = (const float*)d_in[10]; const float* baq  = (const float*)d_in[11];
  const float* Wak  = (const float*)d_in[12]; const float* bak  = (const float*)d_in[13];
  const float* Wav  = (const float*)d_in[14]; const float* bav  = (const float*)d_in[15];
  const float* Wkl  = (const float*)d_in[16]; const float* Wvl  = (const float*)d_in[17];
  const float* Wsl  = (const float*)d_in[18]; const float* bsl  = (const float*)d_in[19];
  const float* Wad  = (const float*)d_in[20]; const float* bad  = (const float*)d_in[21];
  const float* Wout = (const float*)d_in[22]; const float* bout = (const float*)d_in[23];
  const float* Wadd = (const float*)d_in[24]; const float* badd = (const float*)d_in[25];

  char* ws = (char*)d_ws;
  size_t off = 0;
  auto alloc = [&](size_t b){ void* p = ws + off; off += (b + 255) & ~(size_t)255; return p; };

  u16* hs_bf  = (u16*)alloc((size_t)2048*1536*2);
  u16* enc_bf = (u16*)alloc((size_t)154*1536*2);
  u16* pics_bf= (u16*)alloc((size_t)256*1024*2);
  u16* WqT  = (u16*)alloc((size_t)1536*1536*2);
  u16* WkT  = (u16*)alloc((size_t)1536*1536*2);
  u16* WvT  = (u16*)alloc((size_t)1536*1536*2);
  u16* WaqT = (u16*)alloc((size_t)1536*1536*2);
  u16* WakT = (u16*)alloc((size_t)1536*1536*2);
  u16* WavT = (u16*)alloc((size_t)1536*1536*2);
  u16* WoutT= (u16*)alloc((size_t)1536*1536*2);
  u16* WaddT= (u16*)alloc((size_t)1536*1536*2);
  u16* WklT = (u16*)alloc((size_t)1536*1024*2);
  u16* WvlT = (u16*)alloc((size_t)1536*1024*2);
  u16* q2   = (u16*)alloc((size_t)NPAD*1536*2);
  u16* k2   = (u16*)alloc((size_t)NPAD*1536*2);
  u16* v2   = (u16*)alloc((size_t)NPAD*1536*2);
  u16* v2P  = (u16*)alloc((size_t)1536*NPAD*2);
  u16* Kp   = (u16*)alloc((size_t)256*1536*2);
  u16* Vp   = (u16*)alloc((size_t)256*1536*2);
  u16* VpP  = (u16*)alloc((size_t)1536*256*2);
  float* wvec   = (float*)alloc((size_t)1536*4);
  float* multi  = (float*)alloc((size_t)2048*1536*4);
  float* hsbuf  = (float*)alloc((size_t)NTOT*1536*4);
  u16* blended  = (u16*)alloc((size_t)2048*1536*2);
  u16* hstxt    = (u16*)alloc((size_t)154*1536*2);

  const long padn8 = ((long)(NPAD - NTOT) * 1536) / 8;   // 19584
  k_zeropad<<<dim3((padn8 + 255) / 256), 256, 0, stream>>>(
      q2 + (size_t)NTOT*1536, k2 + (size_t)NTOT*1536, v2 + (size_t)NTOT*1536, padn8);

  k_cast<<<dim3(3072), 256, 0, stream>>>(hs,   hs_bf,  (long)2048*1536);
  k_cast<<<dim3(231),  256, 0, stream>>>(enc,  enc_bf, (long)154*1536);
  k_cast<<<dim3(256),  256, 0, stream>>>(pics, pics_bf,(long)256*1024);

  WT10 wts;
  wts.w[0] = {Wq,   WqT,   1536};
  wts.w[1] = {Wk,   WkT,   1536};
  wts.w[2] = {Wv,   WvT,   1536};
  wts.w[3] = {Waq,  WaqT,  1536};
  wts.w[4] = {Wak,  WakT,  1536};
  wts.w[5] = {Wav,  WavT,  1536};
  wts.w[6] = {Wout, WoutT, 1536};
  wts.w[7] = {Wadd, WaddT, 1536};
  wts.w[8] = {Wkl,  WklT,  1024};
  wts.w[9] = {Wvl,  WvlT,  1024};
  k_transpose_w<<<dim3(48, 48, 10), dim3(32, 8), 0, stream>>>(wts);

  // QKV: 576 blocks, region swizzle 8 rows x 9 cols per XCD (nCx=4)
  GOuts oqkv; oqkv.C[0] = q2; oqkv.C[1] = k2; oqkv.C[2] = v2;
  oqkv.b[0] = bq; oqkv.b[1] = bk; oqkv.b[2] = bv;
  k_gemm<0><<<dim3(576), 256, 0, stream>>>(hs_bf, 1536, WqT, 1536, oqkv, 1536, 2048, 4608, 1536, 36, 4, 8, 9);

  GOuts oenc; oenc.C[0] = q2 + (size_t)2048*1536; oenc.C[1] = k2 + (size_t)2048*1536; oenc.C[2] = v2 + (size_t)2048*1536;
  oenc.b[0] = baq; oenc.b[1] = bak; oenc.b[2] = bav;
  k_gemm<0><<<dim3(36, 2), 256, 0, stream>>>(enc_bf, 1536, WaqT, 1536, oenc, 1536, 154, 4608, 1536, 0, 0, 0, 0);

  GOuts okv; okv.C[0] = Kp; okv.C[1] = Vp; okv.C[2] = nullptr;
  okv.b[0] = nullptr; okv.b[1] = nullptr; okv.b[2] = nullptr;
  k_gemm<0><<<dim3(24, 2), 256, 0, stream>>>(pics_bf, 1024, WklT, 1024, okv, 1536, 256, 3072, 1024, 0, 0, 0, 0);

  k_wvec<<<dim3(6), 256, 0, stream>>>(Kp, Wsl, wvec);

  k_transpose_vp<<<dim3(48, NPAD/32), dim3(32, 8), 0, stream>>>(v2, v2P, NPAD, 1536);
  k_transpose_vp<<<dim3(48, 8),       dim3(32, 8), 0, stream>>>(Vp, VpP, 256, 1536);

  k_cross_attn<<<dim3(32, 24), 256, 0, stream>>>(q2, Kp, VpP, clip, Wsl, bsl, wvec, multi);
  k_self_attn<<<dim3(840), 256, 0, stream>>>(q2, k2, v2P, hsbuf);

  k_adaptive<<<dim3(512), 256, 0, stream>>>(multi, hsbuf, Wad, bad, blended);
  k_cast<<<dim3(231), 256, 0, stream>>>(hsbuf + (size_t)2048*1536, hstxt, (long)154*1536);

  // Wout: 192 blocks, region swizzle 4 rows x 6 cols per XCD (nCx=2)
  GOuts oout; oout.C[0] = d_out; oout.C[1] = nullptr; oout.C[2] = nullptr;
  oout.b[0] = bout; oout.b[1] = nullptr; oout.b[2] = nullptr;
  k_gemm<1><<<dim3(192), 256, 0, stream>>>(blended, 1536, WoutT, 1536, oout, 1536, 2048, 1536, 1536, 12, 2, 4, 6);

  GOuts oadd; oadd.C[0] = (float*)d_out + (size_t)2048*1536; oadd.C[1] = nullptr; oadd.C[2] = nullptr;
  oadd.b[0] = badd; oadd.b[1] = nullptr; oadd.b[2] = nullptr;
  k_gemm<1><<<dim3(12, 2), 256, 0, stream>>>(hstxt, 1536, WaddT, 1536, oadd, 1536, 154, 1536, 1536, 0, 0, 0, 0);
}

// Round 10
// 399.890 us; speedup vs baseline: 1.1329x; 1.1329x over previous
//
#include <hip/hip_runtime.h>

typedef unsigned short u16;
typedef unsigned int u32;
typedef __attribute__((ext_vector_type(4))) short bf16x4;
typedef __attribute__((ext_vector_type(8))) short bf16x8;
typedef __attribute__((ext_vector_type(4))) float f32x4;

#define SCALE 0.125f
#define BLENDF 0.4875f
#define NTOT 2202
#define NPAD 2304
#define L2E 1.44269504f

#define SBAR()  __builtin_amdgcn_s_barrier()
#define SCHED0() __builtin_amdgcn_sched_barrier(0)
#define VMWAIT(n) asm volatile("s_waitcnt vmcnt(" #n ")" ::: "memory")

__device__ __forceinline__ u16 f2bf(float x){
  union { float f; unsigned u; } v; v.f = x;
  unsigned r = v.u + 0x7fffu + ((v.u >> 16) & 1u);
  return (u16)(r >> 16);
}
__device__ __forceinline__ float bf2f(u16 b){
  union { unsigned u; float f; } v; v.u = (u32)b << 16; return v.f;
}

__device__ __forceinline__ float fexp2(float x){
#if __has_builtin(__builtin_amdgcn_exp2f)
  return __builtin_amdgcn_exp2f(x);
#else
  return __expf(x * 0.6931472f);
#endif
}

__device__ __forceinline__ f32x4 MFMA(bf16x8 a, bf16x8 b, f32x4 c){
  return __builtin_amdgcn_mfma_f32_16x16x32_bf16(a, b, c, 0, 0, 0);
}

// async global->LDS, 16B per lane; LDS dest is wave-uniform base (+lane*16 implicit)
__device__ __forceinline__ void gload16(const u16* g, u16* l){
  __builtin_amdgcn_global_load_lds(
    (const __attribute__((address_space(1))) u32*)g,
    (__attribute__((address_space(3))) u32*)l, 16, 0, 0);
}

__device__ __forceinline__ float red64_sum(float x){
  x += __shfl_xor(x, 1, 64);
  x += __shfl_xor(x, 2, 64);
  x += __shfl_xor(x, 4, 64);
  x += __shfl_xor(x, 8, 64);
  x += __shfl_xor(x, 16, 64);
  x += __shfl_xor(x, 32, 64);
  return x;
}
// reduce over the l4 axis (lanes sharing the same lane&15)
__device__ __forceinline__ float redl4_sum(float x){
  x += __shfl_xor(x, 16, 64);
  x += __shfl_xor(x, 32, 64);
  return x;
}
__device__ __forceinline__ float redl4_max(float x){
  x = fmaxf(x, __shfl_xor(x, 16, 64));
  x = fmaxf(x, __shfl_xor(x, 32, 64));
  return x;
}

// ---------------- utility kernels ----------------

__global__ void k_zeropad(u16* __restrict__ a, u16* __restrict__ b,
                          u16* __restrict__ c, long n8){
  long i = (long)blockIdx.x * blockDim.x + threadIdx.x;
  if (i < n8){
    const bf16x8 z = {0,0,0,0,0,0,0,0};
    *(bf16x8*)(a + i*8) = z;
    *(bf16x8*)(b + i*8) = z;
    *(bf16x8*)(c + i*8) = z;
  }
}

__global__ void k_cast(const float* __restrict__ in, u16* __restrict__ out, long n){
  long i = ((long)blockIdx.x * blockDim.x + threadIdx.x) * 4;
  long stride = (long)gridDim.x * blockDim.x * 4;
  for (; i < n; i += stride){
    float4 f = *(const float4*)(in + i);
    bf16x4 v = { (short)f2bf(f.x), (short)f2bf(f.y), (short)f2bf(f.z), (short)f2bf(f.w) };
    *(bf16x4*)(out + i) = v;
  }
}

// w_vec[d] = sum_k Wsl[k] * Kp[k][d]  (rank-1 gate precompute)
__global__ __launch_bounds__(256) void k_wvec(const u16* __restrict__ Kp,
                                              const float* __restrict__ Wsl,
                                              float* __restrict__ wvec){
  const int d = blockIdx.x * 256 + threadIdx.x;
  float acc = 0.f;
  for (int k = 0; k < 256; ++k)
    acc += Wsl[k] * bf2f(Kp[(size_t)k * 1536 + d]);
  wvec[d] = acc;
}

struct WT { const float* s; u16* d; int K; };
struct WT10 { WT w[10]; };

// in: [K][1536] fp32 -> out: [1536][K] bf16
__global__ __launch_bounds__(256) void k_transpose_w(WT10 ws){
  const WT t = ws.w[blockIdx.z];
  const int r0 = blockIdx.y * 32;
  if (r0 >= t.K) return;
  const int c0 = blockIdx.x * 32;
  __shared__ float tile[32][33];
  const int x = threadIdx.x, y = threadIdx.y;
  #pragma unroll
  for (int k = 0; k < 4; ++k)
    tile[y + 8*k][x] = t.s[(size_t)(r0 + y + 8*k) * 1536 + c0 + x];
  __syncthreads();
  #pragma unroll
  for (int k = 0; k < 4; ++k)
    t.d[(size_t)(c0 + y + 8*k) * t.K + r0 + x] = f2bf(tile[x][y + 8*k]);
}

// in: [R][C] bf16 -> out[C][R] bf16 with columns PERMUTED within each 32-block:
// out[d][32b + p] = in[32b + k(p)][d], k(p) = ((p>>2)&1)*16 + (p>>3)*4 + (p&3)
// == MFMA k-slot map pi(l4,j) at p = l4*8+j -> a 16B read at col l4*8 is the B-fragment.
__global__ __launch_bounds__(256) void k_transpose_vp(const u16* __restrict__ in,
                                                      u16* __restrict__ out, int R, int C){
  const int r0 = blockIdx.y * 32, c0 = blockIdx.x * 32;
  __shared__ u16 tile[32][34];
  const int x = threadIdx.x, y = threadIdx.y;
  #pragma unroll
  for (int k = 0; k < 4; ++k)
    tile[y + 8*k][x] = in[(size_t)(r0 + y + 8*k) * C + c0 + x];
  __syncthreads();
  const int kx = (((x >> 2) & 1) << 4) + ((x >> 3) << 2) + (x & 3);
  #pragma unroll
  for (int k = 0; k < 4; ++k)
    out[(size_t)(c0 + y + 8*k) * R + r0 + x] = tile[kx][y + 8*k];
}

// ---------------- GEMM: C = A[M][K] * BT[N][K]^T, fused N-segments ----------------
// BM x 128 tile, fragment-major LDS chunks (conflict-free), single 24-32KB buffer.
// BM=64 doubles the grid vs 128 -> 4.5 blocks/CU for QKV (m102: blocks/CU is the
// dominant factor in this regime; 1/CU=320 TF, 4/CU=833 TF).

struct GOuts { void* C[3]; const float* b[3]; };

template<int BM, int OUTF32>
__global__ __launch_bounds__(256, 4) void k_gemm(
  const u16* __restrict__ A, int lda,
  const u16* __restrict__ BT, int ldb,
  GOuts o, int ldc, int M, int N, int K,
  int gx, int nCx, int rBlk, int cBlk)
{
  constexpr int MW  = BM / 32;          // acc row-blocks per wave
  constexpr int ACW = BM / 32;          // A chunks staged per wave (= (BM/16)*2/4)
  __shared__ alignas(1024) u16 As[BM * 64];
  __shared__ alignas(1024) u16 Bs[128 * 64];
  const int tid = threadIdx.x, lane = tid & 63, w = tid >> 6;
  const int l15 = lane & 15, l4 = lane >> 4;

  int bx, by;
  if (gx){
    const int xcd = blockIdx.x & 7, slot = blockIdx.x >> 3;
    const int rx = xcd / nCx, cx = xcd - rx * nCx;
    by = rx * rBlk + slot / cBlk;
    bx = cx * cBlk + slot % cBlk;
  } else {
    bx = blockIdx.x; by = blockIdx.y;
  }
  const int m0 = by * BM, n0 = bx * 128;
  const int wm = (w >> 1) * (BM / 2), wn = (w & 1) * 64;

  f32x4 acc[MW][4];
  #pragma unroll
  for (int i = 0; i < MW; ++i)
    #pragma unroll
    for (int j = 0; j < 4; ++j)
      acc[i][j] = (f32x4){0.f, 0.f, 0.f, 0.f};

  for (int k0 = 0; k0 < K; k0 += 64){
    #pragma unroll
    for (int c = 0; c < ACW; ++c){
      const int id = w * ACW + c;                 // A chunk id = rb*2 + kk
      const int gcol = k0 + (id & 1)*32 + l4*8;
      const int ar = min(m0 + (id >> 1)*16 + l15, M - 1);
      gload16(A + (size_t)ar * lda + gcol, &As[id * 512]);
    }
    #pragma unroll
    for (int c = 0; c < 4; ++c){
      const int id = w * 4 + c;                   // B chunk id = nb*2 + kk
      const int gcol = k0 + (id & 1)*32 + l4*8;
      const int br = min(n0 + (id >> 1)*16 + l15, N - 1);
      gload16(BT + (size_t)br * ldb + gcol, &Bs[id * 512]);
    }
    VMWAIT(0);
    __syncthreads();
    #pragma unroll
    for (int kk = 0; kk < 2; ++kk){
      bf16x8 a[MW], b[4];
      #pragma unroll
      for (int m = 0; m < MW; ++m)
        a[m] = *(const bf16x8*)(As + ((((w>>1)*MW + m)*2 + kk) * 512) + lane*8);
      #pragma unroll
      for (int n = 0; n < 4; ++n)
        b[n] = *(const bf16x8*)(Bs + ((((w&1)*4 + n)*2 + kk) * 512) + lane*8);
      #pragma unroll
      for (int m = 0; m < MW; ++m)
        #pragma unroll
        for (int n = 0; n < 4; ++n)
          acc[m][n] = MFMA(a[m], b[n], acc[m][n]);
    }
    __syncthreads();
  }

  #pragma unroll
  for (int n = 0; n < 4; ++n){
    const int colg = n0 + wn + n*16 + l15;
    const int sel = colg / 1536;
    const int col = colg - sel * 1536;
    const float* bp = o.b[sel];
    const float bi = bp ? bp[col] : 0.f;
    #pragma unroll
    for (int m = 0; m < MW; ++m){
      const int row0 = m0 + wm + m*16 + l4*4;
      #pragma unroll
      for (int r = 0; r < 4; ++r){
        const int row = row0 + r;
        if (row < M){
          float val = acc[m][n][r] + bi;
          if (OUTF32) ((float*)o.C[sel])[(size_t)row * ldc + col] = val;
          else        ((u16*)o.C[sel])[(size_t)row * ldc + col] = f2bf(val);
        }
      }
    }
  }
}

// ---------------- cross attention: flash-style, rank-1 gate, counted vmcnt ----------------

__global__ __launch_bounds__(256, 4) void k_cross_attn(
  const u16* __restrict__ Q,     // [*, 1536], rows 0..2047 used
  const u16* __restrict__ Kp,    // [256][1536]
  const u16* __restrict__ VpP,   // [1536][256], cols pi-permuted per 32-block
  const float* __restrict__ clip,
  const float* __restrict__ Wsl, // [512]
  const float* __restrict__ bslp,
  const float* __restrict__ wvec,// [1536]
  float* __restrict__ multi)     // [2048][1536]
{
  const int h = blockIdx.y;
  const int tid = threadIdx.x, lane = tid & 63, w = tid >> 6;
  const int l15 = lane & 15, l4 = lane >> 4;
  const int qrow = blockIdx.x * 64 + w * 16 + l15;

  __shared__ alignas(1024) u16 Ks[2][4096];
  __shared__ alignas(1024) u16 VTs[2][4096];
  __shared__ float clip_l[256];
  if (tid < 256) clip_l[tid] = clip[tid];

  float cd = 0.f;
  for (int p = lane; p < 256; p += 64) cd += clip[p] * Wsl[256 + p];
  cd = red64_sum(cd);
  const float gate_c = cd + bslp[0];

  bf16x8 qf[2];
  #pragma unroll
  for (int kk = 0; kk < 2; ++kk)
    qf[kk] = *(const bf16x8*)(Q + (size_t)qrow * 1536 + h*64 + kk*32 + l4*8);

  // gate = SCALE * (w_h . q_row) + gate_c   (per q = l15; sum over l4 axis)
  float gd = 0.f;
  #pragma unroll
  for (int kk = 0; kk < 2; ++kk){
    const float4 w0 = *(const float4*)(wvec + h*64 + kk*32 + l4*8);
    const float4 w1 = *(const float4*)(wvec + h*64 + kk*32 + l4*8 + 4);
    gd += w0.x * bf2f((u16)qf[kk][0]) + w0.y * bf2f((u16)qf[kk][1]);
    gd += w0.z * bf2f((u16)qf[kk][2]) + w0.w * bf2f((u16)qf[kk][3]);
    gd += w1.x * bf2f((u16)qf[kk][4]) + w1.y * bf2f((u16)qf[kk][5]);
    gd += w1.z * bf2f((u16)qf[kk][6]) + w1.w * bf2f((u16)qf[kk][7]);
  }
  const float gate = SCALE * redl4_sum(gd) + gate_c;

  f32x4 O[4];
  #pragma unroll
  for (int nb = 0; nb < 4; ++nb) O[nb] = (f32x4){0.f, 0.f, 0.f, 0.f};
  float m_ = -1e30f, l_ = 0.f;

  auto STAGE = [&](int buf, int kt0){
    #pragma unroll
    for (int c = 0; c < 2; ++c){
      gload16(Kp + (size_t)(kt0 + w*16 + l15) * 1536 + h*64 + c*32 + l4*8,
              &Ks[buf][(w*2 + c) * 512]);
      gload16(VpP + (size_t)(h*64 + w*16 + l15) * 256 + kt0 + c*32 + l4*8,
              &VTs[buf][(w*2 + c) * 512]);
    }
  };

  STAGE(0, 0);
  __syncthreads();                      // prologue drain + clip_l visibility

  int buf = 0;
  for (int nt = 0; nt < 4; ++nt){
    if (nt + 1 < 4){
      STAGE(buf ^ 1, (nt + 1) * 64);
      VMWAIT(4);
    } else {
      VMWAIT(0);
    }
    SCHED0();
    SBAR();
    SCHED0();
    const int kt0 = nt * 64;

    f32x4 s[4];
    __builtin_amdgcn_s_setprio(1);
    #pragma unroll
    for (int n4 = 0; n4 < 4; ++n4){
      f32x4 t = {0.f, 0.f, 0.f, 0.f};
      #pragma unroll
      for (int kk = 0; kk < 2; ++kk){
        bf16x8 kf = *(const bf16x8*)(&Ks[buf][(n4*2 + kk) * 512 + lane*8]);
        t = MFMA(kf, qf[kk], t);
      }
      s[n4] = t;
    }
    __builtin_amdgcn_s_setprio(0);

    // bias: s = S*SCALE + gate*clip[key], key = kt0 + n4*16 + l4*4 + r
    #pragma unroll
    for (int n4 = 0; n4 < 4; ++n4){
      const float4 cv = *(const float4*)&clip_l[kt0 + n4*16 + l4*4];
      s[n4][0] = fmaf(s[n4][0], SCALE, gate * cv.x);
      s[n4][1] = fmaf(s[n4][1], SCALE, gate * cv.y);
      s[n4][2] = fmaf(s[n4][2], SCALE, gate * cv.z);
      s[n4][3] = fmaf(s[n4][3], SCALE, gate * cv.w);
    }

    float mt = -1e30f;
    #pragma unroll
    for (int n4 = 0; n4 < 4; ++n4)
      mt = fmaxf(mt, fmaxf(fmaxf(s[n4][0], s[n4][1]), fmaxf(s[n4][2], s[n4][3])));
    mt = redl4_max(mt);

    const float mn = fmaxf(m_, mt);
    const float al = fexp2((m_ - mn) * L2E);
    m_ = mn;
    l_ *= al;
    float alo[4];
    #pragma unroll
    for (int r = 0; r < 4; ++r) alo[r] = __shfl(al, l4*4 + r, 16);
    #pragma unroll
    for (int nb = 0; nb < 4; ++nb)
      #pragma unroll
      for (int r = 0; r < 4; ++r) O[nb][r] *= alo[r];

    const float m2 = m_ * L2E;
    u16 pb[16];
    float ls = 0.f;
    #pragma unroll
    for (int n4 = 0; n4 < 4; ++n4)
      #pragma unroll
      for (int r = 0; r < 4; ++r){
        float pv = fexp2(fmaf(s[n4][r], L2E, -m2));
        ls += pv;
        pb[n4*4 + r] = f2bf(pv);
      }
    l_ += redl4_sum(ls);

    __builtin_amdgcn_s_setprio(1);
    #pragma unroll
    for (int kk = 0; kk < 2; ++kk){
      bf16x8 pa = { (short)pb[kk*8+0], (short)pb[kk*8+1], (short)pb[kk*8+2], (short)pb[kk*8+3],
                    (short)pb[kk*8+4], (short)pb[kk*8+5], (short)pb[kk*8+6], (short)pb[kk*8+7] };
      #pragma unroll
      for (int nb = 0; nb < 4; ++nb){
        bf16x8 vt = *(const bf16x8*)(&VTs[buf][(nb*2 + kk) * 512 + lane*8]);
        O[nb] = MFMA(pa, vt, O[nb]);
      }
    }
    __builtin_amdgcn_s_setprio(0);

    SCHED0();
    SBAR();
    buf ^= 1;
  }

  const float inv = 1.f / l_;
  float li[4];
  #pragma unroll
  for (int r = 0; r < 4; ++r) li[r] = __shfl(inv, l4*4 + r, 16);
  #pragma unroll
  for (int r = 0; r < 4; ++r){
    const int row = blockIdx.x * 64 + w * 16 + l4*4 + r;
    #pragma unroll
    for (int nb = 0; nb < 4; ++nb)
      multi[(size_t)row * 1536 + h*64 + nb*16 + l15] = O[nb][r] * li[r];
  }
}

// ---------------- self attention (flash, swapped QK^T, counted-vmcnt dbuf) ----------------

__global__ __launch_bounds__(256, 4) void k_self_attn(
  const u16* __restrict__ q2,   // [2304][1536]
  const u16* __restrict__ k2,   // [2304][1536]
  const u16* __restrict__ v2P,  // [1536][2304], cols pi-permuted per 32-block
  float* __restrict__ hsout)    // [2202][1536]
{
  const int p = blockIdx.x;
  const int h  = (p & 7) * 3 + (p >> 3) / 35;
  const int qb = (p >> 3) % 35;
  const int tid = threadIdx.x, lane = tid & 63, w = tid >> 6;
  const int l15 = lane & 15, l4 = lane >> 4;
  const int qrow = qb * 64 + w * 16 + l15;

  __shared__ alignas(1024) u16 Ks[2][4096];
  __shared__ alignas(1024) u16 VTs[2][4096];

  bf16x8 qf[2];
  #pragma unroll
  for (int kk = 0; kk < 2; ++kk)
    qf[kk] = *(const bf16x8*)(q2 + (size_t)qrow * 1536 + h*64 + kk*32 + l4*8);

  f32x4 O[4];
  #pragma unroll
  for (int nb = 0; nb < 4; ++nb) O[nb] = (f32x4){0.f, 0.f, 0.f, 0.f};
  float m_ = -1e30f, l_ = 0.f;
  const float C2 = SCALE * L2E;
  const float THR = 44.36f;             // 8 / C2

  const u16* kp  = k2 + h*64;
  const u16* vp0 = v2P + (size_t)(h*64) * NPAD;

  auto STAGE = [&](int buf, int kt0){
    #pragma unroll
    for (int c = 0; c < 2; ++c){
      gload16(kp + (size_t)(kt0 + w*16 + l15) * 1536 + c*32 + l4*8,
              &Ks[buf][(w*2 + c) * 512]);
      gload16(vp0 + (size_t)(w*16 + l15) * NPAD + kt0 + c*32 + l4*8,
              &VTs[buf][(w*2 + c) * 512]);
    }
  };

  STAGE(0, 0);
  __syncthreads();                      // prologue drain (once)

  int buf = 0;
  for (int nt = 0; nt < 35; ++nt){
    if (nt + 1 < 35){
      STAGE(buf ^ 1, (nt + 1) * 64);
      VMWAIT(4);
    } else {
      VMWAIT(0);
    }
    SCHED0();
    SBAR();
    SCHED0();
    const int kt0 = nt * 64;

    f32x4 s[4];
    __builtin_amdgcn_s_setprio(1);
    #pragma unroll
    for (int n4 = 0; n4 < 4; ++n4){
      f32x4 t = {0.f, 0.f, 0.f, 0.f};
      #pragma unroll
      for (int kk = 0; kk < 2; ++kk){
        bf16x8 kf = *(const bf16x8*)(&Ks[buf][(n4*2 + kk) * 512 + lane*8]);
        t = MFMA(kf, qf[kk], t);
      }
      s[n4] = t;
    }
    __builtin_amdgcn_s_setprio(0);

    if (kt0 + 64 > NTOT){                       // only the last tile
      #pragma unroll
      for (int n4 = 0; n4 < 4; ++n4){
        const int keyb = kt0 + n4*16 + l4*4;
        #pragma unroll
        for (int r = 0; r < 4; ++r)
          if (keyb + r >= NTOT) s[n4][r] = -1e30f;
      }
    }

    float mt = -1e30f;
    #pragma unroll
    for (int n4 = 0; n4 < 4; ++n4)
      mt = fmaxf(mt, fmaxf(fmaxf(s[n4][0], s[n4][1]), fmaxf(s[n4][2], s[n4][3])));
    mt = redl4_max(mt);

    if (__any(mt > m_ + THR)){                  // T13 defer-max
      const float mn = fmaxf(m_, mt);
      const float al = fexp2((m_ - mn) * C2);
      m_ = mn;
      l_ *= al;
      float alo[4];
      #pragma unroll
      for (int r = 0; r < 4; ++r) alo[r] = __shfl(al, l4*4 + r, 16);
      #pragma unroll
      for (int nb = 0; nb < 4; ++nb)
        #pragma unroll
        for (int r = 0; r < 4; ++r) O[nb][r] *= alo[r];
    }
    const float m2 = m_ * C2;

    u16 pb[16];
    float ls = 0.f;
    #pragma unroll
    for (int n4 = 0; n4 < 4; ++n4)
      #pragma unroll
      for (int r = 0; r < 4; ++r){
        float pv = fexp2(fmaf(s[n4][r], C2, -m2));
        ls += pv;
        pb[n4*4 + r] = f2bf(pv);
      }
    l_ += redl4_sum(ls);

    __builtin_amdgcn_s_setprio(1);
    #pragma unroll
    for (int kk = 0; kk < 2; ++kk){
      bf16x8 pa = { (short)pb[kk*8+0], (short)pb[kk*8+1], (short)pb[kk*8+2], (short)pb[kk*8+3],
                    (short)pb[kk*8+4], (short)pb[kk*8+5], (short)pb[kk*8+6], (short)pb[kk*8+7] };
      #pragma unroll
      for (int nb = 0; nb < 4; ++nb){
        bf16x8 vt = *(const bf16x8*)(&VTs[buf][(nb*2 + kk) * 512 + lane*8]);
        O[nb] = MFMA(pa, vt, O[nb]);
      }
    }
    __builtin_amdgcn_s_setprio(0);

    SCHED0();
    SBAR();
    buf ^= 1;
  }

  const float inv = 1.f / l_;
  float li[4];
  #pragma unroll
  for (int r = 0; r < 4; ++r) li[r] = __shfl(inv, l4*4 + r, 16);
  #pragma unroll
  for (int r = 0; r < 4; ++r){
    const int row = qb * 64 + w * 16 + l4*4 + r;
    if (row < NTOT){
      #pragma unroll
      for (int nb = 0; nb < 4; ++nb)
        hsout[(size_t)row * 1536 + h*64 + nb*16 + l15] = O[nb][r] * li[r];
    }
  }
}

// ---------------- adaptive gate + blend ----------------

__global__ __launch_bounds__(256) void k_adaptive(
  const float* __restrict__ multi, const float* __restrict__ hsbuf,
  const float* __restrict__ Wad, const float* __restrict__ badp,
  u16* __restrict__ blended)
{
  const int lane = threadIdx.x & 63, wid = threadIdx.x >> 6;
  const int q = blockIdx.x * 4 + wid;
  const float* mrow = multi + (size_t)q * 1536;
  const float* hrow = hsbuf + (size_t)q * 1536;
  float acc = 0.f;
  #pragma unroll
  for (int i = 0; i < 24; ++i){
    int d = lane + 64 * i;
    acc += mrow[d] * Wad[d] + hrow[d] * Wad[1536 + d];
  }
  acc = red64_sum(acc) + badp[0];
  const float sig = 1.f / (1.f + __expf(-acc));
  const float f = BLENDF * sig;
  u16* brow = blended + (size_t)q * 1536;
  #pragma unroll
  for (int i = 0; i < 24; ++i){
    int d = lane + 64 * i;
    brow[d] = f2bf(f * mrow[d] + hrow[d]);
  }
}

// ---------------- launch ----------------

extern "C" void kernel_launch(void* const* d_in, const int* in_sizes, int n_in,
                              void* d_out, int out_size, void* d_ws, size_t ws_size,
                              hipStream_t stream)
{
  (void)in_sizes; (void)n_in; (void)out_size; (void)ws_size;
  const float* hs   = (const float*)d_in[0];
  const float* enc  = (const float*)d_in[1];
  const float* pics = (const float*)d_in[2];
  const float* clip = (const float*)d_in[3];
  const float* Wq   = (const float*)d_in[4];  const float* bq   = (const float*)d_in[5];
  const float* Wk   = (const float*)d_in[6];  const float* bk   = (const float*)d_in[7];
  const float* Wv   = (const float*)d_in[8];  const float* bv   = (const float*)d_in[9];
  const float* Waq  = (const float*)d_in[10]; const float* baq  = (const float*)d_in[11];
  const float* Wak  = (const float*)d_in[12]; const float* bak  = (const float*)d_in[13];
  const float* Wav  = (const float*)d_in[14]; const float* bav  = (const float*)d_in[15];
  const float* Wkl  = (const float*)d_in[16]; const float* Wvl  = (const float*)d_in[17];
  const float* Wsl  = (const float*)d_in[18]; const float* bsl  = (const float*)d_in[19];
  const float* Wad  = (const float*)d_in[20]; const float* bad  = (const float*)d_in[21];
  const float* Wout = (const float*)d_in[22]; const float* bout = (const float*)d_in[23];
  const float* Wadd = (const float*)d_in[24]; const float* badd = (const float*)d_in[25];

  char* ws = (char*)d_ws;
  size_t off = 0;
  auto alloc = [&](size_t b){ void* p = ws + off; off += (b + 255) & ~(size_t)255; return p; };

  u16* hs_bf  = (u16*)alloc((size_t)2048*1536*2);
  u16* enc_bf = (u16*)alloc((size_t)154*1536*2);
  u16* pics_bf= (u16*)alloc((size_t)256*1024*2);
  u16* WqT  = (u16*)alloc((size_t)1536*1536*2);
  u16* WkT  = (u16*)alloc((size_t)1536*1536*2);
  u16* WvT  = (u16*)alloc((size_t)1536*1536*2);
  u16* WaqT = (u16*)alloc((size_t)1536*1536*2);
  u16* WakT = (u16*)alloc((size_t)1536*1536*2);
  u16* WavT = (u16*)alloc((size_t)1536*1536*2);
  u16* WoutT= (u16*)alloc((size_t)1536*1536*2);
  u16* WaddT= (u16*)alloc((size_t)1536*1536*2);
  u16* WklT = (u16*)alloc((size_t)1536*1024*2);
  u16* WvlT = (u16*)alloc((size_t)1536*1024*2);
  u16* q2   = (u16*)alloc((size_t)NPAD*1536*2);
  u16* k2   = (u16*)alloc((size_t)NPAD*1536*2);
  u16* v2   = (u16*)alloc((size_t)NPAD*1536*2);
  u16* v2P  = (u16*)alloc((size_t)1536*NPAD*2);
  u16* Kp   = (u16*)alloc((size_t)256*1536*2);
  u16* Vp   = (u16*)alloc((size_t)256*1536*2);
  u16* VpP  = (u16*)alloc((size_t)1536*256*2);
  float* wvec   = (float*)alloc((size_t)1536*4);
  float* multi  = (float*)alloc((size_t)2048*1536*4);
  float* hsbuf  = (float*)alloc((size_t)NTOT*1536*4);
  u16* blended  = (u16*)alloc((size_t)2048*1536*2);
  u16* hstxt    = (u16*)alloc((size_t)154*1536*2);

  const long padn8 = ((long)(NPAD - NTOT) * 1536) / 8;   // 19584
  k_zeropad<<<dim3((padn8 + 255) / 256), 256, 0, stream>>>(
      q2 + (size_t)NTOT*1536, k2 + (size_t)NTOT*1536, v2 + (size_t)NTOT*1536, padn8);

  k_cast<<<dim3(3072), 256, 0, stream>>>(hs,   hs_bf,  (long)2048*1536);
  k_cast<<<dim3(231),  256, 0, stream>>>(enc,  enc_bf, (long)154*1536);
  k_cast<<<dim3(256),  256, 0, stream>>>(pics, pics_bf,(long)256*1024);

  WT10 wts;
  wts.w[0] = {Wq,   WqT,   1536};
  wts.w[1] = {Wk,   WkT,   1536};
  wts.w[2] = {Wv,   WvT,   1536};
  wts.w[3] = {Waq,  WaqT,  1536};
  wts.w[4] = {Wak,  WakT,  1536};
  wts.w[5] = {Wav,  WavT,  1536};
  wts.w[6] = {Wout, WoutT, 1536};
  wts.w[7] = {Wadd, WaddT, 1536};
  wts.w[8] = {Wkl,  WklT,  1024};
  wts.w[9] = {Wvl,  WvlT,  1024};
  k_transpose_w<<<dim3(48, 48, 10), dim3(32, 8), 0, stream>>>(wts);

  // QKV: 64x128 tiles -> 32x36 = 1152 blocks (4.5/CU); region 16x9 per XCD (nCx=4)
  GOuts oqkv; oqkv.C[0] = q2; oqkv.C[1] = k2; oqkv.C[2] = v2;
  oqkv.b[0] = bq; oqkv.b[1] = bk; oqkv.b[2] = bv;
  k_gemm<64,0><<<dim3(1152), 256, 0, stream>>>(hs_bf, 1536, WqT, 1536, oqkv, 1536, 2048, 4608, 1536, 1, 4, 16, 9);

  GOuts oenc; oenc.C[0] = q2 + (size_t)2048*1536; oenc.C[1] = k2 + (size_t)2048*1536; oenc.C[2] = v2 + (size_t)2048*1536;
  oenc.b[0] = baq; oenc.b[1] = bak; oenc.b[2] = bav;
  k_gemm<64,0><<<dim3(36, 3), 256, 0, stream>>>(enc_bf, 1536, WaqT, 1536, oenc, 1536, 154, 4608, 1536, 0, 0, 0, 0);

  GOuts okv; okv.C[0] = Kp; okv.C[1] = Vp; okv.C[2] = nullptr;
  okv.b[0] = nullptr; okv.b[1] = nullptr; okv.b[2] = nullptr;
  k_gemm<64,0><<<dim3(24, 4), 256, 0, stream>>>(pics_bf, 1024, WklT, 1024, okv, 1536, 256, 3072, 1024, 0, 0, 0, 0);

  k_wvec<<<dim3(6), 256, 0, stream>>>(Kp, Wsl, wvec);

  k_transpose_vp<<<dim3(48, NPAD/32), dim3(32, 8), 0, stream>>>(v2, v2P, NPAD, 1536);
  k_transpose_vp<<<dim3(48, 8),       dim3(32, 8), 0, stream>>>(Vp, VpP, 256, 1536);

  k_cross_attn<<<dim3(32, 24), 256, 0, stream>>>(q2, Kp, VpP, clip, Wsl, bsl, wvec, multi);
  k_self_attn<<<dim3(840), 256, 0, stream>>>(q2, k2, v2P, hsbuf);

  k_adaptive<<<dim3(512), 256, 0, stream>>>(multi, hsbuf, Wad, bad, blended);
  k_cast<<<dim3(231), 256, 0, stream>>>(hsbuf + (size_t)2048*1536, hstxt, (long)154*1536);

  // Wout: 64x128 tiles -> 32x12 = 384 blocks; region 8x6 per XCD (nCx=2)
  GOuts oout; oout.C[0] = d_out; oout.C[1] = nullptr; oout.C[2] = nullptr;
  oout.b[0] = bout; oout.b[1] = nullptr; oout.b[2] = nullptr;
  k_gemm<64,1><<<dim3(384), 256, 0, stream>>>(blended, 1536, WoutT, 1536, oout, 1536, 2048, 1536, 1536, 1, 2, 8, 6);

  GOuts oadd; oadd.C[0] = (float*)d_out + (size_t)2048*1536; oadd.C[1] = nullptr; oadd.C[2] = nullptr;
  oadd.b[0] = badd; oadd.b[1] = nullptr; oadd.b[2] = nullptr;
  k_gemm<64,1><<<dim3(12, 3), 256, 0, stream>>>(hstxt, 1536, WaddT, 1536, oadd, 1536, 154, 1536, 1536, 0, 0, 0, 0);
}

// Round 11
// 300.014 us; speedup vs baseline: 1.5101x; 1.3329x over previous
//
#include <hip/hip_runtime.h>

typedef unsigned short u16;
typedef unsigned int u32;
typedef __attribute__((ext_vector_type(4))) short bf16x4;
typedef __attribute__((ext_vector_type(8))) short bf16x8;
typedef __attribute__((ext_vector_type(4))) float f32x4;

#define SCALE 0.125f
#define BLENDF 0.4875f
#define NTOT 2202
#define NPAD 2304
#define L2E 1.44269504f

#define SBAR()  __builtin_amdgcn_s_barrier()
#define SCHED0() __builtin_amdgcn_sched_barrier(0)
#define VMWAIT(n) asm volatile("s_waitcnt vmcnt(" #n ")" ::: "memory")

__device__ __forceinline__ u16 f2bf(float x){
  union { float f; unsigned u; } v; v.f = x;
  unsigned r = v.u + 0x7fffu + ((v.u >> 16) & 1u);
  return (u16)(r >> 16);
}
__device__ __forceinline__ float bf2f(u16 b){
  union { unsigned u; float f; } v; v.u = (u32)b << 16; return v.f;
}

__device__ __forceinline__ float fexp2(float x){
#if __has_builtin(__builtin_amdgcn_exp2f)
  return __builtin_amdgcn_exp2f(x);
#else
  return __expf(x * 0.6931472f);
#endif
}

__device__ __forceinline__ f32x4 MFMA(bf16x8 a, bf16x8 b, f32x4 c){
  return __builtin_amdgcn_mfma_f32_16x16x32_bf16(a, b, c, 0, 0, 0);
}

// async global->LDS, 16B per lane; LDS dest is wave-uniform base (+lane*16 implicit)
__device__ __forceinline__ void gload16(const u16* g, u16* l){
  __builtin_amdgcn_global_load_lds(
    (const __attribute__((address_space(1))) u32*)g,
    (__attribute__((address_space(3))) u32*)l, 16, 0, 0);
}

__device__ __forceinline__ float red64_sum(float x){
  x += __shfl_xor(x, 1, 64);
  x += __shfl_xor(x, 2, 64);
  x += __shfl_xor(x, 4, 64);
  x += __shfl_xor(x, 8, 64);
  x += __shfl_xor(x, 16, 64);
  x += __shfl_xor(x, 32, 64);
  return x;
}
// reduce over the l4 axis (lanes sharing the same lane&15)
__device__ __forceinline__ float redl4_sum(float x){
  x += __shfl_xor(x, 16, 64);
  x += __shfl_xor(x, 32, 64);
  return x;
}
__device__ __forceinline__ float redl4_max(float x){
  x = fmaxf(x, __shfl_xor(x, 16, 64));
  x = fmaxf(x, __shfl_xor(x, 32, 64));
  return x;
}

// ---------------- utility kernels ----------------

__global__ void k_zeropad(u16* __restrict__ a, u16* __restrict__ b,
                          u16* __restrict__ c, long n8){
  long i = (long)blockIdx.x * blockDim.x + threadIdx.x;
  if (i < n8){
    const bf16x8 z = {0,0,0,0,0,0,0,0};
    *(bf16x8*)(a + i*8) = z;
    *(bf16x8*)(b + i*8) = z;
    *(bf16x8*)(c + i*8) = z;
  }
}

__global__ void k_cast(const float* __restrict__ in, u16* __restrict__ out, long n){
  long i = ((long)blockIdx.x * blockDim.x + threadIdx.x) * 4;
  long stride = (long)gridDim.x * blockDim.x * 4;
  for (; i < n; i += stride){
    float4 f = *(const float4*)(in + i);
    bf16x4 v = { (short)f2bf(f.x), (short)f2bf(f.y), (short)f2bf(f.z), (short)f2bf(f.w) };
    *(bf16x4*)(out + i) = v;
  }
}

// w_vec[d] = sum_k Wsl[k] * Kp[k][d]  (rank-1 gate precompute)
__global__ __launch_bounds__(256) void k_wvec(const u16* __restrict__ Kp,
                                              const float* __restrict__ Wsl,
                                              float* __restrict__ wvec){
  const int d = blockIdx.x * 256 + threadIdx.x;
  float acc = 0.f;
  for (int k = 0; k < 256; ++k)
    acc += Wsl[k] * bf2f(Kp[(size_t)k * 1536 + d]);
  wvec[d] = acc;
}

struct WT { const float* s; u16* d; int K; };
struct WT10 { WT w[10]; };

// in: [K][1536] fp32 -> out: [1536][K] bf16
__global__ __launch_bounds__(256) void k_transpose_w(WT10 ws){
  const WT t = ws.w[blockIdx.z];
  const int r0 = blockIdx.y * 32;
  if (r0 >= t.K) return;
  const int c0 = blockIdx.x * 32;
  __shared__ float tile[32][33];
  const int x = threadIdx.x, y = threadIdx.y;
  #pragma unroll
  for (int k = 0; k < 4; ++k)
    tile[y + 8*k][x] = t.s[(size_t)(r0 + y + 8*k) * 1536 + c0 + x];
  __syncthreads();
  #pragma unroll
  for (int k = 0; k < 4; ++k)
    t.d[(size_t)(c0 + y + 8*k) * t.K + r0 + x] = f2bf(tile[x][y + 8*k]);
}

// in: [R][C] bf16 -> out[C][R] bf16 with columns PERMUTED within each 32-block:
// out[d][32b + p] = in[32b + k(p)][d], k(p) = ((p>>2)&1)*16 + (p>>3)*4 + (p&3)
// == PV A-fragment k-slot map, so a contiguous read is the B-fragment.
__global__ __launch_bounds__(256) void k_transpose_vp(const u16* __restrict__ in,
                                                      u16* __restrict__ out, int R, int C){
  const int r0 = blockIdx.y * 32, c0 = blockIdx.x * 32;
  __shared__ u16 tile[32][34];
  const int x = threadIdx.x, y = threadIdx.y;
  #pragma unroll
  for (int k = 0; k < 4; ++k)
    tile[y + 8*k][x] = in[(size_t)(r0 + y + 8*k) * C + c0 + x];
  __syncthreads();
  const int kx = (((x >> 2) & 1) << 4) + ((x >> 3) << 2) + (x & 3);
  #pragma unroll
  for (int k = 0; k < 4; ++k)
    out[(size_t)(c0 + y + 8*k) * R + r0 + x] = tile[kx][y + 8*k];
}

// ---------------- GEMM: C = A[M][K] * BT[N][K]^T, fused N-segments ----------------
// Row-linear staging: each gload16 = 8 consecutive rows x 128B contiguous (8 full
// cache lines/instr, vs 16 half-lines fragment-major -> halves VMEM service).
// Both-sides XOR swizzle: source col ((l&7)^(l>>3))*16B, read ((kk*4+l4)^(row&7))*16B
// -> 2-way LDS alias (free per m136).

struct GOuts { void* C[3]; const float* b[3]; };

template<int BM, int OUTF32>
__global__ __launch_bounds__(256, 4) void k_gemm(
  const u16* __restrict__ A, int lda,
  const u16* __restrict__ BT, int ldb,
  GOuts o, int ldc, int M, int N, int K,
  int gx, int nCx, int rBlk, int cBlk)
{
  constexpr int MW = BM / 32;           // acc row-blocks per wave
  constexpr int AI = BM / 32;           // A stage-instructions per wave
  __shared__ alignas(1024) u16 As[BM * 64];
  __shared__ alignas(1024) u16 Bs[128 * 64];
  const int tid = threadIdx.x, lane = tid & 63, w = tid >> 6;
  const int l15 = lane & 15, l4 = lane >> 4;
  const int l8 = lane >> 3, l7 = lane & 7;
  const int cbE = (l7 ^ l8) * 8;        // swizzled source col, elements

  int bx, by;
  if (gx){
    const int xcd = blockIdx.x & 7, slot = blockIdx.x >> 3;
    const int rx = xcd / nCx, cx = xcd - rx * nCx;
    by = rx * rBlk + slot / cBlk;
    bx = cx * cBlk + slot % cBlk;
  } else {
    bx = blockIdx.x; by = blockIdx.y;
  }
  const int m0 = by * BM, n0 = bx * 128;
  const int wm = (w >> 1) * (BM / 2), wn = (w & 1) * 64;

  f32x4 acc[MW][4];
  #pragma unroll
  for (int i = 0; i < MW; ++i)
    #pragma unroll
    for (int j = 0; j < 4; ++j)
      acc[i][j] = (f32x4){0.f, 0.f, 0.f, 0.f};

  for (int k0 = 0; k0 < K; k0 += 64){
    #pragma unroll
    for (int c = 0; c < AI; ++c){
      const int a = w * AI + c;                   // 8-row group
      const int ar = min(m0 + a*8 + l8, M - 1);
      gload16(A + (size_t)ar * lda + k0 + cbE, &As[a * 512]);
    }
    #pragma unroll
    for (int c = 0; c < 4; ++c){
      const int b = w * 4 + c;
      const int br = min(n0 + b*8 + l8, N - 1);
      gload16(BT + (size_t)br * ldb + k0 + cbE, &Bs[b * 512]);
    }
    VMWAIT(0);
    __syncthreads();
    #pragma unroll
    for (int kk = 0; kk < 2; ++kk){
      const int sz = ((kk*4 + l4) ^ (l15 & 7)) * 8;
      bf16x8 a[MW], b[4];
      #pragma unroll
      for (int m = 0; m < MW; ++m)
        a[m] = *(const bf16x8*)(As + (wm + m*16 + l15) * 64 + sz);
      #pragma unroll
      for (int n = 0; n < 4; ++n)
        b[n] = *(const bf16x8*)(Bs + (wn + n*16 + l15) * 64 + sz);
      #pragma unroll
      for (int m = 0; m < MW; ++m)
        #pragma unroll
        for (int n = 0; n < 4; ++n)
          acc[m][n] = MFMA(a[m], b[n], acc[m][n]);
    }
    __syncthreads();
  }

  #pragma unroll
  for (int n = 0; n < 4; ++n){
    const int colg = n0 + wn + n*16 + l15;
    const int sel = colg / 1536;
    const int col = colg - sel * 1536;
    const float* bp = o.b[sel];
    const float bi = bp ? bp[col] : 0.f;
    #pragma unroll
    for (int m = 0; m < MW; ++m){
      const int row0 = m0 + wm + m*16 + l4*4;
      #pragma unroll
      for (int r = 0; r < 4; ++r){
        const int row = row0 + r;
        if (row < M){
          float val = acc[m][n][r] + bi;
          if (OUTF32) ((float*)o.C[sel])[(size_t)row * ldc + col] = val;
          else        ((u16*)o.C[sel])[(size_t)row * ldc + col] = f2bf(val);
        }
      }
    }
  }
}

// ---------------- cross attention: flash-style, rank-1 gate, row-linear staging ----------------

__global__ __launch_bounds__(256, 4) void k_cross_attn(
  const u16* __restrict__ Q,     // [*, 1536], rows 0..2047 used
  const u16* __restrict__ Kp,    // [256][1536]
  const u16* __restrict__ VpP,   // [1536][256], cols pi-permuted per 32-block
  const float* __restrict__ clip,
  const float* __restrict__ Wsl, // [512]
  const float* __restrict__ bslp,
  const float* __restrict__ wvec,// [1536]
  float* __restrict__ multi)     // [2048][1536]
{
  const int h = blockIdx.y;
  const int tid = threadIdx.x, lane = tid & 63, w = tid >> 6;
  const int l15 = lane & 15, l4 = lane >> 4;
  const int l8 = lane >> 3, l7 = lane & 7;
  const int cbE = (l7 ^ l8) * 8;
  const int qrow = blockIdx.x * 64 + w * 16 + l15;

  __shared__ alignas(1024) u16 Ks[2][4096];
  __shared__ alignas(1024) u16 VTs[2][4096];
  __shared__ float clip_l[256];
  if (tid < 256) clip_l[tid] = clip[tid];

  float cd = 0.f;
  for (int p = lane; p < 256; p += 64) cd += clip[p] * Wsl[256 + p];
  cd = red64_sum(cd);
  const float gate_c = cd + bslp[0];

  bf16x8 qf[2];
  #pragma unroll
  for (int kk = 0; kk < 2; ++kk)
    qf[kk] = *(const bf16x8*)(Q + (size_t)qrow * 1536 + h*64 + kk*32 + l4*8);

  // gate = SCALE * (w_h . q_row) + gate_c   (per q = l15; sum over l4 axis)
  float gd = 0.f;
  #pragma unroll
  for (int kk = 0; kk < 2; ++kk){
    const float4 w0 = *(const float4*)(wvec + h*64 + kk*32 + l4*8);
    const float4 w1 = *(const float4*)(wvec + h*64 + kk*32 + l4*8 + 4);
    gd += w0.x * bf2f((u16)qf[kk][0]) + w0.y * bf2f((u16)qf[kk][1]);
    gd += w0.z * bf2f((u16)qf[kk][2]) + w0.w * bf2f((u16)qf[kk][3]);
    gd += w1.x * bf2f((u16)qf[kk][4]) + w1.y * bf2f((u16)qf[kk][5]);
    gd += w1.z * bf2f((u16)qf[kk][6]) + w1.w * bf2f((u16)qf[kk][7]);
  }
  const float gate = SCALE * redl4_sum(gd) + gate_c;

  f32x4 O[4];
  #pragma unroll
  for (int nb = 0; nb < 4; ++nb) O[nb] = (f32x4){0.f, 0.f, 0.f, 0.f};
  float m_ = -1e30f, l_ = 0.f;

  const u16* vpb = VpP + (size_t)(h*64) * 256;

  auto STAGE = [&](int buf, int kt0){
    #pragma unroll
    for (int c = 0; c < 2; ++c){
      const int a = w*2 + c;
      const int row = a*8 + l8;
      gload16(Kp + (size_t)(kt0 + row) * 1536 + h*64 + cbE, &Ks[buf][a * 512]);
      gload16(vpb + (size_t)row * 256 + kt0 + cbE, &VTs[buf][a * 512]);
    }
  };

  STAGE(0, 0);
  __syncthreads();                      // prologue drain + clip_l visibility

  int buf = 0;
  for (int nt = 0; nt < 4; ++nt){
    if (nt + 1 < 4){
      STAGE(buf ^ 1, (nt + 1) * 64);
      VMWAIT(4);
    } else {
      VMWAIT(0);
    }
    SCHED0();
    SBAR();
    SCHED0();
    const int kt0 = nt * 64;

    f32x4 s[4];
    __builtin_amdgcn_s_setprio(1);
    #pragma unroll
    for (int n4 = 0; n4 < 4; ++n4){
      f32x4 t = {0.f, 0.f, 0.f, 0.f};
      #pragma unroll
      for (int kk = 0; kk < 2; ++kk){
        const int sz = ((kk*4 + l4) ^ (l15 & 7)) * 8;
        bf16x8 kf = *(const bf16x8*)(&Ks[buf][(n4*16 + l15) * 64 + sz]);
        t = MFMA(kf, qf[kk], t);
      }
      s[n4] = t;
    }
    __builtin_amdgcn_s_setprio(0);

    // bias: s = S*SCALE + gate*clip[key], key = kt0 + n4*16 + l4*4 + r
    #pragma unroll
    for (int n4 = 0; n4 < 4; ++n4){
      const float4 cv = *(const float4*)&clip_l[kt0 + n4*16 + l4*4];
      s[n4][0] = fmaf(s[n4][0], SCALE, gate * cv.x);
      s[n4][1] = fmaf(s[n4][1], SCALE, gate * cv.y);
      s[n4][2] = fmaf(s[n4][2], SCALE, gate * cv.z);
      s[n4][3] = fmaf(s[n4][3], SCALE, gate * cv.w);
    }

    float mt = -1e30f;
    #pragma unroll
    for (int n4 = 0; n4 < 4; ++n4)
      mt = fmaxf(mt, fmaxf(fmaxf(s[n4][0], s[n4][1]), fmaxf(s[n4][2], s[n4][3])));
    mt = redl4_max(mt);

    const float mn = fmaxf(m_, mt);
    const float al = fexp2((m_ - mn) * L2E);
    m_ = mn;
    l_ *= al;
    float alo[4];
    #pragma unroll
    for (int r = 0; r < 4; ++r) alo[r] = __shfl(al, l4*4 + r, 16);
    #pragma unroll
    for (int nb = 0; nb < 4; ++nb)
      #pragma unroll
      for (int r = 0; r < 4; ++r) O[nb][r] *= alo[r];

    const float m2 = m_ * L2E;
    u16 pb[16];
    float ls = 0.f;
    #pragma unroll
    for (int n4 = 0; n4 < 4; ++n4)
      #pragma unroll
      for (int r = 0; r < 4; ++r){
        float pv = fexp2(fmaf(s[n4][r], L2E, -m2));
        ls += pv;
        pb[n4*4 + r] = f2bf(pv);
      }
    l_ += redl4_sum(ls);

    __builtin_amdgcn_s_setprio(1);
    #pragma unroll
    for (int kk = 0; kk < 2; ++kk){
      const int sz = ((kk*4 + l4) ^ (l15 & 7)) * 8;
      bf16x8 pa = { (short)pb[kk*8+0], (short)pb[kk*8+1], (short)pb[kk*8+2], (short)pb[kk*8+3],
                    (short)pb[kk*8+4], (short)pb[kk*8+5], (short)pb[kk*8+6], (short)pb[kk*8+7] };
      #pragma unroll
      for (int nb = 0; nb < 4; ++nb){
        bf16x8 vt = *(const bf16x8*)(&VTs[buf][(nb*16 + l15) * 64 + sz]);
        O[nb] = MFMA(pa, vt, O[nb]);
      }
    }
    __builtin_amdgcn_s_setprio(0);

    SCHED0();
    SBAR();
    buf ^= 1;
  }

  const float inv = 1.f / l_;
  float li[4];
  #pragma unroll
  for (int r = 0; r < 4; ++r) li[r] = __shfl(inv, l4*4 + r, 16);
  #pragma unroll
  for (int r = 0; r < 4; ++r){
    const int row = blockIdx.x * 64 + w * 16 + l4*4 + r;
    #pragma unroll
    for (int nb = 0; nb < 4; ++nb)
      multi[(size_t)row * 1536 + h*64 + nb*16 + l15] = O[nb][r] * li[r];
  }
}

// ---------------- self attention (flash, swapped QK^T, row-linear staging) ----------------

__global__ __launch_bounds__(256, 4) void k_self_attn(
  const u16* __restrict__ q2,   // [2304][1536]
  const u16* __restrict__ k2,   // [2304][1536]
  const u16* __restrict__ v2P,  // [1536][2304], cols pi-permuted per 32-block
  float* __restrict__ hsout)    // [2202][1536]
{
  const int p = blockIdx.x;
  const int h  = (p & 7) * 3 + (p >> 3) / 35;
  const int qb = (p >> 3) % 35;
  const int tid = threadIdx.x, lane = tid & 63, w = tid >> 6;
  const int l15 = lane & 15, l4 = lane >> 4;
  const int l8 = lane >> 3, l7 = lane & 7;
  const int cbE = (l7 ^ l8) * 8;
  const int qrow = qb * 64 + w * 16 + l15;

  __shared__ alignas(1024) u16 Ks[2][4096];
  __shared__ alignas(1024) u16 VTs[2][4096];

  bf16x8 qf[2];
  #pragma unroll
  for (int kk = 0; kk < 2; ++kk)
    qf[kk] = *(const bf16x8*)(q2 + (size_t)qrow * 1536 + h*64 + kk*32 + l4*8);

  f32x4 O[4];
  #pragma unroll
  for (int nb = 0; nb < 4; ++nb) O[nb] = (f32x4){0.f, 0.f, 0.f, 0.f};
  float m_ = -1e30f, l_ = 0.f;
  const float C2 = SCALE * L2E;
  const float THR = 44.36f;             // 8 / C2

  const u16* kp  = k2 + h*64;
  const u16* vp0 = v2P + (size_t)(h*64) * NPAD;

  auto STAGE = [&](int buf, int kt0){
    #pragma unroll
    for (int c = 0; c < 2; ++c){
      const int a = w*2 + c;
      const int row = a*8 + l8;
      gload16(kp + (size_t)(kt0 + row) * 1536 + cbE, &Ks[buf][a * 512]);
      gload16(vp0 + (size_t)row * NPAD + kt0 + cbE, &VTs[buf][a * 512]);
    }
  };

  STAGE(0, 0);
  __syncthreads();                      // prologue drain (once)

  int buf = 0;
  for (int nt = 0; nt < 35; ++nt){
    if (nt + 1 < 35){
      STAGE(buf ^ 1, (nt + 1) * 64);
      VMWAIT(4);
    } else {
      VMWAIT(0);
    }
    SCHED0();
    SBAR();
    SCHED0();
    const int kt0 = nt * 64;

    f32x4 s[4];
    __builtin_amdgcn_s_setprio(1);
    #pragma unroll
    for (int n4 = 0; n4 < 4; ++n4){
      f32x4 t = {0.f, 0.f, 0.f, 0.f};
      #pragma unroll
      for (int kk = 0; kk < 2; ++kk){
        const int sz = ((kk*4 + l4) ^ (l15 & 7)) * 8;
        bf16x8 kf = *(const bf16x8*)(&Ks[buf][(n4*16 + l15) * 64 + sz]);
        t = MFMA(kf, qf[kk], t);
      }
      s[n4] = t;
    }
    __builtin_amdgcn_s_setprio(0);

    if (kt0 + 64 > NTOT){                       // only the last tile
      #pragma unroll
      for (int n4 = 0; n4 < 4; ++n4){
        const int keyb = kt0 + n4*16 + l4*4;
        #pragma unroll
        for (int r = 0; r < 4; ++r)
          if (keyb + r >= NTOT) s[n4][r] = -1e30f;
      }
    }

    float mt = -1e30f;
    #pragma unroll
    for (int n4 = 0; n4 < 4; ++n4)
      mt = fmaxf(mt, fmaxf(fmaxf(s[n4][0], s[n4][1]), fmaxf(s[n4][2], s[n4][3])));
    mt = redl4_max(mt);

    if (__any(mt > m_ + THR)){                  // T13 defer-max
      const float mn = fmaxf(m_, mt);
      const float al = fexp2((m_ - mn) * C2);
      m_ = mn;
      l_ *= al;
      float alo[4];
      #pragma unroll
      for (int r = 0; r < 4; ++r) alo[r] = __shfl(al, l4*4 + r, 16);
      #pragma unroll
      for (int nb = 0; nb < 4; ++nb)
        #pragma unroll
        for (int r = 0; r < 4; ++r) O[nb][r] *= alo[r];
    }
    const float m2 = m_ * C2;

    u16 pb[16];
    float ls = 0.f;
    #pragma unroll
    for (int n4 = 0; n4 < 4; ++n4)
      #pragma unroll
      for (int r = 0; r < 4; ++r){
        float pv = fexp2(fmaf(s[n4][r], C2, -m2));
        ls += pv;
        pb[n4*4 + r] = f2bf(pv);
      }
    l_ += redl4_sum(ls);

    __builtin_amdgcn_s_setprio(1);
    #pragma unroll
    for (int kk = 0; kk < 2; ++kk){
      const int sz = ((kk*4 + l4) ^ (l15 & 7)) * 8;
      bf16x8 pa = { (short)pb[kk*8+0], (short)pb[kk*8+1], (short)pb[kk*8+2], (short)pb[kk*8+3],
                    (short)pb[kk*8+4], (short)pb[kk*8+5], (short)pb[kk*8+6], (short)pb[kk*8+7] };
      #pragma unroll
      for (int nb = 0; nb < 4; ++nb){
        bf16x8 vt = *(const bf16x8*)(&VTs[buf][(nb*16 + l15) * 64 + sz]);
        O[nb] = MFMA(pa, vt, O[nb]);
      }
    }
    __builtin_amdgcn_s_setprio(0);

    SCHED0();
    SBAR();
    buf ^= 1;
  }

  const float inv = 1.f / l_;
  float li[4];
  #pragma unroll
  for (int r = 0; r < 4; ++r) li[r] = __shfl(inv, l4*4 + r, 16);
  #pragma unroll
  for (int r = 0; r < 4; ++r){
    const int row = qb * 64 + w * 16 + l4*4 + r;
    if (row < NTOT){
      #pragma unroll
      for (int nb = 0; nb < 4; ++nb)
        hsout[(size_t)row * 1536 + h*64 + nb*16 + l15] = O[nb][r] * li[r];
    }
  }
}

// ---------------- adaptive gate + blend ----------------

__global__ __launch_bounds__(256) void k_adaptive(
  const float* __restrict__ multi, const float* __restrict__ hsbuf,
  const float* __restrict__ Wad, const float* __restrict__ badp,
  u16* __restrict__ blended)
{
  const int lane = threadIdx.x & 63, wid = threadIdx.x >> 6;
  const int q = blockIdx.x * 4 + wid;
  const float* mrow = multi + (size_t)q * 1536;
  const float* hrow = hsbuf + (size_t)q * 1536;
  float acc = 0.f;
  #pragma unroll
  for (int i = 0; i < 24; ++i){
    int d = lane + 64 * i;
    acc += mrow[d] * Wad[d] + hrow[d] * Wad[1536 + d];
  }
  acc = red64_sum(acc) + badp[0];
  const float sig = 1.f / (1.f + __expf(-acc));
  const float f = BLENDF * sig;
  u16* brow = blended + (size_t)q * 1536;
  #pragma unroll
  for (int i = 0; i < 24; ++i){
    int d = lane + 64 * i;
    brow[d] = f2bf(f * mrow[d] + hrow[d]);
  }
}

// ---------------- launch ----------------

extern "C" void kernel_launch(void* const* d_in, const int* in_sizes, int n_in,
                              void* d_out, int out_size, void* d_ws, size_t ws_size,
                              hipStream_t stream)
{
  (void)in_sizes; (void)n_in; (void)out_size; (void)ws_size;
  const float* hs   = (const float*)d_in[0];
  const float* enc  = (const float*)d_in[1];
  const float* pics = (const float*)d_in[2];
  const float* clip = (const float*)d_in[3];
  const float* Wq   = (const float*)d_in[4];  const float* bq   = (const float*)d_in[5];
  const float* Wk   = (const float*)d_in[6];  const float* bk   = (const float*)d_in[7];
  const float* Wv   = (const float*)d_in[8];  const float* bv   = (const float*)d_in[9];
  const float* Waq  = (const float*)d_in[10]; const float* baq  = (const float*)d_in[11];
  const float* Wak  = (const float*)d_in[12]; const float* bak  = (const float*)d_in[13];
  const float* Wav  = (const float*)d_in[14]; const float* bav  = (const float*)d_in[15];
  const float* Wkl  = (const float*)d_in[16]; const float* Wvl  = (const float*)d_in[17];
  const float* Wsl  = (const float*)d_in[18]; const float* bsl  = (const float*)d_in[19];
  const float* Wad  = (const float*)d_in[20]; const float* bad  = (const float*)d_in[21];
  const float* Wout = (const float*)d_in[22]; const float* bout = (const float*)d_in[23];
  const float* Wadd = (const float*)d_in[24]; const float* badd = (const float*)d_in[25];

  char* ws = (char*)d_ws;
  size_t off = 0;
  auto alloc = [&](size_t b){ void* p = ws + off; off += (b + 255) & ~(size_t)255; return p; };

  u16* hs_bf  = (u16*)alloc((size_t)2048*1536*2);
  u16* enc_bf = (u16*)alloc((size_t)154*1536*2);
  u16* pics_bf= (u16*)alloc((size_t)256*1024*2);
  u16* WqT  = (u16*)alloc((size_t)1536*1536*2);
  u16* WkT  = (u16*)alloc((size_t)1536*1536*2);
  u16* WvT  = (u16*)alloc((size_t)1536*1536*2);
  u16* WaqT = (u16*)alloc((size_t)1536*1536*2);
  u16* WakT = (u16*)alloc((size_t)1536*1536*2);
  u16* WavT = (u16*)alloc((size_t)1536*1536*2);
  u16* WoutT= (u16*)alloc((size_t)1536*1536*2);
  u16* WaddT= (u16*)alloc((size_t)1536*1536*2);
  u16* WklT = (u16*)alloc((size_t)1536*1024*2);
  u16* WvlT = (u16*)alloc((size_t)1536*1024*2);
  u16* q2   = (u16*)alloc((size_t)NPAD*1536*2);
  u16* k2   = (u16*)alloc((size_t)NPAD*1536*2);
  u16* v2   = (u16*)alloc((size_t)NPAD*1536*2);
  u16* v2P  = (u16*)alloc((size_t)1536*NPAD*2);
  u16* Kp   = (u16*)alloc((size_t)256*1536*2);
  u16* Vp   = (u16*)alloc((size_t)256*1536*2);
  u16* VpP  = (u16*)alloc((size_t)1536*256*2);
  float* wvec   = (float*)alloc((size_t)1536*4);
  float* multi  = (float*)alloc((size_t)2048*1536*4);
  float* hsbuf  = (float*)alloc((size_t)NTOT*1536*4);
  u16* blended  = (u16*)alloc((size_t)2048*1536*2);
  u16* hstxt    = (u16*)alloc((size_t)154*1536*2);

  const long padn8 = ((long)(NPAD - NTOT) * 1536) / 8;   // 19584
  k_zeropad<<<dim3((padn8 + 255) / 256), 256, 0, stream>>>(
      q2 + (size_t)NTOT*1536, k2 + (size_t)NTOT*1536, v2 + (size_t)NTOT*1536, padn8);

  k_cast<<<dim3(3072), 256, 0, stream>>>(hs,   hs_bf,  (long)2048*1536);
  k_cast<<<dim3(231),  256, 0, stream>>>(enc,  enc_bf, (long)154*1536);
  k_cast<<<dim3(256),  256, 0, stream>>>(pics, pics_bf,(long)256*1024);

  WT10 wts;
  wts.w[0] = {Wq,   WqT,   1536};
  wts.w[1] = {Wk,   WkT,   1536};
  wts.w[2] = {Wv,   WvT,   1536};
  wts.w[3] = {Waq,  WaqT,  1536};
  wts.w[4] = {Wak,  WakT,  1536};
  wts.w[5] = {Wav,  WavT,  1536};
  wts.w[6] = {Wout, WoutT, 1536};
  wts.w[7] = {Wadd, WaddT, 1536};
  wts.w[8] = {Wkl,  WklT,  1024};
  wts.w[9] = {Wvl,  WvlT,  1024};
  k_transpose_w<<<dim3(48, 48, 10), dim3(32, 8), 0, stream>>>(wts);

  // QKV: 64x128 tiles -> 32x36 = 1152 blocks (4.5/CU); region 16x9 per XCD (nCx=4)
  GOuts oqkv; oqkv.C[0] = q2; oqkv.C[1] = k2; oqkv.C[2] = v2;
  oqkv.b[0] = bq; oqkv.b[1] = bk; oqkv.b[2] = bv;
  k_gemm<64,0><<<dim3(1152), 256, 0, stream>>>(hs_bf, 1536, WqT, 1536, oqkv, 1536, 2048, 4608, 1536, 1, 4, 16, 9);

  GOuts oenc; oenc.C[0] = q2 + (size_t)2048*1536; oenc.C[1] = k2 + (size_t)2048*1536; oenc.C[2] = v2 + (size_t)2048*1536;
  oenc.b[0] = baq; oenc.b[1] = bak; oenc.b[2] = bav;
  k_gemm<64,0><<<dim3(36, 3), 256, 0, stream>>>(enc_bf, 1536, WaqT, 1536, oenc, 1536, 154, 4608, 1536, 0, 0, 0, 0);

  GOuts okv; okv.C[0] = Kp; okv.C[1] = Vp; okv.C[2] = nullptr;
  okv.b[0] = nullptr; okv.b[1] = nullptr; okv.b[2] = nullptr;
  k_gemm<64,0><<<dim3(24, 4), 256, 0, stream>>>(pics_bf, 1024, WklT, 1024, okv, 1536, 256, 3072, 1024, 0, 0, 0, 0);

  k_wvec<<<dim3(6), 256, 0, stream>>>(Kp, Wsl, wvec);

  k_transpose_vp<<<dim3(48, NPAD/32), dim3(32, 8), 0, stream>>>(v2, v2P, NPAD, 1536);
  k_transpose_vp<<<dim3(48, 8),       dim3(32, 8), 0, stream>>>(Vp, VpP, 256, 1536);

  k_cross_attn<<<dim3(32, 24), 256, 0, stream>>>(q2, Kp, VpP, clip, Wsl, bsl, wvec, multi);
  k_self_attn<<<dim3(840), 256, 0, stream>>>(q2, k2, v2P, hsbuf);

  k_adaptive<<<dim3(512), 256, 0, stream>>>(multi, hsbuf, Wad, bad, blended);
  k_cast<<<dim3(231), 256, 0, stream>>>(hsbuf + (size_t)2048*1536, hstxt, (long)154*1536);

  // Wout: 64x128 tiles -> 32x12 = 384 blocks; region 8x6 per XCD (nCx=2)
  GOuts oout; oout.C[0] = d_out; oout.C[1] = nullptr; oout.C[2] = nullptr;
  oout.b[0] = bout; oout.b[1] = nullptr; oout.b[2] = nullptr;
  k_gemm<64,1><<<dim3(384), 256, 0, stream>>>(blended, 1536, WoutT, 1536, oout, 1536, 2048, 1536, 1536, 1, 2, 8, 6);

  GOuts oadd; oadd.C[0] = (float*)d_out + (size_t)2048*1536; oadd.C[1] = nullptr; oadd.C[2] = nullptr;
  oadd.b[0] = badd; oadd.b[1] = nullptr; oadd.b[2] = nullptr;
  k_gemm<64,1><<<dim3(12, 3), 256, 0, stream>>>(hstxt, 1536, WaddT, 1536, oadd, 1536, 154, 1536, 1536, 0, 0, 0, 0);
}

// Round 12
// 297.483 us; speedup vs baseline: 1.5230x; 1.0085x over previous
//
#include <hip/hip_runtime.h>

typedef unsigned short u16;
typedef unsigned int u32;
typedef __attribute__((ext_vector_type(4))) short bf16x4;
typedef __attribute__((ext_vector_type(8))) short bf16x8;
typedef __attribute__((ext_vector_type(4))) float f32x4;

#define SCALE 0.125f
#define BLENDF 0.4875f
#define NTOT 2202
#define NPAD 2304
#define L2E 1.44269504f

#define SBAR()  __builtin_amdgcn_s_barrier()
#define SCHED0() __builtin_amdgcn_sched_barrier(0)
#define VMWAIT(n) asm volatile("s_waitcnt vmcnt(" #n ")" ::: "memory")

__device__ __forceinline__ u16 f2bf(float x){
  union { float f; unsigned u; } v; v.f = x;
  unsigned r = v.u + 0x7fffu + ((v.u >> 16) & 1u);
  return (u16)(r >> 16);
}
__device__ __forceinline__ float bf2f(u16 b){
  union { unsigned u; float f; } v; v.u = (u32)b << 16; return v.f;
}
// hw packer: 2 f32 -> 2 bf16 (RNE), src0 in low half
__device__ __forceinline__ u32 cvtpk(float a, float b){
  u32 r;
  asm("v_cvt_pk_bf16_f32 %0, %1, %2" : "=v"(r) : "v"(a), "v"(b));
  return r;
}

__device__ __forceinline__ float fexp2(float x){
#if __has_builtin(__builtin_amdgcn_exp2f)
  return __builtin_amdgcn_exp2f(x);
#else
  return __expf(x * 0.6931472f);
#endif
}

__device__ __forceinline__ f32x4 MFMA(bf16x8 a, bf16x8 b, f32x4 c){
  return __builtin_amdgcn_mfma_f32_16x16x32_bf16(a, b, c, 0, 0, 0);
}

// async global->LDS, 16B per lane; LDS dest is wave-uniform base (+lane*16 implicit)
__device__ __forceinline__ void gload16(const u16* g, u16* l){
  __builtin_amdgcn_global_load_lds(
    (const __attribute__((address_space(1))) u32*)g,
    (__attribute__((address_space(3))) u32*)l, 16, 0, 0);
}

__device__ __forceinline__ float red64_sum(float x){
  x += __shfl_xor(x, 1, 64);
  x += __shfl_xor(x, 2, 64);
  x += __shfl_xor(x, 4, 64);
  x += __shfl_xor(x, 8, 64);
  x += __shfl_xor(x, 16, 64);
  x += __shfl_xor(x, 32, 64);
  return x;
}
// reduce over the l4 axis (lanes sharing the same lane&15)
__device__ __forceinline__ float redl4_sum(float x){
  x += __shfl_xor(x, 16, 64);
  x += __shfl_xor(x, 32, 64);
  return x;
}
__device__ __forceinline__ float redl4_max(float x){
  x = fmaxf(x, __shfl_xor(x, 16, 64));
  x = fmaxf(x, __shfl_xor(x, 32, 64));
  return x;
}

// ---------------- utility kernels ----------------

__global__ void k_zeropad(u16* __restrict__ a, u16* __restrict__ b,
                          u16* __restrict__ c, long n8){
  long i = (long)blockIdx.x * blockDim.x + threadIdx.x;
  if (i < n8){
    const bf16x8 z = {0,0,0,0,0,0,0,0};
    *(bf16x8*)(a + i*8) = z;
    *(bf16x8*)(b + i*8) = z;
    *(bf16x8*)(c + i*8) = z;
  }
}

__global__ void k_cast(const float* __restrict__ in, u16* __restrict__ out, long n){
  long i = ((long)blockIdx.x * blockDim.x + threadIdx.x) * 4;
  long stride = (long)gridDim.x * blockDim.x * 4;
  for (; i < n; i += stride){
    float4 f = *(const float4*)(in + i);
    bf16x4 v = { (short)f2bf(f.x), (short)f2bf(f.y), (short)f2bf(f.z), (short)f2bf(f.w) };
    *(bf16x4*)(out + i) = v;
  }
}

// w_vec[d] = sum_k Wsl[k] * Kp[k][d]  (rank-1 gate precompute)
__global__ __launch_bounds__(256) void k_wvec(const u16* __restrict__ Kp,
                                              const float* __restrict__ Wsl,
                                              float* __restrict__ wvec){
  const int d = blockIdx.x * 256 + threadIdx.x;
  float acc = 0.f;
  for (int k = 0; k < 256; ++k)
    acc += Wsl[k] * bf2f(Kp[(size_t)k * 1536 + d]);
  wvec[d] = acc;
}

struct WT { const float* s; u16* d; int K; };
struct WT10 { WT w[10]; };

// in: [K][1536] fp32 -> out: [1536][K] bf16
__global__ __launch_bounds__(256) void k_transpose_w(WT10 ws){
  const WT t = ws.w[blockIdx.z];
  const int r0 = blockIdx.y * 32;
  if (r0 >= t.K) return;
  const int c0 = blockIdx.x * 32;
  __shared__ float tile[32][33];
  const int x = threadIdx.x, y = threadIdx.y;
  #pragma unroll
  for (int k = 0; k < 4; ++k)
    tile[y + 8*k][x] = t.s[(size_t)(r0 + y + 8*k) * 1536 + c0 + x];
  __syncthreads();
  #pragma unroll
  for (int k = 0; k < 4; ++k)
    t.d[(size_t)(c0 + y + 8*k) * t.K + r0 + x] = f2bf(tile[x][y + 8*k]);
}

// in: [R][C] bf16 -> out[C][R] bf16 with columns PERMUTED within each 32-block:
// out[d][32b + p] = in[32b + k(p)][d], k(p) = ((p>>2)&1)*16 + (p>>3)*4 + (p&3)
// == PV A-fragment k-slot map, so a contiguous read is the B-fragment.
__global__ __launch_bounds__(256) void k_transpose_vp(const u16* __restrict__ in,
                                                      u16* __restrict__ out, int R, int C){
  const int r0 = blockIdx.y * 32, c0 = blockIdx.x * 32;
  __shared__ u16 tile[32][34];
  const int x = threadIdx.x, y = threadIdx.y;
  #pragma unroll
  for (int k = 0; k < 4; ++k)
    tile[y + 8*k][x] = in[(size_t)(r0 + y + 8*k) * C + c0 + x];
  __syncthreads();
  const int kx = (((x >> 2) & 1) << 4) + ((x >> 3) << 2) + (x & 3);
  #pragma unroll
  for (int k = 0; k < 4; ++k)
    out[(size_t)(c0 + y + 8*k) * R + r0 + x] = tile[kx][y + 8*k];
}

// ---------------- GEMM: C = A[M][K] * BT[N][K]^T, fused N-segments ----------------
// Row-linear staging (8 full cache lines/instr) + both-sides XOR swizzle (2-way alias, free).

struct GOuts { void* C[3]; const float* b[3]; };

template<int BM, int OUTF32>
__global__ __launch_bounds__(256, 4) void k_gemm(
  const u16* __restrict__ A, int lda,
  const u16* __restrict__ BT, int ldb,
  GOuts o, int ldc, int M, int N, int K,
  int gx, int nCx, int rBlk, int cBlk)
{
  constexpr int MW = BM / 32;
  constexpr int AI = BM / 32;
  __shared__ alignas(1024) u16 As[BM * 64];
  __shared__ alignas(1024) u16 Bs[128 * 64];
  const int tid = threadIdx.x, lane = tid & 63, w = tid >> 6;
  const int l15 = lane & 15, l4 = lane >> 4;
  const int l8 = lane >> 3, l7 = lane & 7;
  const int cbE = (l7 ^ l8) * 8;

  int bx, by;
  if (gx){
    const int xcd = blockIdx.x & 7, slot = blockIdx.x >> 3;
    const int rx = xcd / nCx, cx = xcd - rx * nCx;
    by = rx * rBlk + slot / cBlk;
    bx = cx * cBlk + slot % cBlk;
  } else {
    bx = blockIdx.x; by = blockIdx.y;
  }
  const int m0 = by * BM, n0 = bx * 128;
  const int wm = (w >> 1) * (BM / 2), wn = (w & 1) * 64;

  f32x4 acc[MW][4];
  #pragma unroll
  for (int i = 0; i < MW; ++i)
    #pragma unroll
    for (int j = 0; j < 4; ++j)
      acc[i][j] = (f32x4){0.f, 0.f, 0.f, 0.f};

  for (int k0 = 0; k0 < K; k0 += 64){
    #pragma unroll
    for (int c = 0; c < AI; ++c){
      const int a = w * AI + c;
      const int ar = min(m0 + a*8 + l8, M - 1);
      gload16(A + (size_t)ar * lda + k0 + cbE, &As[a * 512]);
    }
    #pragma unroll
    for (int c = 0; c < 4; ++c){
      const int b = w * 4 + c;
      const int br = min(n0 + b*8 + l8, N - 1);
      gload16(BT + (size_t)br * ldb + k0 + cbE, &Bs[b * 512]);
    }
    VMWAIT(0);
    __syncthreads();
    #pragma unroll
    for (int kk = 0; kk < 2; ++kk){
      const int sz = ((kk*4 + l4) ^ (l15 & 7)) * 8;
      bf16x8 a[MW], b[4];
      #pragma unroll
      for (int m = 0; m < MW; ++m)
        a[m] = *(const bf16x8*)(As + (wm + m*16 + l15) * 64 + sz);
      #pragma unroll
      for (int n = 0; n < 4; ++n)
        b[n] = *(const bf16x8*)(Bs + (wn + n*16 + l15) * 64 + sz);
      #pragma unroll
      for (int m = 0; m < MW; ++m)
        #pragma unroll
        for (int n = 0; n < 4; ++n)
          acc[m][n] = MFMA(a[m], b[n], acc[m][n]);
    }
    __syncthreads();
  }

  #pragma unroll
  for (int n = 0; n < 4; ++n){
    const int colg = n0 + wn + n*16 + l15;
    const int sel = colg / 1536;
    const int col = colg - sel * 1536;
    const float* bp = o.b[sel];
    const float bi = bp ? bp[col] : 0.f;
    #pragma unroll
    for (int m = 0; m < MW; ++m){
      const int row0 = m0 + wm + m*16 + l4*4;
      #pragma unroll
      for (int r = 0; r < 4; ++r){
        const int row = row0 + r;
        if (row < M){
          float val = acc[m][n][r] + bi;
          if (OUTF32) ((float*)o.C[sel])[(size_t)row * ldc + col] = val;
          else        ((u16*)o.C[sel])[(size_t)row * ldc + col] = f2bf(val);
        }
      }
    }
  }
}

// ---------------- cross attention: flash-style, rank-1 gate ----------------

__global__ __launch_bounds__(256, 4) void k_cross_attn(
  const u16* __restrict__ Q,
  const u16* __restrict__ Kp,    // [256][1536]
  const u16* __restrict__ VpP,   // [1536][256], cols pi-permuted per 32-block
  const float* __restrict__ clip,
  const float* __restrict__ Wsl, // [512]
  const float* __restrict__ bslp,
  const float* __restrict__ wvec,// [1536]
  float* __restrict__ multi)     // [2048][1536]
{
  const int h = blockIdx.y;
  const int tid = threadIdx.x, lane = tid & 63, w = tid >> 6;
  const int l15 = lane & 15, l4 = lane >> 4;
  const int l8 = lane >> 3, l7 = lane & 7;
  const int cbE = (l7 ^ l8) * 8;
  const int qrow = blockIdx.x * 64 + w * 16 + l15;

  __shared__ alignas(1024) u16 Ks[2][4096];
  __shared__ alignas(1024) u16 VTs[2][4096];
  __shared__ float clip_l[256];
  if (tid < 256) clip_l[tid] = clip[tid];

  float cd = 0.f;
  for (int p = lane; p < 256; p += 64) cd += clip[p] * Wsl[256 + p];
  cd = red64_sum(cd);
  const float gate_c = cd + bslp[0];

  bf16x8 qf[2];
  #pragma unroll
  for (int kk = 0; kk < 2; ++kk)
    qf[kk] = *(const bf16x8*)(Q + (size_t)qrow * 1536 + h*64 + kk*32 + l4*8);

  float gd = 0.f;
  #pragma unroll
  for (int kk = 0; kk < 2; ++kk){
    const float4 w0 = *(const float4*)(wvec + h*64 + kk*32 + l4*8);
    const float4 w1 = *(const float4*)(wvec + h*64 + kk*32 + l4*8 + 4);
    gd += w0.x * bf2f((u16)qf[kk][0]) + w0.y * bf2f((u16)qf[kk][1]);
    gd += w0.z * bf2f((u16)qf[kk][2]) + w0.w * bf2f((u16)qf[kk][3]);
    gd += w1.x * bf2f((u16)qf[kk][4]) + w1.y * bf2f((u16)qf[kk][5]);
    gd += w1.z * bf2f((u16)qf[kk][6]) + w1.w * bf2f((u16)qf[kk][7]);
  }
  const float gate = SCALE * redl4_sum(gd) + gate_c;

  f32x4 O[4];
  #pragma unroll
  for (int nb = 0; nb < 4; ++nb) O[nb] = (f32x4){0.f, 0.f, 0.f, 0.f};
  float m_ = -1e30f, l_ = 0.f;          // l_ lane-local; reduced once at end

  const u16* vpb = VpP + (size_t)(h*64) * 256;

  auto STAGE = [&](int buf, int kt0){
    #pragma unroll
    for (int c = 0; c < 2; ++c){
      const int a = w*2 + c;
      const int row = a*8 + l8;
      gload16(Kp + (size_t)(kt0 + row) * 1536 + h*64 + cbE, &Ks[buf][a * 512]);
      gload16(vpb + (size_t)row * 256 + kt0 + cbE, &VTs[buf][a * 512]);
    }
  };

  STAGE(0, 0);
  __syncthreads();

  int buf = 0;
  for (int nt = 0; nt < 4; ++nt){
    if (nt + 1 < 4){
      STAGE(buf ^ 1, (nt + 1) * 64);
      VMWAIT(4);
    } else {
      VMWAIT(0);
    }
    SCHED0();
    SBAR();
    SCHED0();
    const int kt0 = nt * 64;

    f32x4 s[4];
    __builtin_amdgcn_s_setprio(1);
    #pragma unroll
    for (int n4 = 0; n4 < 4; ++n4){
      f32x4 t = {0.f, 0.f, 0.f, 0.f};
      #pragma unroll
      for (int kk = 0; kk < 2; ++kk){
        const int sz = ((kk*4 + l4) ^ (l15 & 7)) * 8;
        bf16x8 kf = *(const bf16x8*)(&Ks[buf][(n4*16 + l15) * 64 + sz]);
        t = MFMA(kf, qf[kk], t);
      }
      s[n4] = t;
    }
    __builtin_amdgcn_s_setprio(0);

    #pragma unroll
    for (int n4 = 0; n4 < 4; ++n4){
      const float4 cv = *(const float4*)&clip_l[kt0 + n4*16 + l4*4];
      s[n4][0] = fmaf(s[n4][0], SCALE, gate * cv.x);
      s[n4][1] = fmaf(s[n4][1], SCALE, gate * cv.y);
      s[n4][2] = fmaf(s[n4][2], SCALE, gate * cv.z);
      s[n4][3] = fmaf(s[n4][3], SCALE, gate * cv.w);
    }

    float mt = -1e30f;
    #pragma unroll
    for (int n4 = 0; n4 < 4; ++n4)
      mt = fmaxf(mt, fmaxf(fmaxf(s[n4][0], s[n4][1]), fmaxf(s[n4][2], s[n4][3])));
    mt = redl4_max(mt);

    const float mn = fmaxf(m_, mt);
    const float al = fexp2((m_ - mn) * L2E);
    m_ = mn;
    l_ *= al;
    float alo[4];
    #pragma unroll
    for (int r = 0; r < 4; ++r) alo[r] = __shfl(al, l4*4 + r, 16);
    #pragma unroll
    for (int nb = 0; nb < 4; ++nb)
      #pragma unroll
      for (int r = 0; r < 4; ++r) O[nb][r] *= alo[r];

    const float m2 = m_ * L2E;
    #pragma unroll
    for (int n4 = 0; n4 < 4; ++n4)
      #pragma unroll
      for (int r = 0; r < 4; ++r){
        float pv = fexp2(fmaf(s[n4][r], L2E, -m2));
        l_ += pv;
        s[n4][r] = pv;
      }

    __builtin_amdgcn_s_setprio(1);
    #pragma unroll
    for (int kk = 0; kk < 2; ++kk){
      const int sz = ((kk*4 + l4) ^ (l15 & 7)) * 8;
      union { u32 w4[4]; bf16x8 v; } U;
      U.w4[0] = cvtpk(s[2*kk][0],   s[2*kk][1]);
      U.w4[1] = cvtpk(s[2*kk][2],   s[2*kk][3]);
      U.w4[2] = cvtpk(s[2*kk+1][0], s[2*kk+1][1]);
      U.w4[3] = cvtpk(s[2*kk+1][2], s[2*kk+1][3]);
      #pragma unroll
      for (int nb = 0; nb < 4; ++nb){
        bf16x8 vt = *(const bf16x8*)(&VTs[buf][(nb*16 + l15) * 64 + sz]);
        O[nb] = MFMA(U.v, vt, O[nb]);
      }
    }
    __builtin_amdgcn_s_setprio(0);

    SCHED0();
    SBAR();
    buf ^= 1;
  }

  const float inv = 1.f / redl4_sum(l_);
  float li[4];
  #pragma unroll
  for (int r = 0; r < 4; ++r) li[r] = __shfl(inv, l4*4 + r, 16);
  #pragma unroll
  for (int r = 0; r < 4; ++r){
    const int row = blockIdx.x * 64 + w * 16 + l4*4 + r;
    #pragma unroll
    for (int nb = 0; nb < 4; ++nb)
      multi[(size_t)row * 1536 + h*64 + nb*16 + l15] = O[nb][r] * li[r];
  }
}

// ---------------- self attention: flash split-K (2 halves), partials merged later ----------------

__global__ __launch_bounds__(256, 4) void k_self_attn_split(
  const u16* __restrict__ q2,   // [2304][1536]
  const u16* __restrict__ k2,   // [2304][1536]
  const u16* __restrict__ v2P,  // [1536][2304], cols pi-permuted per 32-block
  float* __restrict__ Opart,    // [2][2240][1536] unnormalized
  float2* __restrict__ ml)      // [2][24][2240] (m, l)
{
  const int p = blockIdx.x;
  const int slot = p >> 3;
  const int h   = (p & 7) * 3 + slot / 70;
  const int rem = slot % 70;
  const int qb = rem >> 1, half = rem & 1;
  const int nt0 = half * 18, ntE = half ? 35 : 18;
  const int tid = threadIdx.x, lane = tid & 63, w = tid >> 6;
  const int l15 = lane & 15, l4 = lane >> 4;
  const int l8 = lane >> 3, l7 = lane & 7;
  const int cbE = (l7 ^ l8) * 8;
  const int qrow = qb * 64 + w * 16 + l15;

  __shared__ alignas(1024) u16 Ks[2][4096];
  __shared__ alignas(1024) u16 VTs[2][4096];

  bf16x8 qf[2];
  #pragma unroll
  for (int kk = 0; kk < 2; ++kk)
    qf[kk] = *(const bf16x8*)(q2 + (size_t)qrow * 1536 + h*64 + kk*32 + l4*8);

  f32x4 O[4];
  #pragma unroll
  for (int nb = 0; nb < 4; ++nb) O[nb] = (f32x4){0.f, 0.f, 0.f, 0.f};
  float m_ = -1e30f, l_ = 0.f;          // lane-local l; reduced at end
  const float C2 = SCALE * L2E;
  const float THR = 44.36f;             // 8 / C2

  const u16* kp  = k2 + h*64;
  const u16* vp0 = v2P + (size_t)(h*64) * NPAD;

  auto STAGE = [&](int buf, int kt0){
    #pragma unroll
    for (int c = 0; c < 2; ++c){
      const int a = w*2 + c;
      const int row = a*8 + l8;
      gload16(kp + (size_t)(kt0 + row) * 1536 + cbE, &Ks[buf][a * 512]);
      gload16(vp0 + (size_t)row * NPAD + kt0 + cbE, &VTs[buf][a * 512]);
    }
  };

  STAGE(0, nt0 * 64);
  __syncthreads();

  int buf = 0;
  for (int nt = nt0; nt < ntE; ++nt){
    if (nt + 1 < ntE){
      STAGE(buf ^ 1, (nt + 1) * 64);
      VMWAIT(4);
    } else {
      VMWAIT(0);
    }
    SCHED0();
    SBAR();
    SCHED0();
    const int kt0 = nt * 64;

    f32x4 s[4];
    __builtin_amdgcn_s_setprio(1);
    #pragma unroll
    for (int n4 = 0; n4 < 4; ++n4){
      f32x4 t = {0.f, 0.f, 0.f, 0.f};
      #pragma unroll
      for (int kk = 0; kk < 2; ++kk){
        const int sz = ((kk*4 + l4) ^ (l15 & 7)) * 8;
        bf16x8 kf = *(const bf16x8*)(&Ks[buf][(n4*16 + l15) * 64 + sz]);
        t = MFMA(kf, qf[kk], t);
      }
      s[n4] = t;
    }
    __builtin_amdgcn_s_setprio(0);

    if (kt0 + 64 > NTOT){                       // only the global last tile
      #pragma unroll
      for (int n4 = 0; n4 < 4; ++n4){
        const int keyb = kt0 + n4*16 + l4*4;
        #pragma unroll
        for (int r = 0; r < 4; ++r)
          if (keyb + r >= NTOT) s[n4][r] = -1e30f;
      }
    }

    float mt = -1e30f;
    #pragma unroll
    for (int n4 = 0; n4 < 4; ++n4)
      mt = fmaxf(mt, fmaxf(fmaxf(s[n4][0], s[n4][1]), fmaxf(s[n4][2], s[n4][3])));
    mt = redl4_max(mt);

    if (__any(mt > m_ + THR)){                  // T13 defer-max
      const float mn = fmaxf(m_, mt);
      const float al = fexp2((m_ - mn) * C2);
      m_ = mn;
      l_ *= al;                                 // al uniform across l4-group
      float alo[4];
      #pragma unroll
      for (int r = 0; r < 4; ++r) alo[r] = __shfl(al, l4*4 + r, 16);
      #pragma unroll
      for (int nb = 0; nb < 4; ++nb)
        #pragma unroll
        for (int r = 0; r < 4; ++r) O[nb][r] *= alo[r];
    }
    const float m2 = m_ * C2;

    #pragma unroll
    for (int n4 = 0; n4 < 4; ++n4)
      #pragma unroll
      for (int r = 0; r < 4; ++r){
        float pv = fexp2(fmaf(s[n4][r], C2, -m2));
        l_ += pv;
        s[n4][r] = pv;
      }

    __builtin_amdgcn_s_setprio(1);
    #pragma unroll
    for (int kk = 0; kk < 2; ++kk){
      const int sz = ((kk*4 + l4) ^ (l15 & 7)) * 8;
      union { u32 w4[4]; bf16x8 v; } U;
      U.w4[0] = cvtpk(s[2*kk][0],   s[2*kk][1]);
      U.w4[1] = cvtpk(s[2*kk][2],   s[2*kk][3]);
      U.w4[2] = cvtpk(s[2*kk+1][0], s[2*kk+1][1]);
      U.w4[3] = cvtpk(s[2*kk+1][2], s[2*kk+1][3]);
      #pragma unroll
      for (int nb = 0; nb < 4; ++nb){
        bf16x8 vt = *(const bf16x8*)(&VTs[buf][(nb*16 + l15) * 64 + sz]);
        O[nb] = MFMA(U.v, vt, O[nb]);
      }
    }
    __builtin_amdgcn_s_setprio(0);

    SCHED0();
    SBAR();
    buf ^= 1;
  }

  const float lsum = redl4_sum(l_);
  float* Oh = Opart + (size_t)half * 2240 * 1536;
  #pragma unroll
  for (int r = 0; r < 4; ++r){
    const int row = qb*64 + w*16 + l4*4 + r;
    #pragma unroll
    for (int nb = 0; nb < 4; ++nb)
      Oh[(size_t)row * 1536 + h*64 + nb*16 + l15] = O[nb][r];
  }
  if (l4 == 0)
    ml[(size_t)half*24*2240 + h*2240 + qrow] = make_float2(m_, lsum);
}

// merge: out[row][col] = (e0*O0 + e1*O1) / (e0*l0 + e1*l1), e_i = exp2((m_i - M)*C2)
__global__ __launch_bounds__(256) void k_merge(
  const float* __restrict__ Op,     // [2][2240][1536]
  const float2* __restrict__ ml,    // [2][24][2240]
  float* __restrict__ out)          // [NTOT][1536]
{
  const int row = blockIdx.x;
  const int t = threadIdx.x;
  __shared__ float e0s[24], e1s[24], invs[24];
  if (t < 24){
    const float2 a = ml[t*2240 + row];
    const float2 b = ml[24*2240 + t*2240 + row];
    const float M = fmaxf(a.x, b.x);
    const float C2 = SCALE * L2E;
    const float e0 = fexp2((a.x - M) * C2);
    const float e1 = fexp2((b.x - M) * C2);
    e0s[t] = e0; e1s[t] = e1;
    invs[t] = 1.f / (e0*a.y + e1*b.y);
  }
  __syncthreads();
  const float* O0 = Op + (size_t)row * 1536;
  const float* O1 = Op + (size_t)2240*1536 + (size_t)row * 1536;
  float* orow = out + (size_t)row * 1536;
  #pragma unroll
  for (int i = 0; i < 6; ++i){
    const int col = t + i*256;
    const int h = col >> 6;
    orow[col] = (e0s[h]*O0[col] + e1s[h]*O1[col]) * invs[h];
  }
}

// ---------------- adaptive gate + blend ----------------

__global__ __launch_bounds__(256) void k_adaptive(
  const float* __restrict__ multi, const float* __restrict__ hsbuf,
  const float* __restrict__ Wad, const float* __restrict__ badp,
  u16* __restrict__ blended)
{
  const int lane = threadIdx.x & 63, wid = threadIdx.x >> 6;
  const int q = blockIdx.x * 4 + wid;
  const float* mrow = multi + (size_t)q * 1536;
  const float* hrow = hsbuf + (size_t)q * 1536;
  float acc = 0.f;
  #pragma unroll
  for (int i = 0; i < 24; ++i){
    int d = lane + 64 * i;
    acc += mrow[d] * Wad[d] + hrow[d] * Wad[1536 + d];
  }
  acc = red64_sum(acc) + badp[0];
  const float sig = 1.f / (1.f + __expf(-acc));
  const float f = BLENDF * sig;
  u16* brow = blended + (size_t)q * 1536;
  #pragma unroll
  for (int i = 0; i < 24; ++i){
    int d = lane + 64 * i;
    brow[d] = f2bf(f * mrow[d] + hrow[d]);
  }
}

// ---------------- launch ----------------

extern "C" void kernel_launch(void* const* d_in, const int* in_sizes, int n_in,
                              void* d_out, int out_size, void* d_ws, size_t ws_size,
                              hipStream_t stream)
{
  (void)in_sizes; (void)n_in; (void)out_size; (void)ws_size;
  const float* hs   = (const float*)d_in[0];
  const float* enc  = (const float*)d_in[1];
  const float* pics = (const float*)d_in[2];
  const float* clip = (const float*)d_in[3];
  const float* Wq   = (const float*)d_in[4];  const float* bq   = (const float*)d_in[5];
  const float* Wk   = (const float*)d_in[6];  const float* bk   = (const float*)d_in[7];
  const float* Wv   = (const float*)d_in[8];  const float* bv   = (const float*)d_in[9];
  const float* Waq  = (const float*)d_in[10]; const float* baq  = (const float*)d_in[11];
  const float* Wak  = (const float*)d_in[12]; const float* bak  = (const float*)d_in[13];
  const float* Wav  = (const float*)d_in[14]; const float* bav  = (const float*)d_in[15];
  const float* Wkl  = (const float*)d_in[16]; const float* Wvl  = (const float*)d_in[17];
  const float* Wsl  = (const float*)d_in[18]; const float* bsl  = (const float*)d_in[19];
  const float* Wad  = (const float*)d_in[20]; const float* bad  = (const float*)d_in[21];
  const float* Wout = (const float*)d_in[22]; const float* bout = (const float*)d_in[23];
  const float* Wadd = (const float*)d_in[24]; const float* badd = (const float*)d_in[25];

  char* ws = (char*)d_ws;
  size_t off = 0;
  auto alloc = [&](size_t b){ void* p = ws + off; off += (b + 255) & ~(size_t)255; return p; };

  u16* hs_bf  = (u16*)alloc((size_t)2048*1536*2);
  u16* enc_bf = (u16*)alloc((size_t)154*1536*2);
  u16* pics_bf= (u16*)alloc((size_t)256*1024*2);
  // WqT..WavT (6 x 4.7MB, contiguous) are DEAD after the QKV/enc GEMMs;
  // reused as the split-attn partial-O buffer (27.5MB <= 28.3MB).
  u16* WqT  = (u16*)alloc((size_t)1536*1536*2);
  u16* WkT  = (u16*)alloc((size_t)1536*1536*2);
  u16* WvT  = (u16*)alloc((size_t)1536*1536*2);
  u16* WaqT = (u16*)alloc((size_t)1536*1536*2);
  u16* WakT = (u16*)alloc((size_t)1536*1536*2);
  u16* WavT = (u16*)alloc((size_t)1536*1536*2);
  u16* WoutT= (u16*)alloc((size_t)1536*1536*2);
  u16* WaddT= (u16*)alloc((size_t)1536*1536*2);
  u16* WklT = (u16*)alloc((size_t)1536*1024*2);
  u16* WvlT = (u16*)alloc((size_t)1536*1024*2);
  u16* q2   = (u16*)alloc((size_t)NPAD*1536*2);
  u16* k2   = (u16*)alloc((size_t)NPAD*1536*2);
  u16* v2   = (u16*)alloc((size_t)NPAD*1536*2);
  u16* v2P  = (u16*)alloc((size_t)1536*NPAD*2);
  u16* Kp   = (u16*)alloc((size_t)256*1536*2);
  u16* Vp   = (u16*)alloc((size_t)256*1536*2);
  u16* VpP  = (u16*)alloc((size_t)1536*256*2);
  float* wvec   = (float*)alloc((size_t)1536*4);
  float* multi  = (float*)alloc((size_t)2048*1536*4);
  float* hsbuf  = (float*)alloc((size_t)NTOT*1536*4);
  u16* blended  = (u16*)alloc((size_t)2048*1536*2);
  u16* hstxt    = (u16*)alloc((size_t)154*1536*2);
  float2* mlbuf = (float2*)alloc((size_t)2*24*2240*8);
  float* Opart  = (float*)WqT;   // alias: dead after enc GEMM

  const long padn8 = ((long)(NPAD - NTOT) * 1536) / 8;   // 19584
  k_zeropad<<<dim3((padn8 + 255) / 256), 256, 0, stream>>>(
      q2 + (size_t)NTOT*1536, k2 + (size_t)NTOT*1536, v2 + (size_t)NTOT*1536, padn8);

  k_cast<<<dim3(3072), 256, 0, stream>>>(hs,   hs_bf,  (long)2048*1536);
  k_cast<<<dim3(231),  256, 0, stream>>>(enc,  enc_bf, (long)154*1536);
  k_cast<<<dim3(256),  256, 0, stream>>>(pics, pics_bf,(long)256*1024);

  WT10 wts;
  wts.w[0] = {Wq,   WqT,   1536};
  wts.w[1] = {Wk,   WkT,   1536};
  wts.w[2] = {Wv,   WvT,   1536};
  wts.w[3] = {Waq,  WaqT,  1536};
  wts.w[4] = {Wak,  WakT,  1536};
  wts.w[5] = {Wav,  WavT,  1536};
  wts.w[6] = {Wout, WoutT, 1536};
  wts.w[7] = {Wadd, WaddT, 1536};
  wts.w[8] = {Wkl,  WklT,  1024};
  wts.w[9] = {Wvl,  WvlT,  1024};
  k_transpose_w<<<dim3(48, 48, 10), dim3(32, 8), 0, stream>>>(wts);

  // QKV: 64x128 tiles -> 1152 blocks; region 16x9 per XCD (nCx=4)
  GOuts oqkv; oqkv.C[0] = q2; oqkv.C[1] = k2; oqkv.C[2] = v2;
  oqkv.b[0] = bq; oqkv.b[1] = bk; oqkv.b[2] = bv;
  k_gemm<64,0><<<dim3(1152), 256, 0, stream>>>(hs_bf, 1536, WqT, 1536, oqkv, 1536, 2048, 4608, 1536, 1, 4, 16, 9);

  GOuts oenc; oenc.C[0] = q2 + (size_t)2048*1536; oenc.C[1] = k2 + (size_t)2048*1536; oenc.C[2] = v2 + (size_t)2048*1536;
  oenc.b[0] = baq; oenc.b[1] = bak; oenc.b[2] = bav;
  k_gemm<64,0><<<dim3(36, 3), 256, 0, stream>>>(enc_bf, 1536, WaqT, 1536, oenc, 1536, 154, 4608, 1536, 0, 0, 0, 0);

  GOuts okv; okv.C[0] = Kp; okv.C[1] = Vp; okv.C[2] = nullptr;
  okv.b[0] = nullptr; okv.b[1] = nullptr; okv.b[2] = nullptr;
  k_gemm<64,0><<<dim3(24, 4), 256, 0, stream>>>(pics_bf, 1024, WklT, 1024, okv, 1536, 256, 3072, 1024, 0, 0, 0, 0);

  k_wvec<<<dim3(6), 256, 0, stream>>>(Kp, Wsl, wvec);

  k_transpose_vp<<<dim3(48, NPAD/32), dim3(32, 8), 0, stream>>>(v2, v2P, NPAD, 1536);
  k_transpose_vp<<<dim3(48, 8),       dim3(32, 8), 0, stream>>>(Vp, VpP, 256, 1536);

  k_cross_attn<<<dim3(32, 24), 256, 0, stream>>>(q2, Kp, VpP, clip, Wsl, bsl, wvec, multi);
  // split-K self-attn: 1680 blocks (2 halves per (head,qb)), then merge
  k_self_attn_split<<<dim3(1680), 256, 0, stream>>>(q2, k2, v2P, Opart, mlbuf);
  k_merge<<<dim3(NTOT), 256, 0, stream>>>(Opart, mlbuf, hsbuf);

  k_adaptive<<<dim3(512), 256, 0, stream>>>(multi, hsbuf, Wad, bad, blended);
  k_cast<<<dim3(231), 256, 0, stream>>>(hsbuf + (size_t)2048*1536, hstxt, (long)154*1536);

  // Wout: 64x128 tiles -> 384 blocks; region 8x6 per XCD (nCx=2)
  GOuts oout; oout.C[0] = d_out; oout.C[1] = nullptr; oout.C[2] = nullptr;
  oout.b[0] = bout; oout.b[1] = nullptr; oout.b[2] = nullptr;
  k_gemm<64,1><<<dim3(384), 256, 0, stream>>>(blended, 1536, WoutT, 1536, oout, 1536, 2048, 1536, 1536, 1, 2, 8, 6);

  GOuts oadd; oadd.C[0] = (float*)d_out + (size_t)2048*1536; oadd.C[1] = nullptr; oadd.C[2] = nullptr;
  oadd.b[0] = badd; oadd.b[1] = nullptr; oadd.b[2] = nullptr;
  k_gemm<64,1><<<dim3(12, 3), 256, 0, stream>>>(hstxt, 1536, WaddT, 1536, oadd, 1536, 154, 1536, 1536, 0, 0, 0, 0);
}

// Round 13
// 270.121 us; speedup vs baseline: 1.6772x; 1.1013x over previous
//
#include <hip/hip_runtime.h>

typedef unsigned short u16;
typedef unsigned int u32;
typedef __attribute__((ext_vector_type(4))) short bf16x4;
typedef __attribute__((ext_vector_type(8))) short bf16x8;
typedef __attribute__((ext_vector_type(4))) float f32x4;

#define SCALE 0.125f
#define BLENDF 0.4875f
#define NTOT 2202
#define NPAD 2304
#define L2E 1.44269504f

#define SBAR()  __builtin_amdgcn_s_barrier()
#define SCHED0() __builtin_amdgcn_sched_barrier(0)
#define VMWAIT(n) asm volatile("s_waitcnt vmcnt(" #n ")" ::: "memory")

__device__ __forceinline__ u16 f2bf(float x){
  union { float f; unsigned u; } v; v.f = x;
  unsigned r = v.u + 0x7fffu + ((v.u >> 16) & 1u);
  return (u16)(r >> 16);
}
__device__ __forceinline__ float bf2f(u16 b){
  union { unsigned u; float f; } v; v.u = (u32)b << 16; return v.f;
}
// hw packer: 2 f32 -> 2 bf16 (RNE), src0 in low half
__device__ __forceinline__ u32 cvtpk(float a, float b){
  u32 r;
  asm("v_cvt_pk_bf16_f32 %0, %1, %2" : "=v"(r) : "v"(a), "v"(b));
  return r;
}

__device__ __forceinline__ float fexp2(float x){
#if __has_builtin(__builtin_amdgcn_exp2f)
  return __builtin_amdgcn_exp2f(x);
#else
  return __expf(x * 0.6931472f);
#endif
}

__device__ __forceinline__ f32x4 MFMA(bf16x8 a, bf16x8 b, f32x4 c){
  return __builtin_amdgcn_mfma_f32_16x16x32_bf16(a, b, c, 0, 0, 0);
}

// async global->LDS, 16B per lane; LDS dest is wave-uniform base (+lane*16 implicit)
__device__ __forceinline__ void gload16(const u16* g, u16* l){
  __builtin_amdgcn_global_load_lds(
    (const __attribute__((address_space(1))) u32*)g,
    (__attribute__((address_space(3))) u32*)l, 16, 0, 0);
}

__device__ __forceinline__ float red64_sum(float x){
  x += __shfl_xor(x, 1, 64);
  x += __shfl_xor(x, 2, 64);
  x += __shfl_xor(x, 4, 64);
  x += __shfl_xor(x, 8, 64);
  x += __shfl_xor(x, 16, 64);
  x += __shfl_xor(x, 32, 64);
  return x;
}
// reduce over the l4 axis (lanes sharing the same lane&15)
__device__ __forceinline__ float redl4_sum(float x){
  x += __shfl_xor(x, 16, 64);
  x += __shfl_xor(x, 32, 64);
  return x;
}
__device__ __forceinline__ float redl4_max(float x){
  x = fmaxf(x, __shfl_xor(x, 16, 64));
  x = fmaxf(x, __shfl_xor(x, 32, 64));
  return x;
}

// ---------------- fused input prep: casts + zero-pad (1 launch) ----------------

__device__ __forceinline__ void cast8(const float* in, u16* out){
  float4 a = *(const float4*)(in);
  float4 b = *(const float4*)(in + 4);
  bf16x8 v = { (short)f2bf(a.x), (short)f2bf(a.y), (short)f2bf(a.z), (short)f2bf(a.w),
               (short)f2bf(b.x), (short)f2bf(b.y), (short)f2bf(b.z), (short)f2bf(b.w) };
  *(bf16x8*)(out) = v;
}

__global__ __launch_bounds__(256) void k_prep(
  const float* __restrict__ hs, const float* __restrict__ enc, const float* __restrict__ pics,
  u16* __restrict__ hs_bf, u16* __restrict__ enc_bf, u16* __restrict__ pics_bf,
  u16* __restrict__ q2p, u16* __restrict__ k2p, u16* __restrict__ v2p)
{
  long i = (long)blockIdx.x * 256 + threadIdx.x;      // unit = 8 elements
  const long nh = (long)2048*1536/8, ne = (long)154*1536/8;
  const long np = (long)256*1024/8,  nz = (long)(NPAD-NTOT)*1536/8;
  if (i < nh){ cast8(hs + i*8, hs_bf + i*8); return; }
  i -= nh;
  if (i < ne){ cast8(enc + i*8, enc_bf + i*8); return; }
  i -= ne;
  if (i < np){ cast8(pics + i*8, pics_bf + i*8); return; }
  i -= np;
  if (i < 3*nz){
    const int which = (int)(i / nz);
    const long j = (i - (long)which*nz) * 8;
    u16* d = which == 0 ? q2p : which == 1 ? k2p : v2p;
    const bf16x8 z = {0,0,0,0,0,0,0,0};
    *(bf16x8*)(d + j) = z;
  }
}

// w_vec[d] = sum_k Wsl[k] * Kp[k][d]  (rank-1 gate precompute)
__global__ __launch_bounds__(256) void k_wvec(const u16* __restrict__ Kp,
                                              const float* __restrict__ Wsl,
                                              float* __restrict__ wvec){
  const int d = blockIdx.x * 256 + threadIdx.x;
  float acc = 0.f;
  for (int k = 0; k < 256; ++k)
    acc += Wsl[k] * bf2f(Kp[(size_t)k * 1536 + d]);
  wvec[d] = acc;
}

struct WT { const float* s; u16* d; int K; };
struct WT10 { WT w[10]; };

// in: [K][1536] fp32 -> out: [1536][K] bf16. 64x64 tiles, fully coalesced both sides.
__global__ __launch_bounds__(256) void k_transpose_w(WT10 ws){
  const WT t = ws.w[blockIdx.z];
  const int r0 = blockIdx.y * 64;
  if (r0 >= t.K) return;
  const int c0 = blockIdx.x * 64;
  __shared__ float tile[64][65];
  const int x = threadIdx.x & 63, y = threadIdx.x >> 6;
  #pragma unroll
  for (int k = 0; k < 16; ++k)
    tile[y + 4*k][x] = t.s[(size_t)(r0 + y + 4*k) * 1536 + c0 + x];
  __syncthreads();
  #pragma unroll
  for (int k = 0; k < 16; ++k)
    t.d[(size_t)(c0 + y + 4*k) * t.K + r0 + x] = f2bf(tile[x][y + 4*k]);
}

// in: [R][C] bf16 -> out[C][R] bf16 with columns PERMUTED within each 32-block:
// out[d][32b + p] = in[32b + k(p)][d], k(p) = ((p>>2)&1)*16 + (p>>3)*4 + (p&3)
// == PV A-fragment k-slot map, so a contiguous read is the B-fragment.
__global__ __launch_bounds__(256) void k_transpose_vp(const u16* __restrict__ in,
                                                      u16* __restrict__ out, int R, int C){
  const int r0 = blockIdx.y * 32, c0 = blockIdx.x * 32;
  __shared__ u16 tile[32][34];
  const int x = threadIdx.x, y = threadIdx.y;
  #pragma unroll
  for (int k = 0; k < 4; ++k)
    tile[y + 8*k][x] = in[(size_t)(r0 + y + 8*k) * C + c0 + x];
  __syncthreads();
  const int kx = (((x >> 2) & 1) << 4) + ((x >> 3) << 2) + (x & 3);
  #pragma unroll
  for (int k = 0; k < 4; ++k)
    out[(size_t)(c0 + y + 8*k) * R + r0 + x] = tile[kx][y + 8*k];
}

// ---------------- GEMM: C = A[M][K] * BT[N][K]^T, fused N-segments ----------------
// Row-linear staging (8 full cache lines/instr) + both-sides XOR swizzle (2-way alias, free).

struct GOuts { void* C[3]; const float* b[3]; };

template<int BM, int OUTF32>
__global__ __launch_bounds__(256, 4) void k_gemm(
  const u16* __restrict__ A, int lda,
  const u16* __restrict__ BT, int ldb,
  GOuts o, int ldc, int M, int N, int K,
  int gx, int nCx, int rBlk, int cBlk)
{
  constexpr int MW = BM / 32;
  constexpr int AI = BM / 32;
  __shared__ alignas(1024) u16 As[BM * 64];
  __shared__ alignas(1024) u16 Bs[128 * 64];
  const int tid = threadIdx.x, lane = tid & 63, w = tid >> 6;
  const int l15 = lane & 15, l4 = lane >> 4;
  const int l8 = lane >> 3, l7 = lane & 7;
  const int cbE = (l7 ^ l8) * 8;

  int bx, by;
  if (gx){
    const int xcd = blockIdx.x & 7, slot = blockIdx.x >> 3;
    const int rx = xcd / nCx, cx = xcd - rx * nCx;
    by = rx * rBlk + slot / cBlk;
    bx = cx * cBlk + slot % cBlk;
  } else {
    bx = blockIdx.x; by = blockIdx.y;
  }
  const int m0 = by * BM, n0 = bx * 128;
  const int wm = (w >> 1) * (BM / 2), wn = (w & 1) * 64;

  f32x4 acc[MW][4];
  #pragma unroll
  for (int i = 0; i < MW; ++i)
    #pragma unroll
    for (int j = 0; j < 4; ++j)
      acc[i][j] = (f32x4){0.f, 0.f, 0.f, 0.f};

  for (int k0 = 0; k0 < K; k0 += 64){
    #pragma unroll
    for (int c = 0; c < AI; ++c){
      const int a = w * AI + c;
      const int ar = min(m0 + a*8 + l8, M - 1);
      gload16(A + (size_t)ar * lda + k0 + cbE, &As[a * 512]);
    }
    #pragma unroll
    for (int c = 0; c < 4; ++c){
      const int b = w * 4 + c;
      const int br = min(n0 + b*8 + l8, N - 1);
      gload16(BT + (size_t)br * ldb + k0 + cbE, &Bs[b * 512]);
    }
    VMWAIT(0);
    __syncthreads();
    #pragma unroll
    for (int kk = 0; kk < 2; ++kk){
      const int sz = ((kk*4 + l4) ^ (l15 & 7)) * 8;
      bf16x8 a[MW], b[4];
      #pragma unroll
      for (int m = 0; m < MW; ++m)
        a[m] = *(const bf16x8*)(As + (wm + m*16 + l15) * 64 + sz);
      #pragma unroll
      for (int n = 0; n < 4; ++n)
        b[n] = *(const bf16x8*)(Bs + (wn + n*16 + l15) * 64 + sz);
      #pragma unroll
      for (int m = 0; m < MW; ++m)
        #pragma unroll
        for (int n = 0; n < 4; ++n)
          acc[m][n] = MFMA(a[m], b[n], acc[m][n]);
    }
    __syncthreads();
  }

  #pragma unroll
  for (int n = 0; n < 4; ++n){
    const int colg = n0 + wn + n*16 + l15;
    const int sel = colg / 1536;
    const int col = colg - sel * 1536;
    const float* bp = o.b[sel];
    const float bi = bp ? bp[col] : 0.f;
    #pragma unroll
    for (int m = 0; m < MW; ++m){
      const int row0 = m0 + wm + m*16 + l4*4;
      #pragma unroll
      for (int r = 0; r < 4; ++r){
        const int row = row0 + r;
        if (row < M){
          float val = acc[m][n][r] + bi;
          if (OUTF32) ((float*)o.C[sel])[(size_t)row * ldc + col] = val;
          else        ((u16*)o.C[sel])[(size_t)row * ldc + col] = f2bf(val);
        }
      }
    }
  }
}

// ---------------- cross attention: flash-style, rank-1 gate ----------------

__global__ __launch_bounds__(256, 4) void k_cross_attn(
  const u16* __restrict__ Q,
  const u16* __restrict__ Kp,    // [256][1536]
  const u16* __restrict__ VpP,   // [1536][256], cols pi-permuted per 32-block
  const float* __restrict__ clip,
  const float* __restrict__ Wsl, // [512]
  const float* __restrict__ bslp,
  const float* __restrict__ wvec,// [1536]
  float* __restrict__ multi)     // [2048][1536]
{
  const int h = blockIdx.y;
  const int tid = threadIdx.x, lane = tid & 63, w = tid >> 6;
  const int l15 = lane & 15, l4 = lane >> 4;
  const int l8 = lane >> 3, l7 = lane & 7;
  const int cbE = (l7 ^ l8) * 8;
  const int qrow = blockIdx.x * 64 + w * 16 + l15;

  __shared__ alignas(1024) u16 Ks[2][4096];
  __shared__ alignas(1024) u16 VTs[2][4096];
  __shared__ float clip_l[256];
  if (tid < 256) clip_l[tid] = clip[tid];

  float cd = 0.f;
  for (int p = lane; p < 256; p += 64) cd += clip[p] * Wsl[256 + p];
  cd = red64_sum(cd);
  const float gate_c = cd + bslp[0];

  bf16x8 qf[2];
  #pragma unroll
  for (int kk = 0; kk < 2; ++kk)
    qf[kk] = *(const bf16x8*)(Q + (size_t)qrow * 1536 + h*64 + kk*32 + l4*8);

  float gd = 0.f;
  #pragma unroll
  for (int kk = 0; kk < 2; ++kk){
    const float4 w0 = *(const float4*)(wvec + h*64 + kk*32 + l4*8);
    const float4 w1 = *(const float4*)(wvec + h*64 + kk*32 + l4*8 + 4);
    gd += w0.x * bf2f((u16)qf[kk][0]) + w0.y * bf2f((u16)qf[kk][1]);
    gd += w0.z * bf2f((u16)qf[kk][2]) + w0.w * bf2f((u16)qf[kk][3]);
    gd += w1.x * bf2f((u16)qf[kk][4]) + w1.y * bf2f((u16)qf[kk][5]);
    gd += w1.z * bf2f((u16)qf[kk][6]) + w1.w * bf2f((u16)qf[kk][7]);
  }
  const float gate = SCALE * redl4_sum(gd) + gate_c;

  f32x4 O[4];
  #pragma unroll
  for (int nb = 0; nb < 4; ++nb) O[nb] = (f32x4){0.f, 0.f, 0.f, 0.f};
  float m_ = -1e30f, l_ = 0.f;          // l_ lane-local; reduced once at end

  const u16* vpb = VpP + (size_t)(h*64) * 256;

  auto STAGE = [&](int buf, int kt0){
    #pragma unroll
    for (int c = 0; c < 2; ++c){
      const int a = w*2 + c;
      const int row = a*8 + l8;
      gload16(Kp + (size_t)(kt0 + row) * 1536 + h*64 + cbE, &Ks[buf][a * 512]);
      gload16(vpb + (size_t)row * 256 + kt0 + cbE, &VTs[buf][a * 512]);
    }
  };

  STAGE(0, 0);
  __syncthreads();

  int buf = 0;
  for (int nt = 0; nt < 4; ++nt){
    if (nt + 1 < 4){
      STAGE(buf ^ 1, (nt + 1) * 64);
      VMWAIT(4);
    } else {
      VMWAIT(0);
    }
    SCHED0();
    SBAR();
    SCHED0();
    const int kt0 = nt * 64;

    f32x4 s[4];
    __builtin_amdgcn_s_setprio(1);
    #pragma unroll
    for (int n4 = 0; n4 < 4; ++n4){
      f32x4 t = {0.f, 0.f, 0.f, 0.f};
      #pragma unroll
      for (int kk = 0; kk < 2; ++kk){
        const int sz = ((kk*4 + l4) ^ (l15 & 7)) * 8;
        bf16x8 kf = *(const bf16x8*)(&Ks[buf][(n4*16 + l15) * 64 + sz]);
        t = MFMA(kf, qf[kk], t);
      }
      s[n4] = t;
    }
    __builtin_amdgcn_s_setprio(0);

    #pragma unroll
    for (int n4 = 0; n4 < 4; ++n4){
      const float4 cv = *(const float4*)&clip_l[kt0 + n4*16 + l4*4];
      s[n4][0] = fmaf(s[n4][0], SCALE, gate * cv.x);
      s[n4][1] = fmaf(s[n4][1], SCALE, gate * cv.y);
      s[n4][2] = fmaf(s[n4][2], SCALE, gate * cv.z);
      s[n4][3] = fmaf(s[n4][3], SCALE, gate * cv.w);
    }

    float mt = -1e30f;
    #pragma unroll
    for (int n4 = 0; n4 < 4; ++n4)
      mt = fmaxf(mt, fmaxf(fmaxf(s[n4][0], s[n4][1]), fmaxf(s[n4][2], s[n4][3])));
    mt = redl4_max(mt);

    const float mn = fmaxf(m_, mt);
    const float al = fexp2((m_ - mn) * L2E);
    m_ = mn;
    l_ *= al;
    float alo[4];
    #pragma unroll
    for (int r = 0; r < 4; ++r) alo[r] = __shfl(al, l4*4 + r, 16);
    #pragma unroll
    for (int nb = 0; nb < 4; ++nb)
      #pragma unroll
      for (int r = 0; r < 4; ++r) O[nb][r] *= alo[r];

    const float m2 = m_ * L2E;
    #pragma unroll
    for (int n4 = 0; n4 < 4; ++n4)
      #pragma unroll
      for (int r = 0; r < 4; ++r){
        float pv = fexp2(fmaf(s[n4][r], L2E, -m2));
        l_ += pv;
        s[n4][r] = pv;
      }

    __builtin_amdgcn_s_setprio(1);
    #pragma unroll
    for (int kk = 0; kk < 2; ++kk){
      const int sz = ((kk*4 + l4) ^ (l15 & 7)) * 8;
      union { u32 w4[4]; bf16x8 v; } U;
      U.w4[0] = cvtpk(s[2*kk][0],   s[2*kk][1]);
      U.w4[1] = cvtpk(s[2*kk][2],   s[2*kk][3]);
      U.w4[2] = cvtpk(s[2*kk+1][0], s[2*kk+1][1]);
      U.w4[3] = cvtpk(s[2*kk+1][2], s[2*kk+1][3]);
      #pragma unroll
      for (int nb = 0; nb < 4; ++nb){
        bf16x8 vt = *(const bf16x8*)(&VTs[buf][(nb*16 + l15) * 64 + sz]);
        O[nb] = MFMA(U.v, vt, O[nb]);
      }
    }
    __builtin_amdgcn_s_setprio(0);

    SCHED0();
    SBAR();
    buf ^= 1;
  }

  const float inv = 1.f / redl4_sum(l_);
  float li[4];
  #pragma unroll
  for (int r = 0; r < 4; ++r) li[r] = __shfl(inv, l4*4 + r, 16);
  #pragma unroll
  for (int r = 0; r < 4; ++r){
    const int row = blockIdx.x * 64 + w * 16 + l4*4 + r;
    #pragma unroll
    for (int nb = 0; nb < 4; ++nb)
      multi[(size_t)row * 1536 + h*64 + nb*16 + l15] = O[nb][r] * li[r];
  }
}

// ---------------- self attention: flash split-K (2 halves), partials merged later ----------------

__global__ __launch_bounds__(256, 4) void k_self_attn_split(
  const u16* __restrict__ q2,   // [2304][1536]
  const u16* __restrict__ k2,   // [2304][1536]
  const u16* __restrict__ v2P,  // [1536][2304], cols pi-permuted per 32-block
  float* __restrict__ Opart,    // [2][2240][1536] unnormalized
  float2* __restrict__ ml)      // [2][24][2240] (m, l)
{
  const int p = blockIdx.x;
  const int slot = p >> 3;
  const int h   = (p & 7) * 3 + slot / 70;
  const int rem = slot % 70;
  const int qb = rem >> 1, half = rem & 1;
  const int nt0 = half * 18, ntE = half ? 35 : 18;
  const int tid = threadIdx.x, lane = tid & 63, w = tid >> 6;
  const int l15 = lane & 15, l4 = lane >> 4;
  const int l8 = lane >> 3, l7 = lane & 7;
  const int cbE = (l7 ^ l8) * 8;
  const int qrow = qb * 64 + w * 16 + l15;

  __shared__ alignas(1024) u16 Ks[2][4096];
  __shared__ alignas(1024) u16 VTs[2][4096];

  bf16x8 qf[2];
  #pragma unroll
  for (int kk = 0; kk < 2; ++kk)
    qf[kk] = *(const bf16x8*)(q2 + (size_t)qrow * 1536 + h*64 + kk*32 + l4*8);

  f32x4 O[4];
  #pragma unroll
  for (int nb = 0; nb < 4; ++nb) O[nb] = (f32x4){0.f, 0.f, 0.f, 0.f};
  float m_ = -1e30f, l_ = 0.f;          // lane-local l; reduced at end
  const float C2 = SCALE * L2E;
  const float THR = 44.36f;             // 8 / C2

  const u16* kp  = k2 + h*64;
  const u16* vp0 = v2P + (size_t)(h*64) * NPAD;

  auto STAGE = [&](int buf, int kt0){
    #pragma unroll
    for (int c = 0; c < 2; ++c){
      const int a = w*2 + c;
      const int row = a*8 + l8;
      gload16(kp + (size_t)(kt0 + row) * 1536 + cbE, &Ks[buf][a * 512]);
      gload16(vp0 + (size_t)row * NPAD + kt0 + cbE, &VTs[buf][a * 512]);
    }
  };

  STAGE(0, nt0 * 64);
  __syncthreads();

  int buf = 0;
  for (int nt = nt0; nt < ntE; ++nt){
    if (nt + 1 < ntE){
      STAGE(buf ^ 1, (nt + 1) * 64);
      VMWAIT(4);
    } else {
      VMWAIT(0);
    }
    SCHED0();
    SBAR();
    SCHED0();
    const int kt0 = nt * 64;

    f32x4 s[4];
    __builtin_amdgcn_s_setprio(1);
    #pragma unroll
    for (int n4 = 0; n4 < 4; ++n4){
      f32x4 t = {0.f, 0.f, 0.f, 0.f};
      #pragma unroll
      for (int kk = 0; kk < 2; ++kk){
        const int sz = ((kk*4 + l4) ^ (l15 & 7)) * 8;
        bf16x8 kf = *(const bf16x8*)(&Ks[buf][(n4*16 + l15) * 64 + sz]);
        t = MFMA(kf, qf[kk], t);
      }
      s[n4] = t;
    }
    __builtin_amdgcn_s_setprio(0);

    if (kt0 + 64 > NTOT){                       // only the global last tile
      #pragma unroll
      for (int n4 = 0; n4 < 4; ++n4){
        const int keyb = kt0 + n4*16 + l4*4;
        #pragma unroll
        for (int r = 0; r < 4; ++r)
          if (keyb + r >= NTOT) s[n4][r] = -1e30f;
      }
    }

    float mt = -1e30f;
    #pragma unroll
    for (int n4 = 0; n4 < 4; ++n4)
      mt = fmaxf(mt, fmaxf(fmaxf(s[n4][0], s[n4][1]), fmaxf(s[n4][2], s[n4][3])));
    mt = redl4_max(mt);

    if (__any(mt > m_ + THR)){                  // T13 defer-max
      const float mn = fmaxf(m_, mt);
      const float al = fexp2((m_ - mn) * C2);
      m_ = mn;
      l_ *= al;                                 // al uniform across l4-group
      float alo[4];
      #pragma unroll
      for (int r = 0; r < 4; ++r) alo[r] = __shfl(al, l4*4 + r, 16);
      #pragma unroll
      for (int nb = 0; nb < 4; ++nb)
        #pragma unroll
        for (int r = 0; r < 4; ++r) O[nb][r] *= alo[r];
    }
    const float m2 = m_ * C2;

    #pragma unroll
    for (int n4 = 0; n4 < 4; ++n4)
      #pragma unroll
      for (int r = 0; r < 4; ++r){
        float pv = fexp2(fmaf(s[n4][r], C2, -m2));
        l_ += pv;
        s[n4][r] = pv;
      }

    __builtin_amdgcn_s_setprio(1);
    #pragma unroll
    for (int kk = 0; kk < 2; ++kk){
      const int sz = ((kk*4 + l4) ^ (l15 & 7)) * 8;
      union { u32 w4[4]; bf16x8 v; } U;
      U.w4[0] = cvtpk(s[2*kk][0],   s[2*kk][1]);
      U.w4[1] = cvtpk(s[2*kk][2],   s[2*kk][3]);
      U.w4[2] = cvtpk(s[2*kk+1][0], s[2*kk+1][1]);
      U.w4[3] = cvtpk(s[2*kk+1][2], s[2*kk+1][3]);
      #pragma unroll
      for (int nb = 0; nb < 4; ++nb){
        bf16x8 vt = *(const bf16x8*)(&VTs[buf][(nb*16 + l15) * 64 + sz]);
        O[nb] = MFMA(U.v, vt, O[nb]);
      }
    }
    __builtin_amdgcn_s_setprio(0);

    SCHED0();
    SBAR();
    buf ^= 1;
  }

  const float lsum = redl4_sum(l_);
  float* Oh = Opart + (size_t)half * 2240 * 1536;
  #pragma unroll
  for (int r = 0; r < 4; ++r){
    const int row = qb*64 + w*16 + l4*4 + r;
    #pragma unroll
    for (int nb = 0; nb < 4; ++nb)
      Oh[(size_t)row * 1536 + h*64 + nb*16 + l15] = O[nb][r];
  }
  if (l4 == 0)
    ml[(size_t)half*24*2240 + h*2240 + qrow] = make_float2(m_, lsum);
}

// fused: split-K merge + adaptive gate/blend (img rows) or bf16 cast (txt rows)
__global__ __launch_bounds__(256) void k_merge_blend(
  const float* __restrict__ Op,     // [2][2240][1536]
  const float2* __restrict__ ml,    // [2][24][2240]
  const float* __restrict__ multi,  // [2048][1536]
  const float* __restrict__ Wad,    // [3072]
  const float* __restrict__ badp,
  u16* __restrict__ blended,        // [2048][1536] bf16
  u16* __restrict__ hstxt)          // [154][1536] bf16
{
  const int row = blockIdx.x;       // 0..2201
  const int t = threadIdx.x;
  const int lane = t & 63, wid = t >> 6;
  __shared__ float e0s[24], e1s[24], invs[24];
  __shared__ float redbuf[4];
  if (t < 24){
    const float2 a = ml[t*2240 + row];
    const float2 b = ml[24*2240 + t*2240 + row];
    const float M = fmaxf(a.x, b.x);
    const float C2 = SCALE * L2E;
    const float e0 = fexp2((a.x - M) * C2);
    const float e1 = fexp2((b.x - M) * C2);
    e0s[t] = e0; e1s[t] = e1;
    invs[t] = 1.f / (e0*a.y + e1*b.y);
  }
  __syncthreads();
  const float* O0 = Op + (size_t)row * 1536;
  const float* O1 = Op + (size_t)2240*1536 + (size_t)row * 1536;
  float mg[6];
  #pragma unroll
  for (int i = 0; i < 6; ++i){
    const int col = t + i*256;
    const int h = col >> 6;
    mg[i] = (e0s[h]*O0[col] + e1s[h]*O1[col]) * invs[h];
  }
  if (row < 2048){
    const float* mrow = multi + (size_t)row * 1536;
    float dot = 0.f;
    #pragma unroll
    for (int i = 0; i < 6; ++i){
      const int col = t + i*256;
      dot += mrow[col] * Wad[col] + mg[i] * Wad[1536 + col];
    }
    dot = red64_sum(dot);
    if (lane == 0) redbuf[wid] = dot;
    __syncthreads();
    const float tot = redbuf[0] + redbuf[1] + redbuf[2] + redbuf[3] + badp[0];
    const float f = BLENDF / (1.f + __expf(-tot));
    u16* brow = blended + (size_t)row * 1536;
    #pragma unroll
    for (int i = 0; i < 6; ++i){
      const int col = t + i*256;
      brow[col] = f2bf(fmaf(f, mrow[col], mg[i]));
    }
  } else {
    u16* orow = hstxt + (size_t)(row - 2048) * 1536;
    #pragma unroll
    for (int i = 0; i < 6; ++i)
      orow[t + i*256] = f2bf(mg[i]);
  }
}

// ---------------- launch ----------------

extern "C" void kernel_launch(void* const* d_in, const int* in_sizes, int n_in,
                              void* d_out, int out_size, void* d_ws, size_t ws_size,
                              hipStream_t stream)
{
  (void)in_sizes; (void)n_in; (void)out_size; (void)ws_size;
  const float* hs   = (const float*)d_in[0];
  const float* enc  = (const float*)d_in[1];
  const float* pics = (const float*)d_in[2];
  const float* clip = (const float*)d_in[3];
  const float* Wq   = (const float*)d_in[4];  const float* bq   = (const float*)d_in[5];
  const float* Wk   = (const float*)d_in[6];  const float* bk   = (const float*)d_in[7];
  const float* Wv   = (const float*)d_in[8];  const float* bv   = (const float*)d_in[9];
  const float* Waq  = (const float*)d_in[10]; const float* baq  = (const float*)d_in[11];
  const float* Wak  = (const float*)d_in[12]; const float* bak  = (const float*)d_in[13];
  const float* Wav  = (const float*)d_in[14]; const float* bav  = (const float*)d_in[15];
  const float* Wkl  = (const float*)d_in[16]; const float* Wvl  = (const float*)d_in[17];
  const float* Wsl  = (const float*)d_in[18]; const float* bsl  = (const float*)d_in[19];
  const float* Wad  = (const float*)d_in[20]; const float* bad  = (const float*)d_in[21];
  const float* Wout = (const float*)d_in[22]; const float* bout = (const float*)d_in[23];
  const float* Wadd = (const float*)d_in[24]; const float* badd = (const float*)d_in[25];

  char* ws = (char*)d_ws;
  size_t off = 0;
  auto alloc = [&](size_t b){ void* p = ws + off; off += (b + 255) & ~(size_t)255; return p; };

  u16* hs_bf  = (u16*)alloc((size_t)2048*1536*2);
  u16* enc_bf = (u16*)alloc((size_t)154*1536*2);
  u16* pics_bf= (u16*)alloc((size_t)256*1024*2);
  // WqT..WavT (6 x 4.7MB, contiguous) are DEAD after the QKV/enc GEMMs;
  // reused as the split-attn partial-O buffer (27.5MB <= 28.3MB).
  u16* WqT  = (u16*)alloc((size_t)1536*1536*2);
  u16* WkT  = (u16*)alloc((size_t)1536*1536*2);
  u16* WvT  = (u16*)alloc((size_t)1536*1536*2);
  u16* WaqT = (u16*)alloc((size_t)1536*1536*2);
  u16* WakT = (u16*)alloc((size_t)1536*1536*2);
  u16* WavT = (u16*)alloc((size_t)1536*1536*2);
  u16* WoutT= (u16*)alloc((size_t)1536*1536*2);
  u16* WaddT= (u16*)alloc((size_t)1536*1536*2);
  u16* WklT = (u16*)alloc((size_t)1536*1024*2);
  u16* WvlT = (u16*)alloc((size_t)1536*1024*2);
  u16* q2   = (u16*)alloc((size_t)NPAD*1536*2);
  u16* k2   = (u16*)alloc((size_t)NPAD*1536*2);
  u16* v2   = (u16*)alloc((size_t)NPAD*1536*2);
  u16* v2P  = (u16*)alloc((size_t)1536*NPAD*2);
  u16* Kp   = (u16*)alloc((size_t)256*1536*2);
  u16* Vp   = (u16*)alloc((size_t)256*1536*2);
  u16* VpP  = (u16*)alloc((size_t)1536*256*2);
  float* wvec   = (float*)alloc((size_t)1536*4);
  float* multi  = (float*)alloc((size_t)2048*1536*4);
  u16* blended  = (u16*)alloc((size_t)2048*1536*2);
  u16* hstxt    = (u16*)alloc((size_t)154*1536*2);
  float2* mlbuf = (float2*)alloc((size_t)2*24*2240*8);
  float* Opart  = (float*)WqT;   // alias: dead after enc GEMM

  // fused prep: 3 casts + zero-pad of q2/k2/v2 tail rows (1 launch)
  k_prep<<<dim3(2009), 256, 0, stream>>>(hs, enc, pics, hs_bf, enc_bf, pics_bf,
                                         q2 + (size_t)NTOT*1536,
                                         k2 + (size_t)NTOT*1536,
                                         v2 + (size_t)NTOT*1536);

  WT10 wts;
  wts.w[0] = {Wq,   WqT,   1536};
  wts.w[1] = {Wk,   WkT,   1536};
  wts.w[2] = {Wv,   WvT,   1536};
  wts.w[3] = {Waq,  WaqT,  1536};
  wts.w[4] = {Wak,  WakT,  1536};
  wts.w[5] = {Wav,  WavT,  1536};
  wts.w[6] = {Wout, WoutT, 1536};
  wts.w[7] = {Wadd, WaddT, 1536};
  wts.w[8] = {Wkl,  WklT,  1024};
  wts.w[9] = {Wvl,  WvlT,  1024};
  k_transpose_w<<<dim3(24, 24, 10), 256, 0, stream>>>(wts);

  // QKV: 64x128 tiles -> 1152 blocks; region 16x9 per XCD (nCx=4)
  GOuts oqkv; oqkv.C[0] = q2; oqkv.C[1] = k2; oqkv.C[2] = v2;
  oqkv.b[0] = bq; oqkv.b[1] = bk; oqkv.b[2] = bv;
  k_gemm<64,0><<<dim3(1152), 256, 0, stream>>>(hs_bf, 1536, WqT, 1536, oqkv, 1536, 2048, 4608, 1536, 1, 4, 16, 9);

  GOuts oenc; oenc.C[0] = q2 + (size_t)2048*1536; oenc.C[1] = k2 + (size_t)2048*1536; oenc.C[2] = v2 + (size_t)2048*1536;
  oenc.b[0] = baq; oenc.b[1] = bak; oenc.b[2] = bav;
  k_gemm<64,0><<<dim3(36, 3), 256, 0, stream>>>(enc_bf, 1536, WaqT, 1536, oenc, 1536, 154, 4608, 1536, 0, 0, 0, 0);

  GOuts okv; okv.C[0] = Kp; okv.C[1] = Vp; okv.C[2] = nullptr;
  okv.b[0] = nullptr; okv.b[1] = nullptr; okv.b[2] = nullptr;
  k_gemm<64,0><<<dim3(24, 4), 256, 0, stream>>>(pics_bf, 1024, WklT, 1024, okv, 1536, 256, 3072, 1024, 0, 0, 0, 0);

  k_wvec<<<dim3(6), 256, 0, stream>>>(Kp, Wsl, wvec);

  k_transpose_vp<<<dim3(48, NPAD/32), dim3(32, 8), 0, stream>>>(v2, v2P, NPAD, 1536);
  k_transpose_vp<<<dim3(48, 8),       dim3(32, 8), 0, stream>>>(Vp, VpP, 256, 1536);

  k_cross_attn<<<dim3(32, 24), 256, 0, stream>>>(q2, Kp, VpP, clip, Wsl, bsl, wvec, multi);
  // split-K self-attn: 1680 blocks (2 halves per (head,qb)), then fused merge+blend
  k_self_attn_split<<<dim3(1680), 256, 0, stream>>>(q2, k2, v2P, Opart, mlbuf);
  k_merge_blend<<<dim3(NTOT), 256, 0, stream>>>(Opart, mlbuf, multi, Wad, bad, blended, hstxt);

  // Wout: 64x128 tiles -> 384 blocks; region 8x6 per XCD (nCx=2)
  GOuts oout; oout.C[0] = d_out; oout.C[1] = nullptr; oout.C[2] = nullptr;
  oout.b[0] = bout; oout.b[1] = nullptr; oout.b[2] = nullptr;
  k_gemm<64,1><<<dim3(384), 256, 0, stream>>>(blended, 1536, WoutT, 1536, oout, 1536, 2048, 1536, 1536, 1, 2, 8, 6);

  GOuts oadd; oadd.C[0] = (float*)d_out + (size_t)2048*1536; oadd.C[1] = nullptr; oadd.C[2] = nullptr;
  oadd.b[0] = badd; oadd.b[1] = nullptr; oadd.b[2] = nullptr;
  k_gemm<64,1><<<dim3(12, 3), 256, 0, stream>>>(hstxt, 1536, WaddT, 1536, oadd, 1536, 154, 1536, 1536, 0, 0, 0, 0);
}

// Round 15
// 270.098 us; speedup vs baseline: 1.6774x; 1.0001x over previous
//
#include <hip/hip_runtime.h>

typedef unsigned short u16;
typedef unsigned int u32;
typedef __attribute__((ext_vector_type(4))) short bf16x4;
typedef __attribute__((ext_vector_type(8))) short bf16x8;
typedef __attribute__((ext_vector_type(4))) float f32x4;

#define SCALE 0.125f
#define BLENDF 0.4875f
#define NTOT 2202
#define NPAD 2304
#define L2E 1.44269504f

#define SBAR()  __builtin_amdgcn_s_barrier()
#define SCHED0() __builtin_amdgcn_sched_barrier(0)
#define VMWAIT(n) asm volatile("s_waitcnt vmcnt(" #n ")" ::: "memory")

__device__ __forceinline__ u16 f2bf(float x){
  union { float f; unsigned u; } v; v.f = x;
  unsigned r = v.u + 0x7fffu + ((v.u >> 16) & 1u);
  return (u16)(r >> 16);
}
__device__ __forceinline__ float bf2f(u16 b){
  union { unsigned u; float f; } v; v.u = (u32)b << 16; return v.f;
}
// hw packer: 2 f32 -> 2 bf16 (RNE), src0 in low half
__device__ __forceinline__ u32 cvtpk(float a, float b){
  u32 r;
  asm("v_cvt_pk_bf16_f32 %0, %1, %2" : "=v"(r) : "v"(a), "v"(b));
  return r;
}

__device__ __forceinline__ float fexp2(float x){
#if __has_builtin(__builtin_amdgcn_exp2f)
  return __builtin_amdgcn_exp2f(x);
#else
  return __expf(x * 0.6931472f);
#endif
}

__device__ __forceinline__ f32x4 MFMA(bf16x8 a, bf16x8 b, f32x4 c){
  return __builtin_amdgcn_mfma_f32_16x16x32_bf16(a, b, c, 0, 0, 0);
}

// async global->LDS, 16B per lane; LDS dest is wave-uniform base (+lane*16 implicit)
__device__ __forceinline__ void gload16(const u16* g, u16* l){
  __builtin_amdgcn_global_load_lds(
    (const __attribute__((address_space(1))) u32*)g,
    (__attribute__((address_space(3))) u32*)l, 16, 0, 0);
}

__device__ __forceinline__ float red64_sum(float x){
  x += __shfl_xor(x, 1, 64);
  x += __shfl_xor(x, 2, 64);
  x += __shfl_xor(x, 4, 64);
  x += __shfl_xor(x, 8, 64);
  x += __shfl_xor(x, 16, 64);
  x += __shfl_xor(x, 32, 64);
  return x;
}
// reduce over the l4 axis (lanes sharing the same lane&15)
__device__ __forceinline__ float redl4_sum(float x){
  x += __shfl_xor(x, 16, 64);
  x += __shfl_xor(x, 32, 64);
  return x;
}
__device__ __forceinline__ float redl4_max(float x){
  x = fmaxf(x, __shfl_xor(x, 16, 64));
  x = fmaxf(x, __shfl_xor(x, 32, 64));
  return x;
}

// ---------------- fused input prep: casts + zero-pad (1 launch) ----------------

__device__ __forceinline__ void cast8(const float* in, u16* out){
  float4 a = *(const float4*)(in);
  float4 b = *(const float4*)(in + 4);
  bf16x8 v = { (short)f2bf(a.x), (short)f2bf(a.y), (short)f2bf(a.z), (short)f2bf(a.w),
               (short)f2bf(b.x), (short)f2bf(b.y), (short)f2bf(b.z), (short)f2bf(b.w) };
  *(bf16x8*)(out) = v;
}

__global__ __launch_bounds__(256) void k_prep(
  const float* __restrict__ hs, const float* __restrict__ enc, const float* __restrict__ pics,
  u16* __restrict__ hs_bf, u16* __restrict__ enc_bf, u16* __restrict__ pics_bf,
  u16* __restrict__ q2p, u16* __restrict__ k2p, u16* __restrict__ v2p)
{
  long i = (long)blockIdx.x * 256 + threadIdx.x;      // unit = 8 elements
  const long nh = (long)2048*1536/8, ne = (long)154*1536/8;
  const long np = (long)256*1024/8,  nz = (long)(NPAD-NTOT)*1536/8;
  if (i < nh){ cast8(hs + i*8, hs_bf + i*8); return; }
  i -= nh;
  if (i < ne){ cast8(enc + i*8, enc_bf + i*8); return; }
  i -= ne;
  if (i < np){ cast8(pics + i*8, pics_bf + i*8); return; }
  i -= np;
  if (i < 3*nz){
    const int which = (int)(i / nz);
    const long j = (i - (long)which*nz) * 8;
    u16* d = which == 0 ? q2p : which == 1 ? k2p : v2p;
    const bf16x8 z = {0,0,0,0,0,0,0,0};
    *(bf16x8*)(d + j) = z;
  }
}

// w_vec[d] = sum_k Wsl[k] * Kp[k][d]  (rank-1 gate precompute)
__global__ __launch_bounds__(256) void k_wvec(const u16* __restrict__ Kp,
                                              const float* __restrict__ Wsl,
                                              float* __restrict__ wvec){
  const int d = blockIdx.x * 256 + threadIdx.x;
  float acc = 0.f;
  for (int k = 0; k < 256; ++k)
    acc += Wsl[k] * bf2f(Kp[(size_t)k * 1536 + d]);
  wvec[d] = acc;
}

struct WT { const float* s; u16* d; int K; };
struct WT10 { WT w[10]; };

// in: [K][1536] fp32 -> out: [1536][K] bf16. 64x64 tiles, fully coalesced both sides.
__global__ __launch_bounds__(256) void k_transpose_w(WT10 ws){
  const WT t = ws.w[blockIdx.z];
  const int r0 = blockIdx.y * 64;
  if (r0 >= t.K) return;
  const int c0 = blockIdx.x * 64;
  __shared__ float tile[64][65];
  const int x = threadIdx.x & 63, y = threadIdx.x >> 6;
  #pragma unroll
  for (int k = 0; k < 16; ++k)
    tile[y + 4*k][x] = t.s[(size_t)(r0 + y + 4*k) * 1536 + c0 + x];
  __syncthreads();
  #pragma unroll
  for (int k = 0; k < 16; ++k)
    t.d[(size_t)(c0 + y + 4*k) * t.K + r0 + x] = f2bf(tile[x][y + 4*k]);
}

// in: [R][C] bf16 -> out[C][R] bf16 with columns PERMUTED within each 32-block:
// out[d][32b + p] = in[32b + k(p)][d], k(p) = ((p>>2)&1)*16 + (p>>3)*4 + (p&3)
// == PV A-fragment k-slot map, so a contiguous read is the B-fragment.
__global__ __launch_bounds__(256) void k_transpose_vp(const u16* __restrict__ in,
                                                      u16* __restrict__ out, int R, int C){
  const int r0 = blockIdx.y * 32, c0 = blockIdx.x * 32;
  __shared__ u16 tile[32][34];
  const int x = threadIdx.x, y = threadIdx.y;
  #pragma unroll
  for (int k = 0; k < 4; ++k)
    tile[y + 8*k][x] = in[(size_t)(r0 + y + 8*k) * C + c0 + x];
  __syncthreads();
  const int kx = (((x >> 2) & 1) << 4) + ((x >> 3) << 2) + (x & 3);
  #pragma unroll
  for (int k = 0; k < 4; ++k)
    out[(size_t)(c0 + y + 8*k) * R + r0 + x] = tile[kx][y + 8*k];
}

// ---------------- multi-GEMM: up to 3 segment-fused GEMMs in ONE dispatch ----------------
// Row-linear staging (8 full cache lines/instr) + both-sides XOR swizzle (2-way alias, free).

struct GOuts { void* C[3]; const float* b[3]; };
struct GDesc {
  const u16* A; const u16* BT;
  GOuts o;
  int lda, ldb, ldc, M, N, K;
  int gx, nCx, rBlk, cBlk, nbx;
};

template<int OUTF32>
__global__ __launch_bounds__(256, 4) void k_gemm_multi(GDesc d0, GDesc d1, GDesc d2,
                                                       int n1, int n2)
{
  constexpr int BM = 64, MW = 2, AI = 2;
  __shared__ alignas(1024) u16 As[BM * 64];
  __shared__ alignas(1024) u16 Bs[128 * 64];
  GDesc d; int bid;
  if ((int)blockIdx.x < n1){ d = d0; bid = blockIdx.x; }
  else if ((int)blockIdx.x < n2){ d = d1; bid = blockIdx.x - n1; }
  else { d = d2; bid = blockIdx.x - n2; }

  const int tid = threadIdx.x, lane = tid & 63, w = tid >> 6;
  const int l15 = lane & 15, l4 = lane >> 4;
  const int l8 = lane >> 3, l7 = lane & 7;
  const int cbE = (l7 ^ l8) * 8;

  int bx, by;
  if (d.gx){
    const int xcd = bid & 7, slot = bid >> 3;
    const int rx = xcd / d.nCx, cx = xcd - rx * d.nCx;
    by = rx * d.rBlk + slot / d.cBlk;
    bx = cx * d.cBlk + slot % d.cBlk;
  } else {
    bx = bid % d.nbx; by = bid / d.nbx;
  }
  const int m0 = by * BM, n0 = bx * 128;
  const int wm = (w >> 1) * (BM / 2), wn = (w & 1) * 64;

  f32x4 acc[MW][4];
  #pragma unroll
  for (int i = 0; i < MW; ++i)
    #pragma unroll
    for (int j = 0; j < 4; ++j)
      acc[i][j] = (f32x4){0.f, 0.f, 0.f, 0.f};

  for (int k0 = 0; k0 < d.K; k0 += 64){
    #pragma unroll
    for (int c = 0; c < AI; ++c){
      const int a = w * AI + c;
      const int ar = min(m0 + a*8 + l8, d.M - 1);
      gload16(d.A + (size_t)ar * d.lda + k0 + cbE, &As[a * 512]);
    }
    #pragma unroll
    for (int c = 0; c < 4; ++c){
      const int b = w * 4 + c;
      const int br = min(n0 + b*8 + l8, d.N - 1);
      gload16(d.BT + (size_t)br * d.ldb + k0 + cbE, &Bs[b * 512]);
    }
    VMWAIT(0);
    __syncthreads();
    #pragma unroll
    for (int kk = 0; kk < 2; ++kk){
      const int sz = ((kk*4 + l4) ^ (l15 & 7)) * 8;
      bf16x8 a[MW], b[4];
      #pragma unroll
      for (int m = 0; m < MW; ++m)
        a[m] = *(const bf16x8*)(As + (wm + m*16 + l15) * 64 + sz);
      #pragma unroll
      for (int n = 0; n < 4; ++n)
        b[n] = *(const bf16x8*)(Bs + (wn + n*16 + l15) * 64 + sz);
      #pragma unroll
      for (int m = 0; m < MW; ++m)
        #pragma unroll
        for (int n = 0; n < 4; ++n)
          acc[m][n] = MFMA(a[m], b[n], acc[m][n]);
    }
    __syncthreads();
  }

  #pragma unroll
  for (int n = 0; n < 4; ++n){
    const int colg = n0 + wn + n*16 + l15;
    const int sel = colg / 1536;
    const int col = colg - sel * 1536;
    const float* bp = d.o.b[sel];
    const float bi = bp ? bp[col] : 0.f;
    #pragma unroll
    for (int m = 0; m < MW; ++m){
      const int row0 = m0 + wm + m*16 + l4*4;
      #pragma unroll
      for (int r = 0; r < 4; ++r){
        const int row = row0 + r;
        if (row < d.M){
          float val = acc[m][n][r] + bi;
          if (OUTF32) ((float*)d.o.C[sel])[(size_t)row * d.ldc + col] = val;
          else        ((u16*)d.o.C[sel])[(size_t)row * d.ldc + col] = f2bf(val);
        }
      }
    }
  }
}

// ---------------- cross attention: flash-style, rank-1 gate ----------------

__global__ __launch_bounds__(256, 4) void k_cross_attn(
  const u16* __restrict__ Q,
  const u16* __restrict__ Kp,    // [256][1536]
  const u16* __restrict__ VpP,   // [1536][256], cols pi-permuted per 32-block
  const float* __restrict__ clip,
  const float* __restrict__ Wsl, // [512]
  const float* __restrict__ bslp,
  const float* __restrict__ wvec,// [1536]
  float* __restrict__ multi)     // [2048][1536]
{
  const int h = blockIdx.y;
  const int tid = threadIdx.x, lane = tid & 63, w = tid >> 6;
  const int l15 = lane & 15, l4 = lane >> 4;
  const int l8 = lane >> 3, l7 = lane & 7;
  const int cbE = (l7 ^ l8) * 8;
  const int qrow = blockIdx.x * 64 + w * 16 + l15;

  __shared__ alignas(1024) u16 Ks[2][4096];
  __shared__ alignas(1024) u16 VTs[2][4096];
  __shared__ float clip_l[256];
  if (tid < 256) clip_l[tid] = clip[tid];

  float cd = 0.f;
  for (int p = lane; p < 256; p += 64) cd += clip[p] * Wsl[256 + p];
  cd = red64_sum(cd);
  const float gate_c = cd + bslp[0];

  bf16x8 qf[2];
  #pragma unroll
  for (int kk = 0; kk < 2; ++kk)
    qf[kk] = *(const bf16x8*)(Q + (size_t)qrow * 1536 + h*64 + kk*32 + l4*8);

  float gd = 0.f;
  #pragma unroll
  for (int kk = 0; kk < 2; ++kk){
    const float4 w0 = *(const float4*)(wvec + h*64 + kk*32 + l4*8);
    const float4 w1 = *(const float4*)(wvec + h*64 + kk*32 + l4*8 + 4);
    gd += w0.x * bf2f((u16)qf[kk][0]) + w0.y * bf2f((u16)qf[kk][1]);
    gd += w0.z * bf2f((u16)qf[kk][2]) + w0.w * bf2f((u16)qf[kk][3]);
    gd += w1.x * bf2f((u16)qf[kk][4]) + w1.y * bf2f((u16)qf[kk][5]);
    gd += w1.z * bf2f((u16)qf[kk][6]) + w1.w * bf2f((u16)qf[kk][7]);
  }
  const float gate = SCALE * redl4_sum(gd) + gate_c;

  f32x4 O[4];
  #pragma unroll
  for (int nb = 0; nb < 4; ++nb) O[nb] = (f32x4){0.f, 0.f, 0.f, 0.f};
  float m_ = -1e30f, l_ = 0.f;          // l_ lane-local; reduced once at end

  const u16* vpb = VpP + (size_t)(h*64) * 256;

  auto STAGE = [&](int buf, int kt0){
    #pragma unroll
    for (int c = 0; c < 2; ++c){
      const int a = w*2 + c;
      const int row = a*8 + l8;
      gload16(Kp + (size_t)(kt0 + row) * 1536 + h*64 + cbE, &Ks[buf][a * 512]);
      gload16(vpb + (size_t)row * 256 + kt0 + cbE, &VTs[buf][a * 512]);
    }
  };

  STAGE(0, 0);
  __syncthreads();

  int buf = 0;
  for (int nt = 0; nt < 4; ++nt){
    if (nt + 1 < 4){
      STAGE(buf ^ 1, (nt + 1) * 64);
      VMWAIT(4);
    } else {
      VMWAIT(0);
    }
    SCHED0();
    SBAR();
    SCHED0();
    const int kt0 = nt * 64;

    f32x4 s[4];
    __builtin_amdgcn_s_setprio(1);
    #pragma unroll
    for (int n4 = 0; n4 < 4; ++n4){
      f32x4 t = {0.f, 0.f, 0.f, 0.f};
      #pragma unroll
      for (int kk = 0; kk < 2; ++kk){
        const int sz = ((kk*4 + l4) ^ (l15 & 7)) * 8;
        bf16x8 kf = *(const bf16x8*)(&Ks[buf][(n4*16 + l15) * 64 + sz]);
        t = MFMA(kf, qf[kk], t);
      }
      s[n4] = t;
    }
    __builtin_amdgcn_s_setprio(0);

    #pragma unroll
    for (int n4 = 0; n4 < 4; ++n4){
      const float4 cv = *(const float4*)&clip_l[kt0 + n4*16 + l4*4];
      s[n4][0] = fmaf(s[n4][0], SCALE, gate * cv.x);
      s[n4][1] = fmaf(s[n4][1], SCALE, gate * cv.y);
      s[n4][2] = fmaf(s[n4][2], SCALE, gate * cv.z);
      s[n4][3] = fmaf(s[n4][3], SCALE, gate * cv.w);
    }

    float mt = -1e30f;
    #pragma unroll
    for (int n4 = 0; n4 < 4; ++n4)
      mt = fmaxf(mt, fmaxf(fmaxf(s[n4][0], s[n4][1]), fmaxf(s[n4][2], s[n4][3])));
    mt = redl4_max(mt);

    const float mn = fmaxf(m_, mt);
    const float al = fexp2((m_ - mn) * L2E);
    m_ = mn;
    l_ *= al;
    float alo[4];
    #pragma unroll
    for (int r = 0; r < 4; ++r) alo[r] = __shfl(al, l4*4 + r, 16);
    #pragma unroll
    for (int nb = 0; nb < 4; ++nb)
      #pragma unroll
      for (int r = 0; r < 4; ++r) O[nb][r] *= alo[r];

    const float m2 = m_ * L2E;
    #pragma unroll
    for (int n4 = 0; n4 < 4; ++n4)
      #pragma unroll
      for (int r = 0; r < 4; ++r){
        float pv = fexp2(fmaf(s[n4][r], L2E, -m2));
        l_ += pv;
        s[n4][r] = pv;
      }

    __builtin_amdgcn_s_setprio(1);
    #pragma unroll
    for (int kk = 0; kk < 2; ++kk){
      const int sz = ((kk*4 + l4) ^ (l15 & 7)) * 8;
      union { u32 w4[4]; bf16x8 v; } U;
      U.w4[0] = cvtpk(s[2*kk][0],   s[2*kk][1]);
      U.w4[1] = cvtpk(s[2*kk][2],   s[2*kk][3]);
      U.w4[2] = cvtpk(s[2*kk+1][0], s[2*kk+1][1]);
      U.w4[3] = cvtpk(s[2*kk+1][2], s[2*kk+1][3]);
      #pragma unroll
      for (int nb = 0; nb < 4; ++nb){
        bf16x8 vt = *(const bf16x8*)(&VTs[buf][(nb*16 + l15) * 64 + sz]);
        O[nb] = MFMA(U.v, vt, O[nb]);
      }
    }
    __builtin_amdgcn_s_setprio(0);

    SCHED0();
    SBAR();
    buf ^= 1;
  }

  const float inv = 1.f / redl4_sum(l_);
  float li[4];
  #pragma unroll
  for (int r = 0; r < 4; ++r) li[r] = __shfl(inv, l4*4 + r, 16);
  #pragma unroll
  for (int r = 0; r < 4; ++r){
    const int row = blockIdx.x * 64 + w * 16 + l4*4 + r;
    #pragma unroll
    for (int nb = 0; nb < 4; ++nb)
      multi[(size_t)row * 1536 + h*64 + nb*16 + l15] = O[nb][r] * li[r];
  }
}

// ---------------- self attention: flash split-K (2 halves), partials merged later ----------------

__global__ __launch_bounds__(256, 4) void k_self_attn_split(
  const u16* __restrict__ q2,   // [2304][1536]
  const u16* __restrict__ k2,   // [2304][1536]
  const u16* __restrict__ v2P,  // [1536][2304], cols pi-permuted per 32-block
  float* __restrict__ Opart,    // [2][2240][1536] unnormalized
  float2* __restrict__ ml)      // [2][24][2240] (m, l)
{
  const int p = blockIdx.x;
  const int slot = p >> 3;
  const int h   = (p & 7) * 3 + slot / 70;
  const int rem = slot % 70;
  const int qb = rem >> 1, half = rem & 1;
  const int nt0 = half * 18, ntE = half ? 35 : 18;
  const int tid = threadIdx.x, lane = tid & 63, w = tid >> 6;
  const int l15 = lane & 15, l4 = lane >> 4;
  const int l8 = lane >> 3, l7 = lane & 7;
  const int cbE = (l7 ^ l8) * 8;
  const int qrow = qb * 64 + w * 16 + l15;

  __shared__ alignas(1024) u16 Ks[2][4096];
  __shared__ alignas(1024) u16 VTs[2][4096];

  bf16x8 qf[2];
  #pragma unroll
  for (int kk = 0; kk < 2; ++kk)
    qf[kk] = *(const bf16x8*)(q2 + (size_t)qrow * 1536 + h*64 + kk*32 + l4*8);

  f32x4 O[4];
  #pragma unroll
  for (int nb = 0; nb < 4; ++nb) O[nb] = (f32x4){0.f, 0.f, 0.f, 0.f};
  float m_ = -1e30f, l_ = 0.f;          // lane-local l; reduced at end
  const float C2 = SCALE * L2E;
  const float THR = 44.36f;             // 8 / C2

  const u16* kp  = k2 + h*64;
  const u16* vp0 = v2P + (size_t)(h*64) * NPAD;

  auto STAGE = [&](int buf, int kt0){
    #pragma unroll
    for (int c = 0; c < 2; ++c){
      const int a = w*2 + c;
      const int row = a*8 + l8;
      gload16(kp + (size_t)(kt0 + row) * 1536 + cbE, &Ks[buf][a * 512]);
      gload16(vp0 + (size_t)row * NPAD + kt0 + cbE, &VTs[buf][a * 512]);
    }
  };

  STAGE(0, nt0 * 64);
  __syncthreads();

  int buf = 0;
  for (int nt = nt0; nt < ntE; ++nt){
    if (nt + 1 < ntE){
      STAGE(buf ^ 1, (nt + 1) * 64);
      VMWAIT(4);
    } else {
      VMWAIT(0);
    }
    SCHED0();
    SBAR();
    SCHED0();
    const int kt0 = nt * 64;

    f32x4 s[4];
    __builtin_amdgcn_s_setprio(1);
    #pragma unroll
    for (int n4 = 0; n4 < 4; ++n4){
      f32x4 t = {0.f, 0.f, 0.f, 0.f};
      #pragma unroll
      for (int kk = 0; kk < 2; ++kk){
        const int sz = ((kk*4 + l4) ^ (l15 & 7)) * 8;
        bf16x8 kf = *(const bf16x8*)(&Ks[buf][(n4*16 + l15) * 64 + sz]);
        t = MFMA(kf, qf[kk], t);
      }
      s[n4] = t;
    }
    __builtin_amdgcn_s_setprio(0);

    if (kt0 + 64 > NTOT){                       // only the global last tile
      #pragma unroll
      for (int n4 = 0; n4 < 4; ++n4){
        const int keyb = kt0 + n4*16 + l4*4;
        #pragma unroll
        for (int r = 0; r < 4; ++r)
          if (keyb + r >= NTOT) s[n4][r] = -1e30f;
      }
    }

    float mt = -1e30f;
    #pragma unroll
    for (int n4 = 0; n4 < 4; ++n4)
      mt = fmaxf(mt, fmaxf(fmaxf(s[n4][0], s[n4][1]), fmaxf(s[n4][2], s[n4][3])));
    mt = redl4_max(mt);

    if (__any(mt > m_ + THR)){                  // T13 defer-max
      const float mn = fmaxf(m_, mt);
      const float al = fexp2((m_ - mn) * C2);
      m_ = mn;
      l_ *= al;                                 // al uniform across l4-group
      float alo[4];
      #pragma unroll
      for (int r = 0; r < 4; ++r) alo[r] = __shfl(al, l4*4 + r, 16);
      #pragma unroll
      for (int nb = 0; nb < 4; ++nb)
        #pragma unroll
        for (int r = 0; r < 4; ++r) O[nb][r] *= alo[r];
    }
    const float m2 = m_ * C2;

    #pragma unroll
    for (int n4 = 0; n4 < 4; ++n4)
      #pragma unroll
      for (int r = 0; r < 4; ++r){
        float pv = fexp2(fmaf(s[n4][r], C2, -m2));
        l_ += pv;
        s[n4][r] = pv;
      }

    __builtin_amdgcn_s_setprio(1);
    #pragma unroll
    for (int kk = 0; kk < 2; ++kk){
      const int sz = ((kk*4 + l4) ^ (l15 & 7)) * 8;
      union { u32 w4[4]; bf16x8 v; } U;
      U.w4[0] = cvtpk(s[2*kk][0],   s[2*kk][1]);
      U.w4[1] = cvtpk(s[2*kk][2],   s[2*kk][3]);
      U.w4[2] = cvtpk(s[2*kk+1][0], s[2*kk+1][1]);
      U.w4[3] = cvtpk(s[2*kk+1][2], s[2*kk+1][3]);
      #pragma unroll
      for (int nb = 0; nb < 4; ++nb){
        bf16x8 vt = *(const bf16x8*)(&VTs[buf][(nb*16 + l15) * 64 + sz]);
        O[nb] = MFMA(U.v, vt, O[nb]);
      }
    }
    __builtin_amdgcn_s_setprio(0);

    SCHED0();
    SBAR();
    buf ^= 1;
  }

  const float lsum = redl4_sum(l_);
  float* Oh = Opart + (size_t)half * 2240 * 1536;
  #pragma unroll
  for (int r = 0; r < 4; ++r){
    const int row = qb*64 + w*16 + l4*4 + r;
    #pragma unroll
    for (int nb = 0; nb < 4; ++nb)
      Oh[(size_t)row * 1536 + h*64 + nb*16 + l15] = O[nb][r];
  }
  if (l4 == 0)
    ml[(size_t)half*24*2240 + h*2240 + qrow] = make_float2(m_, lsum);
}

// fused: split-K merge + adaptive gate/blend (img rows) or bf16 cast (txt rows)
__global__ __launch_bounds__(256) void k_merge_blend(
  const float* __restrict__ Op,     // [2][2240][1536]
  const float2* __restrict__ ml,    // [2][24][2240]
  const float* __restrict__ multi,  // [2048][1536]
  const float* __restrict__ Wad,    // [3072]
  const float* __restrict__ badp,
  u16* __restrict__ blended,        // [2048][1536] bf16
  u16* __restrict__ hstxt)          // [154][1536] bf16
{
  const int row = blockIdx.x;       // 0..2201
  const int t = threadIdx.x;
  const int lane = t & 63, wid = t >> 6;
  __shared__ float e0s[24], e1s[24], invs[24];
  __shared__ float redbuf[4];
  if (t < 24){
    const float2 a = ml[t*2240 + row];
    const float2 b = ml[24*2240 + t*2240 + row];
    const float M = fmaxf(a.x, b.x);
    const float C2 = SCALE * L2E;
    const float e0 = fexp2((a.x - M) * C2);
    const float e1 = fexp2((b.x - M) * C2);
    e0s[t] = e0; e1s[t] = e1;
    invs[t] = 1.f / (e0*a.y + e1*b.y);
  }
  __syncthreads();
  const float* O0 = Op + (size_t)row * 1536;
  const float* O1 = Op + (size_t)2240*1536 + (size_t)row * 1536;
  float mg[6];
  #pragma unroll
  for (int i = 0; i < 6; ++i){
    const int col = t + i*256;
    const int h = col >> 6;
    mg[i] = (e0s[h]*O0[col] + e1s[h]*O1[col]) * invs[h];
  }
  if (row < 2048){
    const float* mrow = multi + (size_t)row * 1536;
    float dot = 0.f;
    #pragma unroll
    for (int i = 0; i < 6; ++i){
      const int col = t + i*256;
      dot += mrow[col] * Wad[col] + mg[i] * Wad[1536 + col];
    }
    dot = red64_sum(dot);
    if (lane == 0) redbuf[wid] = dot;
    __syncthreads();
    const float tot = redbuf[0] + redbuf[1] + redbuf[2] + redbuf[3] + badp[0];
    const float f = BLENDF / (1.f + __expf(-tot));
    u16* brow = blended + (size_t)row * 1536;
    #pragma unroll
    for (int i = 0; i < 6; ++i){
      const int col = t + i*256;
      brow[col] = f2bf(fmaf(f, mrow[col], mg[i]));
    }
  } else {
    u16* orow = hstxt + (size_t)(row - 2048) * 1536;
    #pragma unroll
    for (int i = 0; i < 6; ++i)
      orow[t + i*256] = f2bf(mg[i]);
  }
}

// ---------------- launch ----------------

extern "C" void kernel_launch(void* const* d_in, const int* in_sizes, int n_in,
                              void* d_out, int out_size, void* d_ws, size_t ws_size,
                              hipStream_t stream)
{
  (void)in_sizes; (void)n_in; (void)out_size; (void)ws_size;
  const float* hs   = (const float*)d_in[0];
  const float* enc  = (const float*)d_in[1];
  const float* pics = (const float*)d_in[2];
  const float* clip = (const float*)d_in[3];
  const float* Wq   = (const float*)d_in[4];  const float* bq   = (const float*)d_in[5];
  const float* Wk   = (const float*)d_in[6];  const float* bk   = (const float*)d_in[7];
  const float* Wv   = (const float*)d_in[8];  const float* bv   = (const float*)d_in[9];
  const float* Waq  = (const float*)d_in[10]; const float* baq  = (const float*)d_in[11];
  const float* Wak  = (const float*)d_in[12]; const float* bak  = (const float*)d_in[13];
  const float* Wav  = (const float*)d_in[14]; const float* bav  = (const float*)d_in[15];
  const float* Wkl  = (const float*)d_in[16]; const float* Wvl  = (const float*)d_in[17];
  const float* Wsl  = (const float*)d_in[18]; const float* bsl  = (const float*)d_in[19];
  const float* Wad  = (const float*)d_in[20]; const float* bad  = (const float*)d_in[21];
  const float* Wout = (const float*)d_in[22]; const float* bout = (const float*)d_in[23];
  const float* Wadd = (const float*)d_in[24]; const float* badd = (const float*)d_in[25];

  char* ws = (char*)d_ws;
  size_t off = 0;
  auto alloc = [&](size_t b){ void* p = ws + off; off += (b + 255) & ~(size_t)255; return p; };

  u16* hs_bf  = (u16*)alloc((size_t)2048*1536*2);
  u16* enc_bf = (u16*)alloc((size_t)154*1536*2);
  u16* pics_bf= (u16*)alloc((size_t)256*1024*2);
  // WqT..WavT (6 x 4.7MB, contiguous) are DEAD after the input GEMMs;
  // reused as the split-attn partial-O buffer (27.5MB <= 28.3MB).
  u16* WqT  = (u16*)alloc((size_t)1536*1536*2);
  u16* WkT  = (u16*)alloc((size_t)1536*1536*2);
  u16* WvT  = (u16*)alloc((size_t)1536*1536*2);
  u16* WaqT = (u16*)alloc((size_t)1536*1536*2);
  u16* WakT = (u16*)alloc((size_t)1536*1536*2);
  u16* WavT = (u16*)alloc((size_t)1536*1536*2);
  u16* WoutT= (u16*)alloc((size_t)1536*1536*2);
  u16* WaddT= (u16*)alloc((size_t)1536*1536*2);
  u16* WklT = (u16*)alloc((size_t)1536*1024*2);
  u16* WvlT = (u16*)alloc((size_t)1536*1024*2);
  u16* q2   = (u16*)alloc((size_t)NPAD*1536*2);
  u16* k2   = (u16*)alloc((size_t)NPAD*1536*2);
  u16* v2   = (u16*)alloc((size_t)NPAD*1536*2);
  u16* v2P  = (u16*)alloc((size_t)1536*NPAD*2);
  u16* Kp   = (u16*)alloc((size_t)256*1536*2);
  u16* Vp   = (u16*)alloc((size_t)256*1536*2);
  u16* VpP  = (u16*)alloc((size_t)1536*256*2);
  float* wvec   = (float*)alloc((size_t)1536*4);
  float* multi  = (float*)alloc((size_t)2048*1536*4);
  u16* blended  = (u16*)alloc((size_t)2048*1536*2);
  u16* hstxt    = (u16*)alloc((size_t)154*1536*2);
  float2* mlbuf = (float2*)alloc((size_t)2*24*2240*8);
  float* Opart  = (float*)WqT;   // alias: dead after input GEMMs

  // fused prep: 3 casts + zero-pad of q2/k2/v2 tail rows (1 launch)
  k_prep<<<dim3(2009), 256, 0, stream>>>(hs, enc, pics, hs_bf, enc_bf, pics_bf,
                                         q2 + (size_t)NTOT*1536,
                                         k2 + (size_t)NTOT*1536,
                                         v2 + (size_t)NTOT*1536);

  WT10 wts;
  wts.w[0] = {Wq,   WqT,   1536};
  wts.w[1] = {Wk,   WkT,   1536};
  wts.w[2] = {Wv,   WvT,   1536};
  wts.w[3] = {Waq,  WaqT,  1536};
  wts.w[4] = {Wak,  WakT,  1536};
  wts.w[5] = {Wav,  WavT,  1536};
  wts.w[6] = {Wout, WoutT, 1536};
  wts.w[7] = {Wadd, WaddT, 1536};
  wts.w[8] = {Wkl,  WklT,  1024};
  wts.w[9] = {Wvl,  WvlT,  1024};
  k_transpose_w<<<dim3(24, 24, 10), 256, 0, stream>>>(wts);

  // fused input GEMMs: QKV (1152, XCD-region) + enc (108) + pics (96) in one dispatch
  GDesc dq, de, dp;
  dq.A = hs_bf; dq.BT = WqT; dq.lda = 1536; dq.ldb = 1536; dq.ldc = 1536;
  dq.M = 2048; dq.N = 4608; dq.K = 1536; dq.gx = 1; dq.nCx = 4; dq.rBlk = 16; dq.cBlk = 9; dq.nbx = 0;
  dq.o.C[0] = q2; dq.o.C[1] = k2; dq.o.C[2] = v2;
  dq.o.b[0] = bq; dq.o.b[1] = bk; dq.o.b[2] = bv;
  de.A = enc_bf; de.BT = WaqT; de.lda = 1536; de.ldb = 1536; de.ldc = 1536;
  de.M = 154; de.N = 4608; de.K = 1536; de.gx = 0; de.nbx = 36; de.nCx = de.rBlk = de.cBlk = 0;
  de.o.C[0] = q2 + (size_t)2048*1536; de.o.C[1] = k2 + (size_t)2048*1536; de.o.C[2] = v2 + (size_t)2048*1536;
  de.o.b[0] = baq; de.o.b[1] = bak; de.o.b[2] = bav;
  dp.A = pics_bf; dp.BT = WklT; dp.lda = 1024; dp.ldb = 1024; dp.ldc = 1536;
  dp.M = 256; dp.N = 3072; dp.K = 1024; dp.gx = 0; dp.nbx = 24; dp.nCx = dp.rBlk = dp.cBlk = 0;
  dp.o.C[0] = Kp; dp.o.C[1] = Vp; dp.o.C[2] = nullptr;
  dp.o.b[0] = nullptr; dp.o.b[1] = nullptr; dp.o.b[2] = nullptr;
  k_gemm_multi<0><<<dim3(1356), 256, 0, stream>>>(dq, de, dp, 1152, 1260);

  k_wvec<<<dim3(6), 256, 0, stream>>>(Kp, Wsl, wvec);

  k_transpose_vp<<<dim3(48, NPAD/32), dim3(32, 8), 0, stream>>>(v2, v2P, NPAD, 1536);
  k_transpose_vp<<<dim3(48, 8),       dim3(32, 8), 0, stream>>>(Vp, VpP, 256, 1536);

  k_cross_attn<<<dim3(32, 24), 256, 0, stream>>>(q2, Kp, VpP, clip, Wsl, bsl, wvec, multi);
  // split-K self-attn: 1680 blocks (2 halves per (head,qb)), then fused merge+blend
  k_self_attn_split<<<dim3(1680), 256, 0, stream>>>(q2, k2, v2P, Opart, mlbuf);
  k_merge_blend<<<dim3(NTOT), 256, 0, stream>>>(Opart, mlbuf, multi, Wad, bad, blended, hstxt);

  // fused output GEMMs: Wout (384, XCD-region) + Wadd (36) in one dispatch
  GDesc dw, da;
  dw.A = blended; dw.BT = WoutT; dw.lda = 1536; dw.ldb = 1536; dw.ldc = 1536;
  dw.M = 2048; dw.N = 1536; dw.K = 1536; dw.gx = 1; dw.nCx = 2; dw.rBlk = 8; dw.cBlk = 6; dw.nbx = 0;
  dw.o.C[0] = d_out; dw.o.C[1] = nullptr; dw.o.C[2] = nullptr;
  dw.o.b[0] = bout; dw.o.b[1] = nullptr; dw.o.b[2] = nullptr;
  da.A = hstxt; da.BT = WaddT; da.lda = 1536; da.ldb = 1536; da.ldc = 1536;
  da.M = 154; da.N = 1536; da.K = 1536; da.gx = 0; da.nbx = 12; da.nCx = da.rBlk = da.cBlk = 0;
  da.o.C[0] = (float*)d_out + (size_t)2048*1536; da.o.C[1] = nullptr; da.o.C[2] = nullptr;
  da.o.b[0] = badd; da.o.b[1] = nullptr; da.o.b[2] = nullptr;
  k_gemm_multi<1><<<dim3(420), 256, 0, stream>>>(dw, da, da, 384, 420);
}

// Round 16
// 208.185 us; speedup vs baseline: 2.1762x; 1.2974x over previous
//
#include <hip/hip_runtime.h>

typedef unsigned short u16;
typedef unsigned int u32;
typedef __attribute__((ext_vector_type(4))) short bf16x4;
typedef __attribute__((ext_vector_type(8))) short bf16x8;
typedef __attribute__((ext_vector_type(4))) float f32x4;

#define SCALE 0.125f
#define BLENDF 0.4875f
#define NTOT 2202
#define NPAD 2304
#define L2E 1.44269504f

#define SBAR()  __builtin_amdgcn_s_barrier()
#define SCHED0() __builtin_amdgcn_sched_barrier(0)
#define VMWAIT(n) asm volatile("s_waitcnt vmcnt(" #n ")" ::: "memory")

__device__ __forceinline__ u16 f2bf(float x){
  union { float f; unsigned u; } v; v.f = x;
  unsigned r = v.u + 0x7fffu + ((v.u >> 16) & 1u);
  return (u16)(r >> 16);
}
__device__ __forceinline__ float bf2f(u16 b){
  union { unsigned u; float f; } v; v.u = (u32)b << 16; return v.f;
}
// hw packer: 2 f32 -> 2 bf16 (RNE), src0 in low half
__device__ __forceinline__ u32 cvtpk(float a, float b){
  u32 r;
  asm("v_cvt_pk_bf16_f32 %0, %1, %2" : "=v"(r) : "v"(a), "v"(b));
  return r;
}

__device__ __forceinline__ float fexp2(float x){
#if __has_builtin(__builtin_amdgcn_exp2f)
  return __builtin_amdgcn_exp2f(x);
#else
  return __expf(x * 0.6931472f);
#endif
}

__device__ __forceinline__ f32x4 MFMA(bf16x8 a, bf16x8 b, f32x4 c){
  return __builtin_amdgcn_mfma_f32_16x16x32_bf16(a, b, c, 0, 0, 0);
}

// async global->LDS, 16B per lane; LDS dest is wave-uniform base (+lane*16 implicit)
__device__ __forceinline__ void gload16(const u16* g, u16* l){
  __builtin_amdgcn_global_load_lds(
    (const __attribute__((address_space(1))) u32*)g,
    (__attribute__((address_space(3))) u32*)l, 16, 0, 0);
}

__device__ __forceinline__ float red64_sum(float x){
  x += __shfl_xor(x, 1, 64);
  x += __shfl_xor(x, 2, 64);
  x += __shfl_xor(x, 4, 64);
  x += __shfl_xor(x, 8, 64);
  x += __shfl_xor(x, 16, 64);
  x += __shfl_xor(x, 32, 64);
  return x;
}
// reduce over the l4 axis (lanes sharing the same lane&15)
__device__ __forceinline__ float redl4_sum(float x){
  x += __shfl_xor(x, 16, 64);
  x += __shfl_xor(x, 32, 64);
  return x;
}
__device__ __forceinline__ float redl4_max(float x){
  x = fmaxf(x, __shfl_xor(x, 16, 64));
  x = fmaxf(x, __shfl_xor(x, 32, 64));
  return x;
}

// ---------------- fused input prep: casts + zero-pad (1 launch) ----------------

__device__ __forceinline__ void cast8(const float* in, u16* out){
  float4 a = *(const float4*)(in);
  float4 b = *(const float4*)(in + 4);
  bf16x8 v = { (short)f2bf(a.x), (short)f2bf(a.y), (short)f2bf(a.z), (short)f2bf(a.w),
               (short)f2bf(b.x), (short)f2bf(b.y), (short)f2bf(b.z), (short)f2bf(b.w) };
  *(bf16x8*)(out) = v;
}

__global__ __launch_bounds__(256) void k_prep(
  const float* __restrict__ hs, const float* __restrict__ enc, const float* __restrict__ pics,
  u16* __restrict__ hs_bf, u16* __restrict__ enc_bf, u16* __restrict__ pics_bf,
  u16* __restrict__ q2p, u16* __restrict__ k2p, u16* __restrict__ v2p)
{
  long i = (long)blockIdx.x * 256 + threadIdx.x;      // unit = 8 elements
  const long nh = (long)2048*1536/8, ne = (long)154*1536/8;
  const long np = (long)256*1024/8,  nz = (long)(NPAD-NTOT)*1536/8;
  if (i < nh){ cast8(hs + i*8, hs_bf + i*8); return; }
  i -= nh;
  if (i < ne){ cast8(enc + i*8, enc_bf + i*8); return; }
  i -= ne;
  if (i < np){ cast8(pics + i*8, pics_bf + i*8); return; }
  i -= np;
  if (i < 3*nz){
    const int which = (int)(i / nz);
    const long j = (i - (long)which*nz) * 8;
    u16* d = which == 0 ? q2p : which == 1 ? k2p : v2p;
    const bf16x8 z = {0,0,0,0,0,0,0,0};
    *(bf16x8*)(d + j) = z;
  }
}

// w_vec[d] = sum_k Wsl[k] * Kp[k][d]  (rank-1 gate precompute)
__global__ __launch_bounds__(256) void k_wvec(const u16* __restrict__ Kp,
                                              const float* __restrict__ Wsl,
                                              float* __restrict__ wvec){
  const int d = blockIdx.x * 256 + threadIdx.x;
  float acc = 0.f;
  for (int k = 0; k < 256; ++k)
    acc += Wsl[k] * bf2f(Kp[(size_t)k * 1536 + d]);
  wvec[d] = acc;
}

struct WT { const float* s; u16* d; int K; };
struct WT10 { WT w[10]; };

// in: [K][1536] fp32 -> out: [1536][K] bf16. 64x64 tiles, fully coalesced both sides.
__global__ __launch_bounds__(256) void k_transpose_w(WT10 ws){
  const WT t = ws.w[blockIdx.z];
  const int r0 = blockIdx.y * 64;
  if (r0 >= t.K) return;
  const int c0 = blockIdx.x * 64;
  __shared__ float tile[64][65];
  const int x = threadIdx.x & 63, y = threadIdx.x >> 6;
  #pragma unroll
  for (int k = 0; k < 16; ++k)
    tile[y + 4*k][x] = t.s[(size_t)(r0 + y + 4*k) * 1536 + c0 + x];
  __syncthreads();
  #pragma unroll
  for (int k = 0; k < 16; ++k)
    t.d[(size_t)(c0 + y + 4*k) * t.K + r0 + x] = f2bf(tile[x][y + 4*k]);
}

// in: [R][C] bf16 -> out[C][R] bf16 with columns PERMUTED within each 32-block:
// out[d][32b + p] = in[32b + k(p)][d], k(p) = ((p>>2)&1)*16 + (p>>3)*4 + (p&3)
// == PV A-fragment k-slot map, so a contiguous read is the B-fragment.
__global__ __launch_bounds__(256) void k_transpose_vp(const u16* __restrict__ in,
                                                      u16* __restrict__ out, int R, int C){
  const int r0 = blockIdx.y * 32, c0 = blockIdx.x * 32;
  __shared__ u16 tile[32][34];
  const int x = threadIdx.x, y = threadIdx.y;
  #pragma unroll
  for (int k = 0; k < 4; ++k)
    tile[y + 8*k][x] = in[(size_t)(r0 + y + 8*k) * C + c0 + x];
  __syncthreads();
  const int kx = (((x >> 2) & 1) << 4) + ((x >> 3) << 2) + (x & 3);
  #pragma unroll
  for (int k = 0; k < 4; ++k)
    out[(size_t)(c0 + y + 8*k) * R + r0 + x] = tile[kx][y + 8*k];
}

// ---------------- multi-GEMM: up to 3 segment-fused GEMMs in ONE dispatch ----------------
// Fields selected per-block via SCALAR ternaries (aggregate copy of GDesc went to
// scratch in r15: 70MB WRITE_SIZE, MfmaUtil 12.5% -- rule #20).

struct GOuts { void* C[3]; const float* b[3]; };
struct GDesc {
  const u16* A; const u16* BT;
  GOuts o;
  int lda, ldb, ldc, M, N, K;
  int gx, nCx, rBlk, cBlk, nbx;
};

template<int OUTF32>
__global__ __launch_bounds__(256, 4) void k_gemm_multi(GDesc d0, GDesc d1, GDesc d2,
                                                       int n1, int n2)
{
  constexpr int BM = 64, MW = 2, AI = 2;
  __shared__ alignas(1024) u16 As[BM * 64];
  __shared__ alignas(1024) u16 Bs[128 * 64];

  const int which = ((int)blockIdx.x < n1) ? 0 : (((int)blockIdx.x < n2) ? 1 : 2);
  const int bid = (int)blockIdx.x - (which == 0 ? 0 : (which == 1 ? n1 : n2));
#define PICK(f) (which == 0 ? d0.f : (which == 1 ? d1.f : d2.f))
  const u16* A   = PICK(A);
  const u16* BT  = PICK(BT);
  const int lda  = PICK(lda), ldb = PICK(ldb), ldc = PICK(ldc);
  const int M    = PICK(M),   N   = PICK(N),   K   = PICK(K);
  const int gx   = PICK(gx),  nCx = PICK(nCx);
  const int rBlk = PICK(rBlk), cBlk = PICK(cBlk), nbx = PICK(nbx);
  void* C0 = PICK(o.C[0]); void* C1 = PICK(o.C[1]); void* C2v = PICK(o.C[2]);
  const float* b0 = PICK(o.b[0]); const float* b1 = PICK(o.b[1]); const float* b2 = PICK(o.b[2]);
#undef PICK

  const int tid = threadIdx.x, lane = tid & 63, w = tid >> 6;
  const int l15 = lane & 15, l4 = lane >> 4;
  const int l8 = lane >> 3, l7 = lane & 7;
  const int cbE = (l7 ^ l8) * 8;

  int bx, by;
  if (gx){
    const int xcd = bid & 7, slot = bid >> 3;
    const int rx = xcd / nCx, cx = xcd - rx * nCx;
    by = rx * rBlk + slot / cBlk;
    bx = cx * cBlk + slot % cBlk;
  } else {
    bx = bid % nbx; by = bid / nbx;
  }
  const int m0 = by * BM, n0 = bx * 128;
  const int wm = (w >> 1) * (BM / 2), wn = (w & 1) * 64;

  f32x4 acc[MW][4];
  #pragma unroll
  for (int i = 0; i < MW; ++i)
    #pragma unroll
    for (int j = 0; j < 4; ++j)
      acc[i][j] = (f32x4){0.f, 0.f, 0.f, 0.f};

  for (int k0 = 0; k0 < K; k0 += 64){
    #pragma unroll
    for (int c = 0; c < AI; ++c){
      const int a = w * AI + c;
      const int ar = min(m0 + a*8 + l8, M - 1);
      gload16(A + (size_t)ar * lda + k0 + cbE, &As[a * 512]);
    }
    #pragma unroll
    for (int c = 0; c < 4; ++c){
      const int b = w * 4 + c;
      const int br = min(n0 + b*8 + l8, N - 1);
      gload16(BT + (size_t)br * ldb + k0 + cbE, &Bs[b * 512]);
    }
    VMWAIT(0);
    __syncthreads();
    #pragma unroll
    for (int kk = 0; kk < 2; ++kk){
      const int sz = ((kk*4 + l4) ^ (l15 & 7)) * 8;
      bf16x8 a[MW], b[4];
      #pragma unroll
      for (int m = 0; m < MW; ++m)
        a[m] = *(const bf16x8*)(As + (wm + m*16 + l15) * 64 + sz);
      #pragma unroll
      for (int n = 0; n < 4; ++n)
        b[n] = *(const bf16x8*)(Bs + (wn + n*16 + l15) * 64 + sz);
      #pragma unroll
      for (int m = 0; m < MW; ++m)
        #pragma unroll
        for (int n = 0; n < 4; ++n)
          acc[m][n] = MFMA(a[m], b[n], acc[m][n]);
    }
    __syncthreads();
  }

  #pragma unroll
  for (int n = 0; n < 4; ++n){
    const int colg = n0 + wn + n*16 + l15;
    const int sel = colg / 1536;
    const int col = colg - sel * 1536;
    const float* bp = sel == 0 ? b0 : (sel == 1 ? b1 : b2);
    void* Cs = sel == 0 ? C0 : (sel == 1 ? C1 : C2v);
    const float bi = bp ? bp[col] : 0.f;
    #pragma unroll
    for (int m = 0; m < MW; ++m){
      const int row0 = m0 + wm + m*16 + l4*4;
      #pragma unroll
      for (int r = 0; r < 4; ++r){
        const int row = row0 + r;
        if (row < M){
          float val = acc[m][n][r] + bi;
          if (OUTF32) ((float*)Cs)[(size_t)row * ldc + col] = val;
          else        ((u16*)Cs)[(size_t)row * ldc + col] = f2bf(val);
        }
      }
    }
  }
}

// ---------------- cross attention: flash-style, rank-1 gate ----------------

__global__ __launch_bounds__(256, 4) void k_cross_attn(
  const u16* __restrict__ Q,
  const u16* __restrict__ Kp,    // [256][1536]
  const u16* __restrict__ VpP,   // [1536][256], cols pi-permuted per 32-block
  const float* __restrict__ clip,
  const float* __restrict__ Wsl, // [512]
  const float* __restrict__ bslp,
  const float* __restrict__ wvec,// [1536]
  float* __restrict__ multi)     // [2048][1536]
{
  const int h = blockIdx.y;
  const int tid = threadIdx.x, lane = tid & 63, w = tid >> 6;
  const int l15 = lane & 15, l4 = lane >> 4;
  const int l8 = lane >> 3, l7 = lane & 7;
  const int cbE = (l7 ^ l8) * 8;
  const int qrow = blockIdx.x * 64 + w * 16 + l15;

  __shared__ alignas(1024) u16 Ks[2][4096];
  __shared__ alignas(1024) u16 VTs[2][4096];
  __shared__ float clip_l[256];
  if (tid < 256) clip_l[tid] = clip[tid];

  float cd = 0.f;
  for (int p = lane; p < 256; p += 64) cd += clip[p] * Wsl[256 + p];
  cd = red64_sum(cd);
  const float gate_c = cd + bslp[0];

  bf16x8 qf[2];
  #pragma unroll
  for (int kk = 0; kk < 2; ++kk)
    qf[kk] = *(const bf16x8*)(Q + (size_t)qrow * 1536 + h*64 + kk*32 + l4*8);

  float gd = 0.f;
  #pragma unroll
  for (int kk = 0; kk < 2; ++kk){
    const float4 w0 = *(const float4*)(wvec + h*64 + kk*32 + l4*8);
    const float4 w1 = *(const float4*)(wvec + h*64 + kk*32 + l4*8 + 4);
    gd += w0.x * bf2f((u16)qf[kk][0]) + w0.y * bf2f((u16)qf[kk][1]);
    gd += w0.z * bf2f((u16)qf[kk][2]) + w0.w * bf2f((u16)qf[kk][3]);
    gd += w1.x * bf2f((u16)qf[kk][4]) + w1.y * bf2f((u16)qf[kk][5]);
    gd += w1.z * bf2f((u16)qf[kk][6]) + w1.w * bf2f((u16)qf[kk][7]);
  }
  const float gate = SCALE * redl4_sum(gd) + gate_c;

  f32x4 O[4];
  #pragma unroll
  for (int nb = 0; nb < 4; ++nb) O[nb] = (f32x4){0.f, 0.f, 0.f, 0.f};
  float m_ = -1e30f, l_ = 0.f;          // l_ lane-local; reduced once at end

  const u16* vpb = VpP + (size_t)(h*64) * 256;

  auto STAGE = [&](int buf, int kt0){
    #pragma unroll
    for (int c = 0; c < 2; ++c){
      const int a = w*2 + c;
      const int row = a*8 + l8;
      gload16(Kp + (size_t)(kt0 + row) * 1536 + h*64 + cbE, &Ks[buf][a * 512]);
      gload16(vpb + (size_t)row * 256 + kt0 + cbE, &VTs[buf][a * 512]);
    }
  };

  STAGE(0, 0);
  __syncthreads();

  int buf = 0;
  for (int nt = 0; nt < 4; ++nt){
    if (nt + 1 < 4){
      STAGE(buf ^ 1, (nt + 1) * 64);
      VMWAIT(4);
    } else {
      VMWAIT(0);
    }
    SCHED0();
    SBAR();
    SCHED0();
    const int kt0 = nt * 64;

    f32x4 s[4];
    __builtin_amdgcn_s_setprio(1);
    #pragma unroll
    for (int n4 = 0; n4 < 4; ++n4){
      f32x4 t = {0.f, 0.f, 0.f, 0.f};
      #pragma unroll
      for (int kk = 0; kk < 2; ++kk){
        const int sz = ((kk*4 + l4) ^ (l15 & 7)) * 8;
        bf16x8 kf = *(const bf16x8*)(&Ks[buf][(n4*16 + l15) * 64 + sz]);
        t = MFMA(kf, qf[kk], t);
      }
      s[n4] = t;
    }
    __builtin_amdgcn_s_setprio(0);

    #pragma unroll
    for (int n4 = 0; n4 < 4; ++n4){
      const float4 cv = *(const float4*)&clip_l[kt0 + n4*16 + l4*4];
      s[n4][0] = fmaf(s[n4][0], SCALE, gate * cv.x);
      s[n4][1] = fmaf(s[n4][1], SCALE, gate * cv.y);
      s[n4][2] = fmaf(s[n4][2], SCALE, gate * cv.z);
      s[n4][3] = fmaf(s[n4][3], SCALE, gate * cv.w);
    }

    float mt = -1e30f;
    #pragma unroll
    for (int n4 = 0; n4 < 4; ++n4)
      mt = fmaxf(mt, fmaxf(fmaxf(s[n4][0], s[n4][1]), fmaxf(s[n4][2], s[n4][3])));
    mt = redl4_max(mt);

    const float mn = fmaxf(m_, mt);
    const float al = fexp2((m_ - mn) * L2E);
    m_ = mn;
    l_ *= al;
    float alo[4];
    #pragma unroll
    for (int r = 0; r < 4; ++r) alo[r] = __shfl(al, l4*4 + r, 16);
    #pragma unroll
    for (int nb = 0; nb < 4; ++nb)
      #pragma unroll
      for (int r = 0; r < 4; ++r) O[nb][r] *= alo[r];

    const float m2 = m_ * L2E;
    #pragma unroll
    for (int n4 = 0; n4 < 4; ++n4)
      #pragma unroll
      for (int r = 0; r < 4; ++r){
        float pv = fexp2(fmaf(s[n4][r], L2E, -m2));
        l_ += pv;
        s[n4][r] = pv;
      }

    __builtin_amdgcn_s_setprio(1);
    #pragma unroll
    for (int kk = 0; kk < 2; ++kk){
      const int sz = ((kk*4 + l4) ^ (l15 & 7)) * 8;
      union { u32 w4[4]; bf16x8 v; } U;
      U.w4[0] = cvtpk(s[2*kk][0],   s[2*kk][1]);
      U.w4[1] = cvtpk(s[2*kk][2],   s[2*kk][3]);
      U.w4[2] = cvtpk(s[2*kk+1][0], s[2*kk+1][1]);
      U.w4[3] = cvtpk(s[2*kk+1][2], s[2*kk+1][3]);
      #pragma unroll
      for (int nb = 0; nb < 4; ++nb){
        bf16x8 vt = *(const bf16x8*)(&VTs[buf][(nb*16 + l15) * 64 + sz]);
        O[nb] = MFMA(U.v, vt, O[nb]);
      }
    }
    __builtin_amdgcn_s_setprio(0);

    SCHED0();
    SBAR();
    buf ^= 1;
  }

  const float inv = 1.f / redl4_sum(l_);
  float li[4];
  #pragma unroll
  for (int r = 0; r < 4; ++r) li[r] = __shfl(inv, l4*4 + r, 16);
  #pragma unroll
  for (int r = 0; r < 4; ++r){
    const int row = blockIdx.x * 64 + w * 16 + l4*4 + r;
    #pragma unroll
    for (int nb = 0; nb < 4; ++nb)
      multi[(size_t)row * 1536 + h*64 + nb*16 + l15] = O[nb][r] * li[r];
  }
}

// ---------------- self attention: flash split-K (2 halves), partials merged later ----------------

__global__ __launch_bounds__(256, 4) void k_self_attn_split(
  const u16* __restrict__ q2,   // [2304][1536]
  const u16* __restrict__ k2,   // [2304][1536]
  const u16* __restrict__ v2P,  // [1536][2304], cols pi-permuted per 32-block
  float* __restrict__ Opart,    // [2][2240][1536] unnormalized
  float2* __restrict__ ml)      // [2][24][2240] (m, l)
{
  const int p = blockIdx.x;
  const int slot = p >> 3;
  const int h   = (p & 7) * 3 + slot / 70;
  const int rem = slot % 70;
  const int qb = rem >> 1, half = rem & 1;
  const int nt0 = half * 18, ntE = half ? 35 : 18;
  const int tid = threadIdx.x, lane = tid & 63, w = tid >> 6;
  const int l15 = lane & 15, l4 = lane >> 4;
  const int l8 = lane >> 3, l7 = lane & 7;
  const int cbE = (l7 ^ l8) * 8;
  const int qrow = qb * 64 + w * 16 + l15;

  __shared__ alignas(1024) u16 Ks[2][4096];
  __shared__ alignas(1024) u16 VTs[2][4096];

  bf16x8 qf[2];
  #pragma unroll
  for (int kk = 0; kk < 2; ++kk)
    qf[kk] = *(const bf16x8*)(q2 + (size_t)qrow * 1536 + h*64 + kk*32 + l4*8);

  f32x4 O[4];
  #pragma unroll
  for (int nb = 0; nb < 4; ++nb) O[nb] = (f32x4){0.f, 0.f, 0.f, 0.f};
  float m_ = -1e30f, l_ = 0.f;          // lane-local l; reduced at end
  const float C2 = SCALE * L2E;
  const float THR = 44.36f;             // 8 / C2

  const u16* kp  = k2 + h*64;
  const u16* vp0 = v2P + (size_t)(h*64) * NPAD;

  auto STAGE = [&](int buf, int kt0){
    #pragma unroll
    for (int c = 0; c < 2; ++c){
      const int a = w*2 + c;
      const int row = a*8 + l8;
      gload16(kp + (size_t)(kt0 + row) * 1536 + cbE, &Ks[buf][a * 512]);
      gload16(vp0 + (size_t)row * NPAD + kt0 + cbE, &VTs[buf][a * 512]);
    }
  };

  STAGE(0, nt0 * 64);
  __syncthreads();

  int buf = 0;
  for (int nt = nt0; nt < ntE; ++nt){
    if (nt + 1 < ntE){
      STAGE(buf ^ 1, (nt + 1) * 64);
      VMWAIT(4);
    } else {
      VMWAIT(0);
    }
    SCHED0();
    SBAR();
    SCHED0();
    const int kt0 = nt * 64;

    f32x4 s[4];
    __builtin_amdgcn_s_setprio(1);
    #pragma unroll
    for (int n4 = 0; n4 < 4; ++n4){
      f32x4 t = {0.f, 0.f, 0.f, 0.f};
      #pragma unroll
      for (int kk = 0; kk < 2; ++kk){
        const int sz = ((kk*4 + l4) ^ (l15 & 7)) * 8;
        bf16x8 kf = *(const bf16x8*)(&Ks[buf][(n4*16 + l15) * 64 + sz]);
        t = MFMA(kf, qf[kk], t);
      }
      s[n4] = t;
    }
    __builtin_amdgcn_s_setprio(0);

    if (kt0 + 64 > NTOT){                       // only the global last tile
      #pragma unroll
      for (int n4 = 0; n4 < 4; ++n4){
        const int keyb = kt0 + n4*16 + l4*4;
        #pragma unroll
        for (int r = 0; r < 4; ++r)
          if (keyb + r >= NTOT) s[n4][r] = -1e30f;
      }
    }

    float mt = -1e30f;
    #pragma unroll
    for (int n4 = 0; n4 < 4; ++n4)
      mt = fmaxf(mt, fmaxf(fmaxf(s[n4][0], s[n4][1]), fmaxf(s[n4][2], s[n4][3])));
    mt = redl4_max(mt);

    if (__any(mt > m_ + THR)){                  // T13 defer-max
      const float mn = fmaxf(m_, mt);
      const float al = fexp2((m_ - mn) * C2);
      m_ = mn;
      l_ *= al;                                 // al uniform across l4-group
      float alo[4];
      #pragma unroll
      for (int r = 0; r < 4; ++r) alo[r] = __shfl(al, l4*4 + r, 16);
      #pragma unroll
      for (int nb = 0; nb < 4; ++nb)
        #pragma unroll
        for (int r = 0; r < 4; ++r) O[nb][r] *= alo[r];
    }
    const float m2 = m_ * C2;

    #pragma unroll
    for (int n4 = 0; n4 < 4; ++n4)
      #pragma unroll
      for (int r = 0; r < 4; ++r){
        float pv = fexp2(fmaf(s[n4][r], C2, -m2));
        l_ += pv;
        s[n4][r] = pv;
      }

    __builtin_amdgcn_s_setprio(1);
    #pragma unroll
    for (int kk = 0; kk < 2; ++kk){
      const int sz = ((kk*4 + l4) ^ (l15 & 7)) * 8;
      union { u32 w4[4]; bf16x8 v; } U;
      U.w4[0] = cvtpk(s[2*kk][0],   s[2*kk][1]);
      U.w4[1] = cvtpk(s[2*kk][2],   s[2*kk][3]);
      U.w4[2] = cvtpk(s[2*kk+1][0], s[2*kk+1][1]);
      U.w4[3] = cvtpk(s[2*kk+1][2], s[2*kk+1][3]);
      #pragma unroll
      for (int nb = 0; nb < 4; ++nb){
        bf16x8 vt = *(const bf16x8*)(&VTs[buf][(nb*16 + l15) * 64 + sz]);
        O[nb] = MFMA(U.v, vt, O[nb]);
      }
    }
    __builtin_amdgcn_s_setprio(0);

    SCHED0();
    SBAR();
    buf ^= 1;
  }

  const float lsum = redl4_sum(l_);
  float* Oh = Opart + (size_t)half * 2240 * 1536;
  #pragma unroll
  for (int r = 0; r < 4; ++r){
    const int row = qb*64 + w*16 + l4*4 + r;
    #pragma unroll
    for (int nb = 0; nb < 4; ++nb)
      Oh[(size_t)row * 1536 + h*64 + nb*16 + l15] = O[nb][r];
  }
  if (l4 == 0)
    ml[(size_t)half*24*2240 + h*2240 + qrow] = make_float2(m_, lsum);
}

// fused: split-K merge + adaptive gate/blend (img rows) or bf16 cast (txt rows)
__global__ __launch_bounds__(256) void k_merge_blend(
  const float* __restrict__ Op,     // [2][2240][1536]
  const float2* __restrict__ ml,    // [2][24][2240]
  const float* __restrict__ multi,  // [2048][1536]
  const float* __restrict__ Wad,    // [3072]
  const float* __restrict__ badp,
  u16* __restrict__ blended,        // [2048][1536] bf16
  u16* __restrict__ hstxt)          // [154][1536] bf16
{
  const int row = blockIdx.x;       // 0..2201
  const int t = threadIdx.x;
  const int lane = t & 63, wid = t >> 6;
  __shared__ float e0s[24], e1s[24], invs[24];
  __shared__ float redbuf[4];
  if (t < 24){
    const float2 a = ml[t*2240 + row];
    const float2 b = ml[24*2240 + t*2240 + row];
    const float M = fmaxf(a.x, b.x);
    const float C2 = SCALE * L2E;
    const float e0 = fexp2((a.x - M) * C2);
    const float e1 = fexp2((b.x - M) * C2);
    e0s[t] = e0; e1s[t] = e1;
    invs[t] = 1.f / (e0*a.y + e1*b.y);
  }
  __syncthreads();
  const float* O0 = Op + (size_t)row * 1536;
  const float* O1 = Op + (size_t)2240*1536 + (size_t)row * 1536;
  float mg[6];
  #pragma unroll
  for (int i = 0; i < 6; ++i){
    const int col = t + i*256;
    const int h = col >> 6;
    mg[i] = (e0s[h]*O0[col] + e1s[h]*O1[col]) * invs[h];
  }
  if (row < 2048){
    const float* mrow = multi + (size_t)row * 1536;
    float dot = 0.f;
    #pragma unroll
    for (int i = 0; i < 6; ++i){
      const int col = t + i*256;
      dot += mrow[col] * Wad[col] + mg[i] * Wad[1536 + col];
    }
    dot = red64_sum(dot);
    if (lane == 0) redbuf[wid] = dot;
    __syncthreads();
    const float tot = redbuf[0] + redbuf[1] + redbuf[2] + redbuf[3] + badp[0];
    const float f = BLENDF / (1.f + __expf(-tot));
    u16* brow = blended + (size_t)row * 1536;
    #pragma unroll
    for (int i = 0; i < 6; ++i){
      const int col = t + i*256;
      brow[col] = f2bf(fmaf(f, mrow[col], mg[i]));
    }
  } else {
    u16* orow = hstxt + (size_t)(row - 2048) * 1536;
    #pragma unroll
    for (int i = 0; i < 6; ++i)
      orow[t + i*256] = f2bf(mg[i]);
  }
}

// ---------------- launch ----------------

extern "C" void kernel_launch(void* const* d_in, const int* in_sizes, int n_in,
                              void* d_out, int out_size, void* d_ws, size_t ws_size,
                              hipStream_t stream)
{
  (void)in_sizes; (void)n_in; (void)out_size; (void)ws_size;
  const float* hs   = (const float*)d_in[0];
  const float* enc  = (const float*)d_in[1];
  const float* pics = (const float*)d_in[2];
  const float* clip = (const float*)d_in[3];
  const float* Wq   = (const float*)d_in[4];  const float* bq   = (const float*)d_in[5];
  const float* Wk   = (const float*)d_in[6];  const float* bk   = (const float*)d_in[7];
  const float* Wv   = (const float*)d_in[8];  const float* bv   = (const float*)d_in[9];
  const float* Waq  = (const float*)d_in[10]; const float* baq  = (const float*)d_in[11];
  const float* Wak  = (const float*)d_in[12]; const float* bak  = (const float*)d_in[13];
  const float* Wav  = (const float*)d_in[14]; const float* bav  = (const float*)d_in[15];
  const float* Wkl  = (const float*)d_in[16]; const float* Wvl  = (const float*)d_in[17];
  const float* Wsl  = (const float*)d_in[18]; const float* bsl  = (const float*)d_in[19];
  const float* Wad  = (const float*)d_in[20]; const float* bad  = (const float*)d_in[21];
  const float* Wout = (const float*)d_in[22]; const float* bout = (const float*)d_in[23];
  const float* Wadd = (const float*)d_in[24]; const float* badd = (const float*)d_in[25];

  char* ws = (char*)d_ws;
  size_t off = 0;
  auto alloc = [&](size_t b){ void* p = ws + off; off += (b + 255) & ~(size_t)255; return p; };

  u16* hs_bf  = (u16*)alloc((size_t)2048*1536*2);
  u16* enc_bf = (u16*)alloc((size_t)154*1536*2);
  u16* pics_bf= (u16*)alloc((size_t)256*1024*2);
  // WqT..WavT (6 x 4.7MB, contiguous) are DEAD after the input GEMMs;
  // reused as the split-attn partial-O buffer (27.5MB <= 28.3MB).
  u16* WqT  = (u16*)alloc((size_t)1536*1536*2);
  u16* WkT  = (u16*)alloc((size_t)1536*1536*2);
  u16* WvT  = (u16*)alloc((size_t)1536*1536*2);
  u16* WaqT = (u16*)alloc((size_t)1536*1536*2);
  u16* WakT = (u16*)alloc((size_t)1536*1536*2);
  u16* WavT = (u16*)alloc((size_t)1536*1536*2);
  u16* WoutT= (u16*)alloc((size_t)1536*1536*2);
  u16* WaddT= (u16*)alloc((size_t)1536*1536*2);
  u16* WklT = (u16*)alloc((size_t)1536*1024*2);
  u16* WvlT = (u16*)alloc((size_t)1536*1024*2);
  u16* q2   = (u16*)alloc((size_t)NPAD*1536*2);
  u16* k2   = (u16*)alloc((size_t)NPAD*1536*2);
  u16* v2   = (u16*)alloc((size_t)NPAD*1536*2);
  u16* v2P  = (u16*)alloc((size_t)1536*NPAD*2);
  u16* Kp   = (u16*)alloc((size_t)256*1536*2);
  u16* Vp   = (u16*)alloc((size_t)256*1536*2);
  u16* VpP  = (u16*)alloc((size_t)1536*256*2);
  float* wvec   = (float*)alloc((size_t)1536*4);
  float* multi  = (float*)alloc((size_t)2048*1536*4);
  u16* blended  = (u16*)alloc((size_t)2048*1536*2);
  u16* hstxt    = (u16*)alloc((size_t)154*1536*2);
  float2* mlbuf = (float2*)alloc((size_t)2*24*2240*8);
  float* Opart  = (float*)WqT;   // alias: dead after input GEMMs

  // fused prep: 3 casts + zero-pad of q2/k2/v2 tail rows (1 launch)
  k_prep<<<dim3(2009), 256, 0, stream>>>(hs, enc, pics, hs_bf, enc_bf, pics_bf,
                                         q2 + (size_t)NTOT*1536,
                                         k2 + (size_t)NTOT*1536,
                                         v2 + (size_t)NTOT*1536);

  WT10 wts;
  wts.w[0] = {Wq,   WqT,   1536};
  wts.w[1] = {Wk,   WkT,   1536};
  wts.w[2] = {Wv,   WvT,   1536};
  wts.w[3] = {Waq,  WaqT,  1536};
  wts.w[4] = {Wak,  WakT,  1536};
  wts.w[5] = {Wav,  WavT,  1536};
  wts.w[6] = {Wout, WoutT, 1536};
  wts.w[7] = {Wadd, WaddT, 1536};
  wts.w[8] = {Wkl,  WklT,  1024};
  wts.w[9] = {Wvl,  WvlT,  1024};
  k_transpose_w<<<dim3(24, 24, 10), 256, 0, stream>>>(wts);

  // fused input GEMMs: QKV (1152, XCD-region) + enc (108) + pics (96) in one dispatch
  GDesc dq, de, dp;
  dq.A = hs_bf; dq.BT = WqT; dq.lda = 1536; dq.ldb = 1536; dq.ldc = 1536;
  dq.M = 2048; dq.N = 4608; dq.K = 1536; dq.gx = 1; dq.nCx = 4; dq.rBlk = 16; dq.cBlk = 9; dq.nbx = 0;
  dq.o.C[0] = q2; dq.o.C[1] = k2; dq.o.C[2] = v2;
  dq.o.b[0] = bq; dq.o.b[1] = bk; dq.o.b[2] = bv;
  de.A = enc_bf; de.BT = WaqT; de.lda = 1536; de.ldb = 1536; de.ldc = 1536;
  de.M = 154; de.N = 4608; de.K = 1536; de.gx = 0; de.nbx = 36; de.nCx = de.rBlk = de.cBlk = 0;
  de.o.C[0] = q2 + (size_t)2048*1536; de.o.C[1] = k2 + (size_t)2048*1536; de.o.C[2] = v2 + (size_t)2048*1536;
  de.o.b[0] = baq; de.o.b[1] = bak; de.o.b[2] = bav;
  dp.A = pics_bf; dp.BT = WklT; dp.lda = 1024; dp.ldb = 1024; dp.ldc = 1536;
  dp.M = 256; dp.N = 3072; dp.K = 1024; dp.gx = 0; dp.nbx = 24; dp.nCx = dp.rBlk = dp.cBlk = 0;
  dp.o.C[0] = Kp; dp.o.C[1] = Vp; dp.o.C[2] = nullptr;
  dp.o.b[0] = nullptr; dp.o.b[1] = nullptr; dp.o.b[2] = nullptr;
  k_gemm_multi<0><<<dim3(1356), 256, 0, stream>>>(dq, de, dp, 1152, 1260);

  k_wvec<<<dim3(6), 256, 0, stream>>>(Kp, Wsl, wvec);

  k_transpose_vp<<<dim3(48, NPAD/32), dim3(32, 8), 0, stream>>>(v2, v2P, NPAD, 1536);
  k_transpose_vp<<<dim3(48, 8),       dim3(32, 8), 0, stream>>>(Vp, VpP, 256, 1536);

  k_cross_attn<<<dim3(32, 24), 256, 0, stream>>>(q2, Kp, VpP, clip, Wsl, bsl, wvec, multi);
  // split-K self-attn: 1680 blocks (2 halves per (head,qb)), then fused merge+blend
  k_self_attn_split<<<dim3(1680), 256, 0, stream>>>(q2, k2, v2P, Opart, mlbuf);
  k_merge_blend<<<dim3(NTOT), 256, 0, stream>>>(Opart, mlbuf, multi, Wad, bad, blended, hstxt);

  // fused output GEMMs: Wout (384, XCD-region) + Wadd (36) in one dispatch
  GDesc dw, da;
  dw.A = blended; dw.BT = WoutT; dw.lda = 1536; dw.ldb = 1536; dw.ldc = 1536;
  dw.M = 2048; dw.N = 1536; dw.K = 1536; dw.gx = 1; dw.nCx = 2; dw.rBlk = 8; dw.cBlk = 6; dw.nbx = 0;
  dw.o.C[0] = d_out; dw.o.C[1] = nullptr; dw.o.C[2] = nullptr;
  dw.o.b[0] = bout; dw.o.b[1] = nullptr; dw.o.b[2] = nullptr;
  da.A = hstxt; da.BT = WaddT; da.lda = 1536; da.ldb = 1536; da.ldc = 1536;
  da.M = 154; da.N = 1536; da.K = 1536; da.gx = 0; da.nbx = 12; da.nCx = da.rBlk = da.cBlk = 0;
  da.o.C[0] = (float*)d_out + (size_t)2048*1536; da.o.C[1] = nullptr; da.o.C[2] = nullptr;
  da.o.b[0] = badd; da.o.b[1] = nullptr; da.o.b[2] = nullptr;
  k_gemm_multi<1><<<dim3(420), 256, 0, stream>>>(dw, da, da, 384, 420);
}